// Round 11
// baseline (660.895 us; speedup 1.0000x reference)
//
#include <hip/hip_runtime.h>

#define NN 100000
#define NE 1600000
#define NT (NE + NN)     // edges incl. self-loops
#define FD 128
#define NC 10
#define NG 64

#define NBKT ((NN + 127) >> 7)   // 782 buckets of 128 nodes
#define NCH 128                  // edge chunks
#define CH (NE / NCH)            // 12500 edges per chunk
#define NBC2 (NBKT * NCH)        // 100096 (bucket, chunk) counters
#define SCB2 196                 // 196*512 = 100352 >= NBC2
#define CAP 3072                 // LDS edge cap per bucket (mean 2046, sigma ~45)

typedef __attribute__((ext_vector_type(8))) short short8v;   // 8 bf16 (4 VGPRs)
typedef __attribute__((ext_vector_type(4))) float f32x4;

__device__ inline ushort f2bf(float x) {                     // round-to-nearest-even
  unsigned u = __float_as_uint(x);
  return (ushort)((u + 0x7FFF + ((u >> 16) & 1)) >> 16);
}
__device__ inline float bf2f(ushort h) { return __uint_as_float(((unsigned)h) << 16); }

// ---------- chunked-LDS binned CSR build (no global atomics) ----------

// per-chunk LDS histogram -> histG[bucket*NCH + chunk]
__global__ __launch_bounds__(256) void k_hist(const int* __restrict__ dst,
                                              int* __restrict__ histG) {
  __shared__ int hist[NBKT];
  int tid = threadIdx.x, chunk = blockIdx.x;
  for (int i = tid; i < NBKT; i += 256) hist[i] = 0;
  __syncthreads();
  int e0 = chunk * CH;
  for (int i = tid; i < CH; i += 256)
    atomicAdd(&hist[dst[e0 + i] >> 7], 1);
  __syncthreads();
  for (int i = tid; i < NBKT; i += 256) histG[i * NCH + chunk] = hist[i];
}

// 3-phase exclusive scan over NBC2 counters -> boffC
__global__ void k_s2A(const int* __restrict__ cnt, int* __restrict__ blockSums) {
  __shared__ int red[256];
  int t = threadIdx.x, b = blockIdx.x;
  int i0 = b * 512 + t * 2;
  int s = 0;
#pragma unroll
  for (int j = 0; j < 2; ++j) { int i = i0 + j; if (i < NBC2) s += cnt[i]; }
  red[t] = s;
  __syncthreads();
  for (int off = 128; off > 0; off >>= 1) {
    if (t < off) red[t] += red[t + off];
    __syncthreads();
  }
  if (t == 0) blockSums[b] = red[0];
}

__global__ void k_s2B(const int* __restrict__ blockSums, int* __restrict__ blockOffs,
                      int* __restrict__ boffC) {
  __shared__ int sh[256];
  int t = threadIdx.x;
  int v = (t < SCB2) ? blockSums[t] : 0;
  sh[t] = v;
  __syncthreads();
  for (int off = 1; off < 256; off <<= 1) {
    int u = (t >= off) ? sh[t - off] : 0;
    __syncthreads();
    sh[t] += u;
    __syncthreads();
  }
  if (t < SCB2) blockOffs[t] = sh[t] - v;   // exclusive
  if (t == 255) boffC[NBC2] = sh[255];      // = NE
}

__global__ void k_s2C(const int* __restrict__ cnt, const int* __restrict__ blockOffs,
                      int* __restrict__ boffC) {
  __shared__ int sh[256];
  int t = threadIdx.x, b = blockIdx.x;
  int i0 = b * 512 + t * 2;
  int c[2];
  int s = 0;
#pragma unroll
  for (int j = 0; j < 2; ++j) {
    int i = i0 + j;
    c[j] = (i < NBC2) ? cnt[i] : 0;
    s += c[j];
  }
  sh[t] = s;
  __syncthreads();
  for (int off = 1; off < 256; off <<= 1) {
    int u = (t >= off) ? sh[t - off] : 0;
    __syncthreads();
    sh[t] += u;
    __syncthreads();
  }
  int run = blockOffs[b] + sh[t] - s;
#pragma unroll
  for (int j = 0; j < 2; ++j) {
    int i = i0 + j;
    if (i < NBC2) { boffC[i] = run; run += c[j]; }
  }
}

// re-read chunk, LDS cursors, append packed (local_dst<<17 | src): line-local writes
__global__ __launch_bounds__(256) void k_chscatter(const int* __restrict__ src,
                                                   const int* __restrict__ dst,
                                                   const int* __restrict__ boffC,
                                                   unsigned* __restrict__ binned) {
  __shared__ int curs[NBKT];
  int tid = threadIdx.x, chunk = blockIdx.x;
  for (int i = tid; i < NBKT; i += 256) curs[i] = boffC[i * NCH + chunk];
  __syncthreads();
  int e0 = chunk * CH;
  for (int i = tid; i < CH; i += 256) {
    int e = e0 + i;
    int d = dst[e], s = src[e];
    int slot = atomicAdd(&curs[d >> 7], 1);
    binned[slot] = ((unsigned)(d & 127) << 17) | (unsigned)s;
  }
}

// one block per bucket: local degree count, local scan (+self), emit rowptr/dinv,
// LDS scatter, contiguous coalesced CSR write. Fallback to global scatter if >CAP.
__global__ __launch_bounds__(256) void k_csr_bucket(
    const int* __restrict__ boffC, const unsigned* __restrict__ binned,
    int* __restrict__ rowptr, float* __restrict__ dinv, int* __restrict__ csr_src) {
  __shared__ unsigned varr[CAP];
  __shared__ int earr[CAP + 128];
  __shared__ int deg[128];
  __shared__ int sh[128];
  int b = blockIdx.x, tid = threadIdx.x;
  int e0 = boffC[b * NCH], e1 = boffC[(b + 1) * NCH], seg = e1 - e0;
  int n0 = b << 7;
  int nb = NN - n0; if (nb > 128) nb = 128;
  int gbase = e0 + n0;                      // + one self per preceding node
  if (tid < 128) deg[tid] = 0;
  __syncthreads();
  bool fast = (seg <= CAP);
  if (fast) {
    for (int i = tid; i < seg; i += 256) {
      unsigned v = binned[e0 + i];
      varr[i] = v;
      atomicAdd(&deg[(v >> 17) & 127], 1);
    }
  } else {
    for (int i = tid; i < seg; i += 256) {
      unsigned v = binned[e0 + i];
      atomicAdd(&deg[(v >> 17) & 127], 1);
    }
  }
  __syncthreads();
  int dl = 0;
  if (tid < 128) {
    dl = (tid < nb) ? deg[tid] + 1 : 0;     // +1 self-loop
    sh[tid] = dl;
  }
  __syncthreads();
  for (int off = 1; off < 128; off <<= 1) {
    int u = 0;
    if (tid < 128 && tid >= off) u = sh[tid - off];
    __syncthreads();
    if (tid < 128) sh[tid] += u;
    __syncthreads();
  }
  int excl = 0;
  if (tid < nb) {
    excl = sh[tid] - dl;
    rowptr[n0 + tid] = gbase + excl;
    dinv[n0 + tid] = rsqrtf((float)dl);
    if (fast) earr[excl] = n0 + tid;        // self-loop in first slot
    else      csr_src[gbase + excl] = n0 + tid;
  }
  __syncthreads();
  if (tid < 128) deg[tid] = (tid < nb) ? (excl + 1) : 0;   // cursor after self
  __syncthreads();
  if (fast) {
    for (int i = tid; i < seg; i += 256) {
      unsigned v = varr[i];
      int l = (v >> 17) & 127;
      int pos = atomicAdd(&deg[l], 1);
      earr[pos] = (int)(v & 0x1FFFF);
    }
    __syncthreads();
    int tot = seg + nb;
    for (int i = tid; i < tot; i += 256) csr_src[gbase + i] = earr[i];
  } else {
    for (int i = tid; i < seg; i += 256) {
      unsigned v = binned[e0 + i];
      int l = (v >> 17) & 127;
      int pos = atomicAdd(&deg[l], 1);
      csr_src[gbase + pos] = (int)(v & 0x1FFFF);
    }
  }
  if (b == 0 && tid == 0) rowptr[NN] = NT;
}

// ---------- split-bf16 prep ----------

__global__ void k_split(const float* __restrict__ X, ushort* __restrict__ Hh,
                        ushort* __restrict__ Hl) {
  int t = blockIdx.x * 256 + threadIdx.x;
  if (t >= NN * FD / 4) return;
  float4 v = ((const float4*)X)[t];
  ushort4 h, l;
  h.x = f2bf(v.x); l.x = f2bf(v.x - bf2f(h.x));
  h.y = f2bf(v.y); l.y = f2bf(v.y - bf2f(h.y));
  h.z = f2bf(v.z); l.z = f2bf(v.z - bf2f(h.z));
  h.w = f2bf(v.w); l.w = f2bf(v.w - bf2f(h.w));
  ((ushort4*)Hh)[t] = h;
  ((ushort4*)Hl)[t] = l;
}

// Pack W[k][col] into MFMA B-fragment order, split hi/lo:
// packed[(((k>>5)*128 + col)*4 + ((k>>3)&3))*8 + (k&7)]
__global__ void k_packW(const float* __restrict__ W, ushort* __restrict__ Wh,
                        ushort* __restrict__ Wl) {
  int idx = blockIdx.x * 256 + threadIdx.x;
  if (idx >= FD * FD) return;
  int k = idx >> 7, col = idx & 127;
  float v = W[idx];
  ushort h = f2bf(v);
  ushort l = f2bf(v - bf2f(h));
  size_t o = ((((size_t)(k >> 5)) * 128 + col) * 4 + ((k >> 3) & 3)) * 8 + (k & 7);
  Wh[o] = h; Wl[o] = l;
}

// ---------- MFMA GEMM: Qh = bf16( dinv[row] * ((Ah+Al)@(Wh+Wl)) ) ----------
// 32 rows/wave (two 16-row A-frag sets): halves B traffic, doubles MFMA ILP.
__global__ __launch_bounds__(256, 3) void k_gemm_mfma(
    const ushort* __restrict__ Ah, const ushort* __restrict__ Al,
    const ushort* __restrict__ Bh, const ushort* __restrict__ Bl,
    const float* __restrict__ dinv, ushort* __restrict__ Qh) {
  int tid = threadIdx.x;
  int wave = tid >> 6, lane = tid & 63;
  int m15 = lane & 15, k0 = lane >> 4;
  int row0 = blockIdx.x * 128 + wave * 32;

  int ar0 = row0 + m15;      if (ar0 >= NN) ar0 = NN - 1;
  int ar1 = row0 + 16 + m15; if (ar1 >= NN) ar1 = NN - 1;
  short8v ah0[4], al0[4], ah1[4], al1[4];
#pragma unroll
  for (int kc = 0; kc < 4; ++kc) {
    size_t o0 = (size_t)ar0 * FD + kc * 32 + k0 * 8;
    size_t o1 = (size_t)ar1 * FD + kc * 32 + k0 * 8;
    ah0[kc] = *(const short8v*)(Ah + o0);
    al0[kc] = *(const short8v*)(Al + o0);
    ah1[kc] = *(const short8v*)(Ah + o1);
    al1[kc] = *(const short8v*)(Al + o1);
  }

  int orow0 = row0 + k0 * 4;
  int orow1 = row0 + 16 + k0 * 4;
  float dv0[4], dv1[4];
#pragma unroll
  for (int j = 0; j < 4; ++j) {
    int r0 = orow0 + j; dv0[j] = (r0 < NN) ? dinv[r0] : 0.f;
    int r1 = orow1 + j; dv1[j] = (r1 < NN) ? dinv[r1] : 0.f;
  }

#pragma unroll
  for (int nt = 0; nt < 8; ++nt) {
    int col = nt * 16 + m15;
    f32x4 acc0 = {0.f, 0.f, 0.f, 0.f};
    f32x4 acc1 = {0.f, 0.f, 0.f, 0.f};
#pragma unroll
    for (int kc = 0; kc < 4; ++kc) {
      size_t off = (((size_t)kc * 128 + col) * 4 + k0) * 8;
      short8v bh = *(const short8v*)(Bh + off);
      short8v bl = *(const short8v*)(Bl + off);
      acc0 = __builtin_amdgcn_mfma_f32_16x16x32_bf16(ah0[kc], bh, acc0, 0, 0, 0);
      acc1 = __builtin_amdgcn_mfma_f32_16x16x32_bf16(ah1[kc], bh, acc1, 0, 0, 0);
      acc0 = __builtin_amdgcn_mfma_f32_16x16x32_bf16(ah0[kc], bl, acc0, 0, 0, 0);
      acc1 = __builtin_amdgcn_mfma_f32_16x16x32_bf16(ah1[kc], bl, acc1, 0, 0, 0);
      acc0 = __builtin_amdgcn_mfma_f32_16x16x32_bf16(al0[kc], bh, acc0, 0, 0, 0);
      acc1 = __builtin_amdgcn_mfma_f32_16x16x32_bf16(al1[kc], bh, acc1, 0, 0, 0);
    }
#pragma unroll
    for (int j = 0; j < 4; ++j) {
      int r0 = orow0 + j;
      if (r0 < NN) Qh[(size_t)r0 * FD + col] = f2bf(dv0[j] * acc0[j]);
      int r1 = orow1 + j;
      if (r1 < NN) Qh[(size_t)r1 * FD + col] = f2bf(dv1[j] * acc1[j]);
    }
  }
}

// ---------- gather (feature-sliced for XCD L2 affinity) ----------
// blockIdx&7 -> XCD (default round-robin); slice = (blockIdx&7)>>1: 4 slices of
// 32 cols (one 64B line per row-slice); per-XCD working set 6.4 MB vs 25.6.
// 8 lanes per node (ushort4 each), 32 nodes per block.
__global__ __launch_bounds__(256) void k_gather(
    const int* __restrict__ rowptr, const int* __restrict__ csr_src,
    const ushort* __restrict__ Qh, const float* __restrict__ b,
    const float* __restrict__ dinv, ushort* __restrict__ Ph, ushort* __restrict__ Pl) {
  int g8 = blockIdx.x & 7;
  int node = (blockIdx.x >> 3) * 64 + (g8 & 1) * 32 + (threadIdx.x >> 3);
  if (node >= NN) return;
  int colv = ((g8 >> 1) << 3) + (threadIdx.x & 7);   // ushort4 index in row
  const ushort4* __restrict__ Q4 = (const ushort4*)Qh;
  float4 acc = {0.f, 0.f, 0.f, 0.f};
  int e0 = rowptr[node], e1 = rowptr[node + 1];
  int e = e0;
  for (; e + 3 < e1; e += 4) {
    int s0 = csr_src[e], s1 = csr_src[e + 1], s2 = csr_src[e + 2], s3 = csr_src[e + 3];
    ushort4 q0 = Q4[(size_t)s0 * 32 + colv];
    ushort4 q1 = Q4[(size_t)s1 * 32 + colv];
    ushort4 q2 = Q4[(size_t)s2 * 32 + colv];
    ushort4 q3 = Q4[(size_t)s3 * 32 + colv];
    acc.x += (bf2f(q0.x) + bf2f(q1.x)) + (bf2f(q2.x) + bf2f(q3.x));
    acc.y += (bf2f(q0.y) + bf2f(q1.y)) + (bf2f(q2.y) + bf2f(q3.y));
    acc.z += (bf2f(q0.z) + bf2f(q1.z)) + (bf2f(q2.z) + bf2f(q3.z));
    acc.w += (bf2f(q0.w) + bf2f(q1.w)) + (bf2f(q2.w) + bf2f(q3.w));
  }
  for (; e < e1; ++e) {
    int s0 = csr_src[e];
    ushort4 q0 = Q4[(size_t)s0 * 32 + colv];
    acc.x += bf2f(q0.x); acc.y += bf2f(q0.y);
    acc.z += bf2f(q0.z); acc.w += bf2f(q0.w);
  }
  float di = dinv[node];
  float4 bv = ((const float4*)b)[colv];
  acc.x = fmaxf(fmaf(di, acc.x, bv.x), 0.f);
  acc.y = fmaxf(fmaf(di, acc.y, bv.y), 0.f);
  acc.z = fmaxf(fmaf(di, acc.z, bv.z), 0.f);
  acc.w = fmaxf(fmaf(di, acc.w, bv.w), 0.f);
  ushort4 h, l;
  h.x = f2bf(acc.x); l.x = f2bf(acc.x - bf2f(h.x));
  h.y = f2bf(acc.y); l.y = f2bf(acc.y - bf2f(h.y));
  h.z = f2bf(acc.z); l.z = f2bf(acc.z - bf2f(h.z));
  h.w = f2bf(acc.w); l.w = f2bf(acc.w - bf2f(h.w));
  size_t o = (size_t)node * 32 + colv;
  ((ushort4*)Ph)[o] = h;
  ((ushort4*)Pl)[o] = l;
}

// ---------- pooling + head ----------

__global__ void k_zero_pool(float* __restrict__ sums, float* __restrict__ counts) {
  int t = blockIdx.x * 256 + threadIdx.x;
  if (t < NG * FD) sums[t] = 0.f;
  if (t < NG) counts[t] = 0.f;
}

#define POOL_BLOCKS 1024
#define POOL_CHUNK 98
__global__ void k_pool(const int* __restrict__ batch, const ushort* __restrict__ Ph,
                       const ushort* __restrict__ Pl, float* __restrict__ sums,
                       float* __restrict__ counts) {
  int f = threadIdx.x;  // 0..127
  int i0 = blockIdx.x * POOL_CHUNK;
  if (i0 >= NN) return;
  int i1 = i0 + POOL_CHUNK;
  if (i1 > NN) i1 = NN;
  float acc = 0.f;
  int gcur = batch[i0];
  int cnt = 0;
  for (int i = i0; i < i1; ++i) {
    int g = batch[i];
    if (g != gcur) {
      atomicAdd(&sums[gcur * FD + f], acc);
      if (f == 0) atomicAdd(&counts[gcur], (float)cnt);
      acc = 0.f; cnt = 0; gcur = g;
    }
    size_t o = (size_t)i * FD + f;
    acc += bf2f(Ph[o]) + bf2f(Pl[o]);
    ++cnt;
  }
  atomicAdd(&sums[gcur * FD + f], acc);
  if (f == 0) atomicAdd(&counts[gcur], (float)cnt);
}

__global__ void k_head(const float* __restrict__ sums, const float* __restrict__ counts,
                       const float* __restrict__ Wm, const float* __restrict__ bm,
                       float* __restrict__ out) {
  int t = blockIdx.x * 256 + threadIdx.x;
  if (t >= NG * NC) return;
  int g = t / NC, c = t % NC;
  float inv = 1.0f / fmaxf(counts[g], 1.0f);
  float s = 0.f;
#pragma unroll 4
  for (int f = 0; f < FD; ++f) s = fmaf(sums[g * FD + f] * inv, Wm[f * NC + c], s);
  out[t] = s + bm[c];
}

extern "C" void kernel_launch(void* const* d_in, const int* in_sizes, int n_in,
                              void* d_out, int out_size, void* d_ws, size_t ws_size,
                              hipStream_t stream) {
  const float* x     = (const float*)d_in[0];
  const int*   ei    = (const int*)d_in[1];
  const int*   batch = (const int*)d_in[2];
  const float* W_in  = (const float*)d_in[3];
  const float* b_in  = (const float*)d_in[4];
  const float* W_mid = (const float*)d_in[5];
  const float* b_mid = (const float*)d_in[6];
  const float* W_mlp = (const float*)d_in[7];
  const float* b_mlp = (const float*)d_in[8];
  float* out = (float*)d_out;

  const int* src = ei;        // edge_index[0]
  const int* dst = ei + NE;   // edge_index[1]

  char* ws = (char*)d_ws;
  ushort*   Qh      = (ushort*)ws;    ws += (size_t)NN * FD * 2;   // 25.6 MB
  ushort*   Ph      = (ushort*)ws;    ws += (size_t)NN * FD * 2;   // 25.6 MB
  ushort*   Pl      = (ushort*)ws;    ws += (size_t)NN * FD * 2;   // 25.6 MB
  float*    dinv    = (float*)ws;     ws += (size_t)NN * 4;
  int*      rowptr  = (int*)ws;       ws += (size_t)(NN + 1) * 4;
  int*      csr_src = (int*)ws;       ws += (size_t)NT * 4;        // 6.8 MB
  unsigned* binned  = (unsigned*)ws;  ws += (size_t)NE * 4;        // 6.4 MB
  int*      histG   = (int*)ws;       ws += (size_t)NBC2 * 4;      // 400 KB
  int*      boffC   = (int*)ws;       ws += (size_t)(NBC2 + 1) * 4;
  int*      cSums   = (int*)ws;       ws += 256 * 4;
  int*      cOffs   = (int*)ws;       ws += 256 * 4;
  ushort*   WhA     = (ushort*)ws;    ws += (size_t)FD * FD * 2;
  ushort*   WlA     = (ushort*)ws;    ws += (size_t)FD * FD * 2;
  ushort*   WhB     = (ushort*)ws;    ws += (size_t)FD * FD * 2;
  ushort*   WlB     = (ushort*)ws;    ws += (size_t)FD * FD * 2;
  float*    sums    = (float*)ws;     ws += (size_t)NG * FD * 4;
  float*    counts  = (float*)ws;     ws += (size_t)NG * 4;

  // chunked binned CSR build (incl. self-loops; reused by all 4 layers)
  k_hist<<<NCH, 256, 0, stream>>>(dst, histG);
  k_s2A<<<SCB2, 256, 0, stream>>>(histG, cSums);
  k_s2B<<<1, 256, 0, stream>>>(cSums, cOffs, boffC);
  k_s2C<<<SCB2, 256, 0, stream>>>(histG, cOffs, boffC);
  k_chscatter<<<NCH, 256, 0, stream>>>(src, dst, boffC, binned);
  k_csr_bucket<<<NBKT, 256, 0, stream>>>(boffC, binned, rowptr, dinv, csr_src);

  // weight packing + input split
  k_packW<<<(FD * FD + 255) / 256, 256, 0, stream>>>(W_in, WhA, WlA);
  k_packW<<<(FD * FD + 255) / 256, 256, 0, stream>>>(W_mid, WhB, WlB);
  k_split<<<(NN * FD / 4 + 255) / 256, 256, 0, stream>>>(x, Ph, Pl);

  const int gM = (NN + 127) / 128;     // 782 blocks, 128 rows each
  const int gG = ((NN + 63) / 64) * 8; // 12504 blocks: 64-node groups x 8 (slice pairs)
  for (int L = 0; L < 4; ++L) {
    const ushort* Wh = (L == 0) ? WhA : WhB;
    const ushort* Wl = (L == 0) ? WlA : WlB;
    const float*  b  = (L == 0) ? b_in : b_mid;
    k_gemm_mfma<<<gM, 256, 0, stream>>>(Ph, Pl, Wh, Wl, dinv, Qh);
    k_gather<<<gG, 256, 0, stream>>>(rowptr, csr_src, Qh, b, dinv, Ph, Pl);
  }

  k_zero_pool<<<32, 256, 0, stream>>>(sums, counts);
  k_pool<<<POOL_BLOCKS, 128, 0, stream>>>(batch, Ph, Pl, sums, counts);
  k_head<<<(NG * NC + 255) / 256, 256, 0, stream>>>(sums, counts, W_mlp, b_mlp, out);
}

// Round 12
// 500.947 us; speedup vs baseline: 1.3193x; 1.3193x over previous
//
#include <hip/hip_runtime.h>

#define NN 100000
#define NE 1600000
#define NT (NE + NN)     // edges incl. self-loops
#define FD 128
#define NC 10
#define NG 64

#define NBKT ((NN + 127) >> 7)   // 782 buckets of 128 nodes
#define NCH 128                  // edge chunks
#define CH (NE / NCH)            // 12500 edges per chunk
#define NBC2 (NBKT * NCH)        // 100096 (bucket, chunk) counters
#define SCB2 196                 // 196*512 = 100352 >= NBC2
#define CAP 3072                 // LDS edge cap per bucket (mean 2046, sigma ~45)

typedef __attribute__((ext_vector_type(8))) short short8v;   // 8 bf16 (4 VGPRs)
typedef __attribute__((ext_vector_type(4))) float f32x4;

__device__ inline ushort f2bf(float x) {                     // round-to-nearest-even
  unsigned u = __float_as_uint(x);
  return (ushort)((u + 0x7FFF + ((u >> 16) & 1)) >> 16);
}
__device__ inline float bf2f(ushort h) { return __uint_as_float(((unsigned)h) << 16); }

// ---------- chunked-LDS binned CSR build (no global atomics) ----------

__global__ __launch_bounds__(256) void k_hist(const int* __restrict__ dst,
                                              int* __restrict__ histG) {
  __shared__ int hist[NBKT];
  int tid = threadIdx.x, chunk = blockIdx.x;
  for (int i = tid; i < NBKT; i += 256) hist[i] = 0;
  __syncthreads();
  int e0 = chunk * CH;
  for (int i = tid; i < CH; i += 256)
    atomicAdd(&hist[dst[e0 + i] >> 7], 1);
  __syncthreads();
  for (int i = tid; i < NBKT; i += 256) histG[i * NCH + chunk] = hist[i];
}

__global__ void k_s2A(const int* __restrict__ cnt, int* __restrict__ blockSums) {
  __shared__ int red[256];
  int t = threadIdx.x, b = blockIdx.x;
  int i0 = b * 512 + t * 2;
  int s = 0;
#pragma unroll
  for (int j = 0; j < 2; ++j) { int i = i0 + j; if (i < NBC2) s += cnt[i]; }
  red[t] = s;
  __syncthreads();
  for (int off = 128; off > 0; off >>= 1) {
    if (t < off) red[t] += red[t + off];
    __syncthreads();
  }
  if (t == 0) blockSums[b] = red[0];
}

__global__ void k_s2B(const int* __restrict__ blockSums, int* __restrict__ blockOffs,
                      int* __restrict__ boffC) {
  __shared__ int sh[256];
  int t = threadIdx.x;
  int v = (t < SCB2) ? blockSums[t] : 0;
  sh[t] = v;
  __syncthreads();
  for (int off = 1; off < 256; off <<= 1) {
    int u = (t >= off) ? sh[t - off] : 0;
    __syncthreads();
    sh[t] += u;
    __syncthreads();
  }
  if (t < SCB2) blockOffs[t] = sh[t] - v;   // exclusive
  if (t == 255) boffC[NBC2] = sh[255];      // = NE
}

__global__ void k_s2C(const int* __restrict__ cnt, const int* __restrict__ blockOffs,
                      int* __restrict__ boffC) {
  __shared__ int sh[256];
  int t = threadIdx.x, b = blockIdx.x;
  int i0 = b * 512 + t * 2;
  int c[2];
  int s = 0;
#pragma unroll
  for (int j = 0; j < 2; ++j) {
    int i = i0 + j;
    c[j] = (i < NBC2) ? cnt[i] : 0;
    s += c[j];
  }
  sh[t] = s;
  __syncthreads();
  for (int off = 1; off < 256; off <<= 1) {
    int u = (t >= off) ? sh[t - off] : 0;
    __syncthreads();
    sh[t] += u;
    __syncthreads();
  }
  int run = blockOffs[b] + sh[t] - s;
#pragma unroll
  for (int j = 0; j < 2; ++j) {
    int i = i0 + j;
    if (i < NBC2) { boffC[i] = run; run += c[j]; }
  }
}

__global__ __launch_bounds__(256) void k_chscatter(const int* __restrict__ src,
                                                   const int* __restrict__ dst,
                                                   const int* __restrict__ boffC,
                                                   unsigned* __restrict__ binned) {
  __shared__ int curs[NBKT];
  int tid = threadIdx.x, chunk = blockIdx.x;
  for (int i = tid; i < NBKT; i += 256) curs[i] = boffC[i * NCH + chunk];
  __syncthreads();
  int e0 = chunk * CH;
  for (int i = tid; i < CH; i += 256) {
    int e = e0 + i;
    int d = dst[e], s = src[e];
    int slot = atomicAdd(&curs[d >> 7], 1);
    binned[slot] = ((unsigned)(d & 127) << 17) | (unsigned)s;
  }
}

__global__ __launch_bounds__(256) void k_csr_bucket(
    const int* __restrict__ boffC, const unsigned* __restrict__ binned,
    int* __restrict__ rowptr, float* __restrict__ dinv, int* __restrict__ csr_src) {
  __shared__ unsigned varr[CAP];
  __shared__ int earr[CAP + 128];
  __shared__ int deg[128];
  __shared__ int sh[128];
  int b = blockIdx.x, tid = threadIdx.x;
  int e0 = boffC[b * NCH], e1 = boffC[(b + 1) * NCH], seg = e1 - e0;
  int n0 = b << 7;
  int nb = NN - n0; if (nb > 128) nb = 128;
  int gbase = e0 + n0;                      // + one self per preceding node
  if (tid < 128) deg[tid] = 0;
  __syncthreads();
  bool fast = (seg <= CAP);
  if (fast) {
    for (int i = tid; i < seg; i += 256) {
      unsigned v = binned[e0 + i];
      varr[i] = v;
      atomicAdd(&deg[(v >> 17) & 127], 1);
    }
  } else {
    for (int i = tid; i < seg; i += 256) {
      unsigned v = binned[e0 + i];
      atomicAdd(&deg[(v >> 17) & 127], 1);
    }
  }
  __syncthreads();
  int dl = 0;
  if (tid < 128) {
    dl = (tid < nb) ? deg[tid] + 1 : 0;     // +1 self-loop
    sh[tid] = dl;
  }
  __syncthreads();
  for (int off = 1; off < 128; off <<= 1) {
    int u = 0;
    if (tid < 128 && tid >= off) u = sh[tid - off];
    __syncthreads();
    if (tid < 128) sh[tid] += u;
    __syncthreads();
  }
  int excl = 0;
  if (tid < nb) {
    excl = sh[tid] - dl;
    rowptr[n0 + tid] = gbase + excl;
    dinv[n0 + tid] = rsqrtf((float)dl);
    if (fast) earr[excl] = n0 + tid;        // self-loop in first slot
    else      csr_src[gbase + excl] = n0 + tid;
  }
  __syncthreads();
  if (tid < 128) deg[tid] = (tid < nb) ? (excl + 1) : 0;   // cursor after self
  __syncthreads();
  if (fast) {
    for (int i = tid; i < seg; i += 256) {
      unsigned v = varr[i];
      int l = (v >> 17) & 127;
      int pos = atomicAdd(&deg[l], 1);
      earr[pos] = (int)(v & 0x1FFFF);
    }
    __syncthreads();
    int tot = seg + nb;
    for (int i = tid; i < tot; i += 256) csr_src[gbase + i] = earr[i];
  } else {
    for (int i = tid; i < seg; i += 256) {
      unsigned v = binned[e0 + i];
      int l = (v >> 17) & 127;
      int pos = atomicAdd(&deg[l], 1);
      csr_src[gbase + pos] = (int)(v & 0x1FFFF);
    }
  }
  if (b == 0 && tid == 0) rowptr[NN] = NT;
}

// ---------- split-bf16 prep ----------

__global__ void k_split(const float* __restrict__ X, ushort* __restrict__ Hh,
                        ushort* __restrict__ Hl) {
  int t = blockIdx.x * 256 + threadIdx.x;
  if (t >= NN * FD / 4) return;
  float4 v = ((const float4*)X)[t];
  ushort4 h, l;
  h.x = f2bf(v.x); l.x = f2bf(v.x - bf2f(h.x));
  h.y = f2bf(v.y); l.y = f2bf(v.y - bf2f(h.y));
  h.z = f2bf(v.z); l.z = f2bf(v.z - bf2f(h.z));
  h.w = f2bf(v.w); l.w = f2bf(v.w - bf2f(h.w));
  ((ushort4*)Hh)[t] = h;
  ((ushort4*)Hl)[t] = l;
}

// Pack W[k][col] into MFMA B-fragment order, split hi/lo:
// packed[(((k>>5)*128 + col)*4 + ((k>>3)&3))*8 + (k&7)]
__global__ void k_packW(const float* __restrict__ W, ushort* __restrict__ Wh,
                        ushort* __restrict__ Wl) {
  int idx = blockIdx.x * 256 + threadIdx.x;
  if (idx >= FD * FD) return;
  int k = idx >> 7, col = idx & 127;
  float v = W[idx];
  ushort h = f2bf(v);
  ushort l = f2bf(v - bf2f(h));
  size_t o = ((((size_t)(k >> 5)) * 128 + col) * 4 + ((k >> 3) & 3)) * 8 + (k & 7);
  Wh[o] = h; Wl[o] = l;
}

// ---------- MFMA GEMM: Qh = bf16( dinv[row] * ((Ah+Al)@(Wh+Wl)) ) ----------
// 32 rows/wave (two 16-row A-frag sets): halves B traffic, doubles MFMA ILP.
__global__ __launch_bounds__(256, 3) void k_gemm_mfma(
    const ushort* __restrict__ Ah, const ushort* __restrict__ Al,
    const ushort* __restrict__ Bh, const ushort* __restrict__ Bl,
    const float* __restrict__ dinv, ushort* __restrict__ Qh) {
  int tid = threadIdx.x;
  int wave = tid >> 6, lane = tid & 63;
  int m15 = lane & 15, k0 = lane >> 4;
  int row0 = blockIdx.x * 128 + wave * 32;

  int ar0 = row0 + m15;      if (ar0 >= NN) ar0 = NN - 1;
  int ar1 = row0 + 16 + m15; if (ar1 >= NN) ar1 = NN - 1;
  short8v ah0[4], al0[4], ah1[4], al1[4];
#pragma unroll
  for (int kc = 0; kc < 4; ++kc) {
    size_t o0 = (size_t)ar0 * FD + kc * 32 + k0 * 8;
    size_t o1 = (size_t)ar1 * FD + kc * 32 + k0 * 8;
    ah0[kc] = *(const short8v*)(Ah + o0);
    al0[kc] = *(const short8v*)(Al + o0);
    ah1[kc] = *(const short8v*)(Ah + o1);
    al1[kc] = *(const short8v*)(Al + o1);
  }

  int orow0 = row0 + k0 * 4;
  int orow1 = row0 + 16 + k0 * 4;
  float dv0[4], dv1[4];
#pragma unroll
  for (int j = 0; j < 4; ++j) {
    int r0 = orow0 + j; dv0[j] = (r0 < NN) ? dinv[r0] : 0.f;
    int r1 = orow1 + j; dv1[j] = (r1 < NN) ? dinv[r1] : 0.f;
  }

#pragma unroll
  for (int nt = 0; nt < 8; ++nt) {
    int col = nt * 16 + m15;
    f32x4 acc0 = {0.f, 0.f, 0.f, 0.f};
    f32x4 acc1 = {0.f, 0.f, 0.f, 0.f};
#pragma unroll
    for (int kc = 0; kc < 4; ++kc) {
      size_t off = (((size_t)kc * 128 + col) * 4 + k0) * 8;
      short8v bh = *(const short8v*)(Bh + off);
      short8v bl = *(const short8v*)(Bl + off);
      acc0 = __builtin_amdgcn_mfma_f32_16x16x32_bf16(ah0[kc], bh, acc0, 0, 0, 0);
      acc1 = __builtin_amdgcn_mfma_f32_16x16x32_bf16(ah1[kc], bh, acc1, 0, 0, 0);
      acc0 = __builtin_amdgcn_mfma_f32_16x16x32_bf16(ah0[kc], bl, acc0, 0, 0, 0);
      acc1 = __builtin_amdgcn_mfma_f32_16x16x32_bf16(ah1[kc], bl, acc1, 0, 0, 0);
      acc0 = __builtin_amdgcn_mfma_f32_16x16x32_bf16(al0[kc], bh, acc0, 0, 0, 0);
      acc1 = __builtin_amdgcn_mfma_f32_16x16x32_bf16(al1[kc], bh, acc1, 0, 0, 0);
    }
#pragma unroll
    for (int j = 0; j < 4; ++j) {
      int r0 = orow0 + j;
      if (r0 < NN) Qh[(size_t)r0 * FD + col] = f2bf(dv0[j] * acc0[j]);
      int r1 = orow1 + j;
      if (r1 < NN) Qh[(size_t)r1 * FD + col] = f2bf(dv1[j] * acc1[j]);
    }
  }
}

// ---------- gather: Ph,Pl = split( relu( dinv[i]*sum_e Qh[src_e] + b ) ) ----------
// 32 lanes/node, full 128-col row (ushort4/lane), 4 edges in flight.
__global__ void k_gather(const int* __restrict__ rowptr, const int* __restrict__ csr_src,
                         const ushort* __restrict__ Qh, const float* __restrict__ b,
                         const float* __restrict__ dinv,
                         ushort* __restrict__ Ph, ushort* __restrict__ Pl) {
  int node = blockIdx.x * 8 + (threadIdx.x >> 5);
  if (node >= NN) return;
  int lane = threadIdx.x & 31;
  const ushort4* __restrict__ Q4 = (const ushort4*)Qh;
  float4 acc = {0.f, 0.f, 0.f, 0.f};
  int e0 = rowptr[node], e1 = rowptr[node + 1];
  int e = e0;
  for (; e + 3 < e1; e += 4) {
    int s0 = csr_src[e], s1 = csr_src[e + 1], s2 = csr_src[e + 2], s3 = csr_src[e + 3];
    ushort4 q0 = Q4[(size_t)s0 * 32 + lane];
    ushort4 q1 = Q4[(size_t)s1 * 32 + lane];
    ushort4 q2 = Q4[(size_t)s2 * 32 + lane];
    ushort4 q3 = Q4[(size_t)s3 * 32 + lane];
    acc.x += (bf2f(q0.x) + bf2f(q1.x)) + (bf2f(q2.x) + bf2f(q3.x));
    acc.y += (bf2f(q0.y) + bf2f(q1.y)) + (bf2f(q2.y) + bf2f(q3.y));
    acc.z += (bf2f(q0.z) + bf2f(q1.z)) + (bf2f(q2.z) + bf2f(q3.z));
    acc.w += (bf2f(q0.w) + bf2f(q1.w)) + (bf2f(q2.w) + bf2f(q3.w));
  }
  for (; e < e1; ++e) {
    int s0 = csr_src[e];
    ushort4 q0 = Q4[(size_t)s0 * 32 + lane];
    acc.x += bf2f(q0.x); acc.y += bf2f(q0.y);
    acc.z += bf2f(q0.z); acc.w += bf2f(q0.w);
  }
  float di = dinv[node];
  float4 bv = ((const float4*)b)[lane];
  acc.x = fmaxf(fmaf(di, acc.x, bv.x), 0.f);
  acc.y = fmaxf(fmaf(di, acc.y, bv.y), 0.f);
  acc.z = fmaxf(fmaf(di, acc.z, bv.z), 0.f);
  acc.w = fmaxf(fmaf(di, acc.w, bv.w), 0.f);
  ushort4 h, l;
  h.x = f2bf(acc.x); l.x = f2bf(acc.x - bf2f(h.x));
  h.y = f2bf(acc.y); l.y = f2bf(acc.y - bf2f(h.y));
  h.z = f2bf(acc.z); l.z = f2bf(acc.z - bf2f(h.z));
  h.w = f2bf(acc.w); l.w = f2bf(acc.w - bf2f(h.w));
  size_t o = (size_t)node * 32 + lane;
  ((ushort4*)Ph)[o] = h;
  ((ushort4*)Pl)[o] = l;
}

// ---------- pooling + head ----------

__global__ void k_zero_pool(float* __restrict__ sums, float* __restrict__ counts) {
  int t = blockIdx.x * 256 + threadIdx.x;
  if (t < NG * FD) sums[t] = 0.f;
  if (t < NG) counts[t] = 0.f;
}

#define POOL_BLOCKS 1024
#define POOL_CHUNK 98
__global__ void k_pool(const int* __restrict__ batch, const ushort* __restrict__ Ph,
                       const ushort* __restrict__ Pl, float* __restrict__ sums,
                       float* __restrict__ counts) {
  int f = threadIdx.x;  // 0..127
  int i0 = blockIdx.x * POOL_CHUNK;
  if (i0 >= NN) return;
  int i1 = i0 + POOL_CHUNK;
  if (i1 > NN) i1 = NN;
  float acc = 0.f;
  int gcur = batch[i0];
  int cnt = 0;
  for (int i = i0; i < i1; ++i) {
    int g = batch[i];
    if (g != gcur) {
      atomicAdd(&sums[gcur * FD + f], acc);
      if (f == 0) atomicAdd(&counts[gcur], (float)cnt);
      acc = 0.f; cnt = 0; gcur = g;
    }
    size_t o = (size_t)i * FD + f;
    acc += bf2f(Ph[o]) + bf2f(Pl[o]);
    ++cnt;
  }
  atomicAdd(&sums[gcur * FD + f], acc);
  if (f == 0) atomicAdd(&counts[gcur], (float)cnt);
}

__global__ void k_head(const float* __restrict__ sums, const float* __restrict__ counts,
                       const float* __restrict__ Wm, const float* __restrict__ bm,
                       float* __restrict__ out) {
  int t = blockIdx.x * 256 + threadIdx.x;
  if (t >= NG * NC) return;
  int g = t / NC, c = t % NC;
  float inv = 1.0f / fmaxf(counts[g], 1.0f);
  float s = 0.f;
#pragma unroll 4
  for (int f = 0; f < FD; ++f) s = fmaf(sums[g * FD + f] * inv, Wm[f * NC + c], s);
  out[t] = s + bm[c];
}

extern "C" void kernel_launch(void* const* d_in, const int* in_sizes, int n_in,
                              void* d_out, int out_size, void* d_ws, size_t ws_size,
                              hipStream_t stream) {
  const float* x     = (const float*)d_in[0];
  const int*   ei    = (const int*)d_in[1];
  const int*   batch = (const int*)d_in[2];
  const float* W_in  = (const float*)d_in[3];
  const float* b_in  = (const float*)d_in[4];
  const float* W_mid = (const float*)d_in[5];
  const float* b_mid = (const float*)d_in[6];
  const float* W_mlp = (const float*)d_in[7];
  const float* b_mlp = (const float*)d_in[8];
  float* out = (float*)d_out;

  const int* src = ei;        // edge_index[0]
  const int* dst = ei + NE;   // edge_index[1]

  char* ws = (char*)d_ws;
  ushort*   Qh      = (ushort*)ws;    ws += (size_t)NN * FD * 2;   // 25.6 MB
  ushort*   Ph      = (ushort*)ws;    ws += (size_t)NN * FD * 2;   // 25.6 MB
  ushort*   Pl      = (ushort*)ws;    ws += (size_t)NN * FD * 2;   // 25.6 MB
  float*    dinv    = (float*)ws;     ws += (size_t)NN * 4;
  int*      rowptr  = (int*)ws;       ws += (size_t)(NN + 1) * 4;
  int*      csr_src = (int*)ws;       ws += (size_t)NT * 4;        // 6.8 MB
  unsigned* binned  = (unsigned*)ws;  ws += (size_t)NE * 4;        // 6.4 MB
  int*      histG   = (int*)ws;       ws += (size_t)NBC2 * 4;      // 400 KB
  int*      boffC   = (int*)ws;       ws += (size_t)(NBC2 + 1) * 4;
  int*      cSums   = (int*)ws;       ws += 256 * 4;
  int*      cOffs   = (int*)ws;       ws += 256 * 4;
  ushort*   WhA     = (ushort*)ws;    ws += (size_t)FD * FD * 2;
  ushort*   WlA     = (ushort*)ws;    ws += (size_t)FD * FD * 2;
  ushort*   WhB     = (ushort*)ws;    ws += (size_t)FD * FD * 2;
  ushort*   WlB     = (ushort*)ws;    ws += (size_t)FD * FD * 2;
  float*    sums    = (float*)ws;     ws += (size_t)NG * FD * 4;
  float*    counts  = (float*)ws;     ws += (size_t)NG * 4;

  // chunked binned CSR build (incl. self-loops; reused by all 4 layers)
  k_hist<<<NCH, 256, 0, stream>>>(dst, histG);
  k_s2A<<<SCB2, 256, 0, stream>>>(histG, cSums);
  k_s2B<<<1, 256, 0, stream>>>(cSums, cOffs, boffC);
  k_s2C<<<SCB2, 256, 0, stream>>>(histG, cOffs, boffC);
  k_chscatter<<<NCH, 256, 0, stream>>>(src, dst, boffC, binned);
  k_csr_bucket<<<NBKT, 256, 0, stream>>>(boffC, binned, rowptr, dinv, csr_src);

  // weight packing + input split
  k_packW<<<(FD * FD + 255) / 256, 256, 0, stream>>>(W_in, WhA, WlA);
  k_packW<<<(FD * FD + 255) / 256, 256, 0, stream>>>(W_mid, WhB, WlB);
  k_split<<<(NN * FD / 4 + 255) / 256, 256, 0, stream>>>(x, Ph, Pl);

  const int gM = (NN + 127) / 128;   // 782 blocks, 128 rows each
  const int gG = (NN + 7) / 8;       // 12500 blocks, 8 nodes each
  for (int L = 0; L < 4; ++L) {
    const ushort* Wh = (L == 0) ? WhA : WhB;
    const ushort* Wl = (L == 0) ? WlA : WlB;
    const float*  b  = (L == 0) ? b_in : b_mid;
    k_gemm_mfma<<<gM, 256, 0, stream>>>(Ph, Pl, Wh, Wl, dinv, Qh);
    k_gather<<<gG, 256, 0, stream>>>(rowptr, csr_src, Qh, b, dinv, Ph, Pl);
  }

  k_zero_pool<<<32, 256, 0, stream>>>(sums, counts);
  k_pool<<<POOL_BLOCKS, 128, 0, stream>>>(batch, Ph, Pl, sums, counts);
  k_head<<<(NG * NC + 255) / 256, 256, 0, stream>>>(sums, counts, W_mlp, b_mlp, out);
}

// Round 13
// 469.570 us; speedup vs baseline: 1.4074x; 1.0668x over previous
//
#include <hip/hip_runtime.h>

#define NN 100000
#define NE 1600000
#define NT (NE + NN)     // edges incl. self-loops
#define FD 128
#define NC 10
#define NG 64

#define NBKT ((NN + 127) >> 7)   // 782 buckets of 128 nodes
#define NCH 128                  // edge chunks
#define CH (NE / NCH)            // 12500 edges per chunk
#define NBC2 (NBKT * NCH)        // 100096 (bucket, chunk) counters
#define SCB2 196                 // 196*512 = 100352 >= NBC2
#define CAP 3072                 // LDS edge cap per bucket (mean 2046, sigma ~45)

typedef __attribute__((ext_vector_type(8))) short short8v;   // 8 bf16 (4 VGPRs)
typedef __attribute__((ext_vector_type(4))) float f32x4;

__device__ inline ushort f2bf(float x) {                     // round-to-nearest-even
  unsigned u = __float_as_uint(x);
  return (ushort)((u + 0x7FFF + ((u >> 16) & 1)) >> 16);
}
__device__ inline float bf2f(ushort h) { return __uint_as_float(((unsigned)h) << 16); }

// ---------- chunked-LDS binned CSR build (no global atomics) ----------

__global__ __launch_bounds__(256) void k_hist(const int* __restrict__ dst,
                                              int* __restrict__ histG) {
  __shared__ int hist[NBKT];
  int tid = threadIdx.x, chunk = blockIdx.x;
  for (int i = tid; i < NBKT; i += 256) hist[i] = 0;
  __syncthreads();
  int e0 = chunk * CH;
  for (int i = tid; i < CH; i += 256)
    atomicAdd(&hist[dst[e0 + i] >> 7], 1);
  __syncthreads();
  for (int i = tid; i < NBKT; i += 256) histG[i * NCH + chunk] = hist[i];
}

__global__ void k_s2A(const int* __restrict__ cnt, int* __restrict__ blockSums) {
  __shared__ int red[256];
  int t = threadIdx.x, b = blockIdx.x;
  int i0 = b * 512 + t * 2;
  int s = 0;
#pragma unroll
  for (int j = 0; j < 2; ++j) { int i = i0 + j; if (i < NBC2) s += cnt[i]; }
  red[t] = s;
  __syncthreads();
  for (int off = 128; off > 0; off >>= 1) {
    if (t < off) red[t] += red[t + off];
    __syncthreads();
  }
  if (t == 0) blockSums[b] = red[0];
}

__global__ void k_s2B(const int* __restrict__ blockSums, int* __restrict__ blockOffs,
                      int* __restrict__ boffC) {
  __shared__ int sh[256];
  int t = threadIdx.x;
  int v = (t < SCB2) ? blockSums[t] : 0;
  sh[t] = v;
  __syncthreads();
  for (int off = 1; off < 256; off <<= 1) {
    int u = (t >= off) ? sh[t - off] : 0;
    __syncthreads();
    sh[t] += u;
    __syncthreads();
  }
  if (t < SCB2) blockOffs[t] = sh[t] - v;   // exclusive
  if (t == 255) boffC[NBC2] = sh[255];      // = NE
}

__global__ void k_s2C(const int* __restrict__ cnt, const int* __restrict__ blockOffs,
                      int* __restrict__ boffC) {
  __shared__ int sh[256];
  int t = threadIdx.x, b = blockIdx.x;
  int i0 = b * 512 + t * 2;
  int c[2];
  int s = 0;
#pragma unroll
  for (int j = 0; j < 2; ++j) {
    int i = i0 + j;
    c[j] = (i < NBC2) ? cnt[i] : 0;
    s += c[j];
  }
  sh[t] = s;
  __syncthreads();
  for (int off = 1; off < 256; off <<= 1) {
    int u = (t >= off) ? sh[t - off] : 0;
    __syncthreads();
    sh[t] += u;
    __syncthreads();
  }
  int run = blockOffs[b] + sh[t] - s;
#pragma unroll
  for (int j = 0; j < 2; ++j) {
    int i = i0 + j;
    if (i < NBC2) { boffC[i] = run; run += c[j]; }
  }
}

__global__ __launch_bounds__(256) void k_chscatter(const int* __restrict__ src,
                                                   const int* __restrict__ dst,
                                                   const int* __restrict__ boffC,
                                                   unsigned* __restrict__ binned) {
  __shared__ int curs[NBKT];
  int tid = threadIdx.x, chunk = blockIdx.x;
  for (int i = tid; i < NBKT; i += 256) curs[i] = boffC[i * NCH + chunk];
  __syncthreads();
  int e0 = chunk * CH;
  for (int i = tid; i < CH; i += 256) {
    int e = e0 + i;
    int d = dst[e], s = src[e];
    int slot = atomicAdd(&curs[d >> 7], 1);
    binned[slot] = ((unsigned)(d & 127) << 17) | (unsigned)s;
  }
}

__global__ __launch_bounds__(256) void k_csr_bucket(
    const int* __restrict__ boffC, const unsigned* __restrict__ binned,
    int* __restrict__ rowptr, float* __restrict__ dinv, int* __restrict__ csr_src) {
  __shared__ unsigned varr[CAP];
  __shared__ int earr[CAP + 128];
  __shared__ int deg[128];
  __shared__ int sh[128];
  int b = blockIdx.x, tid = threadIdx.x;
  int e0 = boffC[b * NCH], e1 = boffC[(b + 1) * NCH], seg = e1 - e0;
  int n0 = b << 7;
  int nb = NN - n0; if (nb > 128) nb = 128;
  int gbase = e0 + n0;                      // + one self per preceding node
  if (tid < 128) deg[tid] = 0;
  __syncthreads();
  bool fast = (seg <= CAP);
  if (fast) {
    for (int i = tid; i < seg; i += 256) {
      unsigned v = binned[e0 + i];
      varr[i] = v;
      atomicAdd(&deg[(v >> 17) & 127], 1);
    }
  } else {
    for (int i = tid; i < seg; i += 256) {
      unsigned v = binned[e0 + i];
      atomicAdd(&deg[(v >> 17) & 127], 1);
    }
  }
  __syncthreads();
  int dl = 0;
  if (tid < 128) {
    dl = (tid < nb) ? deg[tid] + 1 : 0;     // +1 self-loop
    sh[tid] = dl;
  }
  __syncthreads();
  for (int off = 1; off < 128; off <<= 1) {
    int u = 0;
    if (tid < 128 && tid >= off) u = sh[tid - off];
    __syncthreads();
    if (tid < 128) sh[tid] += u;
    __syncthreads();
  }
  int excl = 0;
  if (tid < nb) {
    excl = sh[tid] - dl;
    rowptr[n0 + tid] = gbase + excl;
    dinv[n0 + tid] = rsqrtf((float)dl);
    if (fast) earr[excl] = n0 + tid;        // self-loop in first slot
    else      csr_src[gbase + excl] = n0 + tid;
  }
  __syncthreads();
  if (tid < 128) deg[tid] = (tid < nb) ? (excl + 1) : 0;   // cursor after self
  __syncthreads();
  if (fast) {
    for (int i = tid; i < seg; i += 256) {
      unsigned v = varr[i];
      int l = (v >> 17) & 127;
      int pos = atomicAdd(&deg[l], 1);
      earr[pos] = (int)(v & 0x1FFFF);
    }
    __syncthreads();
    int tot = seg + nb;
    for (int i = tid; i < tot; i += 256) csr_src[gbase + i] = earr[i];
  } else {
    for (int i = tid; i < seg; i += 256) {
      unsigned v = binned[e0 + i];
      int l = (v >> 17) & 127;
      int pos = atomicAdd(&deg[l], 1);
      csr_src[gbase + pos] = (int)(v & 0x1FFFF);
    }
  }
  if (b == 0 && tid == 0) rowptr[NN] = NT;
}

// ---------- prep: x -> bf16, W -> packed split hi/lo ----------

__global__ void k_cvt(const float* __restrict__ X, ushort* __restrict__ Hh) {
  int t = blockIdx.x * 256 + threadIdx.x;
  if (t >= NN * FD / 4) return;
  float4 v = ((const float4*)X)[t];
  ushort4 h;
  h.x = f2bf(v.x); h.y = f2bf(v.y); h.z = f2bf(v.z); h.w = f2bf(v.w);
  ((ushort4*)Hh)[t] = h;
}

// Pack W[k][col] into MFMA B-fragment order, split hi/lo (weight split kept:
// W error is systematic across nodes and would NOT average out in pooling):
// packed[(((k>>5)*128 + col)*4 + ((k>>3)&3))*8 + (k&7)]
__global__ void k_packW(const float* __restrict__ W, ushort* __restrict__ Wh,
                        ushort* __restrict__ Wl) {
  int idx = blockIdx.x * 256 + threadIdx.x;
  if (idx >= FD * FD) return;
  int k = idx >> 7, col = idx & 127;
  float v = W[idx];
  ushort h = f2bf(v);
  ushort l = f2bf(v - bf2f(h));
  size_t o = ((((size_t)(k >> 5)) * 128 + col) * 4 + ((k >> 3) & 3)) * 8 + (k & 7);
  Wh[o] = h; Wl[o] = l;
}

// ---------- MFMA GEMM: Qh = bf16( dinv[row] * (Ah@(Wh+Wl)) ) ----------
// bf16 activations (Al dropped); 32 rows/wave; 2 MFMAs per (nt,kc).
__global__ __launch_bounds__(256, 4) void k_gemm_mfma(
    const ushort* __restrict__ Ah,
    const ushort* __restrict__ Bh, const ushort* __restrict__ Bl,
    const float* __restrict__ dinv, ushort* __restrict__ Qh) {
  int tid = threadIdx.x;
  int wave = tid >> 6, lane = tid & 63;
  int m15 = lane & 15, k0 = lane >> 4;
  int row0 = blockIdx.x * 128 + wave * 32;

  int ar0 = row0 + m15;      if (ar0 >= NN) ar0 = NN - 1;
  int ar1 = row0 + 16 + m15; if (ar1 >= NN) ar1 = NN - 1;
  short8v ah0[4], ah1[4];
#pragma unroll
  for (int kc = 0; kc < 4; ++kc) {
    size_t o0 = (size_t)ar0 * FD + kc * 32 + k0 * 8;
    size_t o1 = (size_t)ar1 * FD + kc * 32 + k0 * 8;
    ah0[kc] = *(const short8v*)(Ah + o0);
    ah1[kc] = *(const short8v*)(Ah + o1);
  }

  int orow0 = row0 + k0 * 4;
  int orow1 = row0 + 16 + k0 * 4;
  float dv0[4], dv1[4];
#pragma unroll
  for (int j = 0; j < 4; ++j) {
    int r0 = orow0 + j; dv0[j] = (r0 < NN) ? dinv[r0] : 0.f;
    int r1 = orow1 + j; dv1[j] = (r1 < NN) ? dinv[r1] : 0.f;
  }

#pragma unroll
  for (int nt = 0; nt < 8; ++nt) {
    int col = nt * 16 + m15;
    f32x4 acc0 = {0.f, 0.f, 0.f, 0.f};
    f32x4 acc1 = {0.f, 0.f, 0.f, 0.f};
#pragma unroll
    for (int kc = 0; kc < 4; ++kc) {
      size_t off = (((size_t)kc * 128 + col) * 4 + k0) * 8;
      short8v bh = *(const short8v*)(Bh + off);
      short8v bl = *(const short8v*)(Bl + off);
      acc0 = __builtin_amdgcn_mfma_f32_16x16x32_bf16(ah0[kc], bh, acc0, 0, 0, 0);
      acc1 = __builtin_amdgcn_mfma_f32_16x16x32_bf16(ah1[kc], bh, acc1, 0, 0, 0);
      acc0 = __builtin_amdgcn_mfma_f32_16x16x32_bf16(ah0[kc], bl, acc0, 0, 0, 0);
      acc1 = __builtin_amdgcn_mfma_f32_16x16x32_bf16(ah1[kc], bl, acc1, 0, 0, 0);
    }
#pragma unroll
    for (int j = 0; j < 4; ++j) {
      int r0 = orow0 + j;
      if (r0 < NN) Qh[(size_t)r0 * FD + col] = f2bf(dv0[j] * acc0[j]);
      int r1 = orow1 + j;
      if (r1 < NN) Qh[(size_t)r1 * FD + col] = f2bf(dv1[j] * acc1[j]);
    }
  }
}

// ---------- gather: Ph = bf16( relu( dinv[i]*sum_e Qh[src_e] + b ) ) ----------
// 32 lanes/node, full 128-col row (ushort4/lane), 4 edges in flight.
__global__ void k_gather(const int* __restrict__ rowptr, const int* __restrict__ csr_src,
                         const ushort* __restrict__ Qh, const float* __restrict__ b,
                         const float* __restrict__ dinv, ushort* __restrict__ Ph) {
  int node = blockIdx.x * 8 + (threadIdx.x >> 5);
  if (node >= NN) return;
  int lane = threadIdx.x & 31;
  const ushort4* __restrict__ Q4 = (const ushort4*)Qh;
  float4 acc = {0.f, 0.f, 0.f, 0.f};
  int e0 = rowptr[node], e1 = rowptr[node + 1];
  int e = e0;
  for (; e + 3 < e1; e += 4) {
    int s0 = csr_src[e], s1 = csr_src[e + 1], s2 = csr_src[e + 2], s3 = csr_src[e + 3];
    ushort4 q0 = Q4[(size_t)s0 * 32 + lane];
    ushort4 q1 = Q4[(size_t)s1 * 32 + lane];
    ushort4 q2 = Q4[(size_t)s2 * 32 + lane];
    ushort4 q3 = Q4[(size_t)s3 * 32 + lane];
    acc.x += (bf2f(q0.x) + bf2f(q1.x)) + (bf2f(q2.x) + bf2f(q3.x));
    acc.y += (bf2f(q0.y) + bf2f(q1.y)) + (bf2f(q2.y) + bf2f(q3.y));
    acc.z += (bf2f(q0.z) + bf2f(q1.z)) + (bf2f(q2.z) + bf2f(q3.z));
    acc.w += (bf2f(q0.w) + bf2f(q1.w)) + (bf2f(q2.w) + bf2f(q3.w));
  }
  for (; e < e1; ++e) {
    int s0 = csr_src[e];
    ushort4 q0 = Q4[(size_t)s0 * 32 + lane];
    acc.x += bf2f(q0.x); acc.y += bf2f(q0.y);
    acc.z += bf2f(q0.z); acc.w += bf2f(q0.w);
  }
  float di = dinv[node];
  float4 bv = ((const float4*)b)[lane];
  acc.x = fmaxf(fmaf(di, acc.x, bv.x), 0.f);
  acc.y = fmaxf(fmaf(di, acc.y, bv.y), 0.f);
  acc.z = fmaxf(fmaf(di, acc.z, bv.z), 0.f);
  acc.w = fmaxf(fmaf(di, acc.w, bv.w), 0.f);
  ushort4 h;
  h.x = f2bf(acc.x); h.y = f2bf(acc.y); h.z = f2bf(acc.z); h.w = f2bf(acc.w);
  ((ushort4*)Ph)[(size_t)node * 32 + lane] = h;
}

// ---------- pooling + head ----------

__global__ void k_zero_pool(float* __restrict__ sums, float* __restrict__ counts) {
  int t = blockIdx.x * 256 + threadIdx.x;
  if (t < NG * FD) sums[t] = 0.f;
  if (t < NG) counts[t] = 0.f;
}

#define POOL_BLOCKS 1024
#define POOL_CHUNK 98
__global__ void k_pool(const int* __restrict__ batch, const ushort* __restrict__ Ph,
                       float* __restrict__ sums, float* __restrict__ counts) {
  int f = threadIdx.x;  // 0..127
  int i0 = blockIdx.x * POOL_CHUNK;
  if (i0 >= NN) return;
  int i1 = i0 + POOL_CHUNK;
  if (i1 > NN) i1 = NN;
  float acc = 0.f;
  int gcur = batch[i0];
  int cnt = 0;
  for (int i = i0; i < i1; ++i) {
    int g = batch[i];
    if (g != gcur) {
      atomicAdd(&sums[gcur * FD + f], acc);
      if (f == 0) atomicAdd(&counts[gcur], (float)cnt);
      acc = 0.f; cnt = 0; gcur = g;
    }
    acc += bf2f(Ph[(size_t)i * FD + f]);
    ++cnt;
  }
  atomicAdd(&sums[gcur * FD + f], acc);
  if (f == 0) atomicAdd(&counts[gcur], (float)cnt);
}

__global__ void k_head(const float* __restrict__ sums, const float* __restrict__ counts,
                       const float* __restrict__ Wm, const float* __restrict__ bm,
                       float* __restrict__ out) {
  int t = blockIdx.x * 256 + threadIdx.x;
  if (t >= NG * NC) return;
  int g = t / NC, c = t % NC;
  float inv = 1.0f / fmaxf(counts[g], 1.0f);
  float s = 0.f;
#pragma unroll 4
  for (int f = 0; f < FD; ++f) s = fmaf(sums[g * FD + f] * inv, Wm[f * NC + c], s);
  out[t] = s + bm[c];
}

extern "C" void kernel_launch(void* const* d_in, const int* in_sizes, int n_in,
                              void* d_out, int out_size, void* d_ws, size_t ws_size,
                              hipStream_t stream) {
  const float* x     = (const float*)d_in[0];
  const int*   ei    = (const int*)d_in[1];
  const int*   batch = (const int*)d_in[2];
  const float* W_in  = (const float*)d_in[3];
  const float* b_in  = (const float*)d_in[4];
  const float* W_mid = (const float*)d_in[5];
  const float* b_mid = (const float*)d_in[6];
  const float* W_mlp = (const float*)d_in[7];
  const float* b_mlp = (const float*)d_in[8];
  float* out = (float*)d_out;

  const int* src = ei;        // edge_index[0]
  const int* dst = ei + NE;   // edge_index[1]

  char* ws = (char*)d_ws;
  ushort*   Qh      = (ushort*)ws;    ws += (size_t)NN * FD * 2;   // 25.6 MB
  ushort*   Ph      = (ushort*)ws;    ws += (size_t)NN * FD * 2;   // 25.6 MB
  float*    dinv    = (float*)ws;     ws += (size_t)NN * 4;
  int*      rowptr  = (int*)ws;       ws += (size_t)(NN + 1) * 4;
  int*      csr_src = (int*)ws;       ws += (size_t)NT * 4;        // 6.8 MB
  unsigned* binned  = (unsigned*)ws;  ws += (size_t)NE * 4;        // 6.4 MB
  int*      histG   = (int*)ws;       ws += (size_t)NBC2 * 4;      // 400 KB
  int*      boffC   = (int*)ws;       ws += (size_t)(NBC2 + 1) * 4;
  int*      cSums   = (int*)ws;       ws += 256 * 4;
  int*      cOffs   = (int*)ws;       ws += 256 * 4;
  ushort*   WhA     = (ushort*)ws;    ws += (size_t)FD * FD * 2;
  ushort*   WlA     = (ushort*)ws;    ws += (size_t)FD * FD * 2;
  ushort*   WhB     = (ushort*)ws;    ws += (size_t)FD * FD * 2;
  ushort*   WlB     = (ushort*)ws;    ws += (size_t)FD * FD * 2;
  float*    sums    = (float*)ws;     ws += (size_t)NG * FD * 4;
  float*    counts  = (float*)ws;     ws += (size_t)NG * 4;

  // chunked binned CSR build (incl. self-loops; reused by all 4 layers)
  k_hist<<<NCH, 256, 0, stream>>>(dst, histG);
  k_s2A<<<SCB2, 256, 0, stream>>>(histG, cSums);
  k_s2B<<<1, 256, 0, stream>>>(cSums, cOffs, boffC);
  k_s2C<<<SCB2, 256, 0, stream>>>(histG, cOffs, boffC);
  k_chscatter<<<NCH, 256, 0, stream>>>(src, dst, boffC, binned);
  k_csr_bucket<<<NBKT, 256, 0, stream>>>(boffC, binned, rowptr, dinv, csr_src);

  // weight packing + input conversion
  k_packW<<<(FD * FD + 255) / 256, 256, 0, stream>>>(W_in, WhA, WlA);
  k_packW<<<(FD * FD + 255) / 256, 256, 0, stream>>>(W_mid, WhB, WlB);
  k_cvt<<<(NN * FD / 4 + 255) / 256, 256, 0, stream>>>(x, Ph);

  const int gM = (NN + 127) / 128;   // 782 blocks, 128 rows each
  const int gG = (NN + 7) / 8;       // 12500 blocks, 8 nodes each
  for (int L = 0; L < 4; ++L) {
    const ushort* Wh = (L == 0) ? WhA : WhB;
    const ushort* Wl = (L == 0) ? WlA : WlB;
    const float*  b  = (L == 0) ? b_in : b_mid;
    k_gemm_mfma<<<gM, 256, 0, stream>>>(Ph, Wh, Wl, dinv, Qh);
    k_gather<<<gG, 256, 0, stream>>>(rowptr, csr_src, Qh, b, dinv, Ph);
  }

  k_zero_pool<<<32, 256, 0, stream>>>(sums, counts);
  k_pool<<<POOL_BLOCKS, 128, 0, stream>>>(batch, Ph, sums, counts);
  k_head<<<(NG * NC + 255) / 256, 256, 0, stream>>>(sums, counts, W_mlp, b_mlp, out);
}

// Round 14
// 423.920 us; speedup vs baseline: 1.5590x; 1.1077x over previous
//
#include <hip/hip_runtime.h>

#define NN 100000
#define NE 1600000
#define NT (NE + NN)     // edges incl. self-loops
#define FD 128
#define NC 10
#define NG 64

#define NBKT ((NN + 127) >> 7)   // 782 buckets of 128 nodes
#define NCH 128                  // edge chunks
#define CH (NE / NCH)            // 12500 edges per chunk
#define NBC2 (NBKT * NCH)        // 100096 (bucket, chunk) counters
#define SCB2 196                 // 196*512 = 100352 >= NBC2
#define CAP 3072                 // LDS edge cap per bucket (mean 2046, sigma ~45)

typedef __attribute__((ext_vector_type(8))) short short8v;   // 8 bf16 (4 VGPRs)
typedef __attribute__((ext_vector_type(4))) float f32x4;
typedef _Float16 half2v __attribute__((ext_vector_type(2)));

__device__ inline ushort f2bf(float x) {                     // round-to-nearest-even
  unsigned u = __float_as_uint(x);
  return (ushort)((u + 0x7FFF + ((u >> 16) & 1)) >> 16);
}
__device__ inline float bf2f(ushort h) { return __uint_as_float(((unsigned)h) << 16); }

// f32 -> e4m3fn byte (via f16 at 2^-8 scale; RN to 3-bit mantissa; f16 denorm = e4m3 denorm)
__device__ inline unsigned char f2e4m3(float x) {
  x = fminf(fmaxf(x, -448.f), 448.f);
  _Float16 hf = (_Float16)(x * 0.00390625f);
  unsigned short b = __builtin_bit_cast(unsigned short, hf);
  unsigned short r = (unsigned short)((b & 0x7fff) + 0x3F + ((b >> 7) & 1));
  return (unsigned char)(((r >> 7) & 0x7f) | ((b >> 8) & 0x80));
}

// 4 e4m3 bytes (one u32) -> 4 f32.  dec(b) = f16((b&0x7f)<<7 | s<<15) * 2^8
__device__ inline void e4m3x4(unsigned v, float* f) {
  unsigned p0 = __builtin_amdgcn_perm(0u, v, 0x010c000cu);   // [0,b0,0,b1]
  unsigned p1 = __builtin_amdgcn_perm(0u, v, 0x030c020cu);   // [0,b2,0,b3]
  p0 = ((p0 >> 1) & 0x3f803f80u) | (p0 & 0x80008000u);
  p1 = ((p1 >> 1) & 0x3f803f80u) | (p1 & 0x80008000u);
  half2v h0 = __builtin_bit_cast(half2v, p0);
  half2v h1 = __builtin_bit_cast(half2v, p1);
  half2v s = {(_Float16)256.0f, (_Float16)256.0f};
  h0 *= s; h1 *= s;
  f[0] = (float)h0[0]; f[1] = (float)h0[1];
  f[2] = (float)h1[0]; f[3] = (float)h1[1];
}

// ---------- chunked-LDS binned CSR build (no global atomics) ----------

__global__ __launch_bounds__(256) void k_hist(const int* __restrict__ dst,
                                              int* __restrict__ histG) {
  __shared__ int hist[NBKT];
  int tid = threadIdx.x, chunk = blockIdx.x;
  for (int i = tid; i < NBKT; i += 256) hist[i] = 0;
  __syncthreads();
  int e0 = chunk * CH;
  for (int i = tid; i < CH; i += 256)
    atomicAdd(&hist[dst[e0 + i] >> 7], 1);
  __syncthreads();
  for (int i = tid; i < NBKT; i += 256) histG[i * NCH + chunk] = hist[i];
}

__global__ void k_s2A(const int* __restrict__ cnt, int* __restrict__ blockSums) {
  __shared__ int red[256];
  int t = threadIdx.x, b = blockIdx.x;
  int i0 = b * 512 + t * 2;
  int s = 0;
#pragma unroll
  for (int j = 0; j < 2; ++j) { int i = i0 + j; if (i < NBC2) s += cnt[i]; }
  red[t] = s;
  __syncthreads();
  for (int off = 128; off > 0; off >>= 1) {
    if (t < off) red[t] += red[t + off];
    __syncthreads();
  }
  if (t == 0) blockSums[b] = red[0];
}

__global__ void k_s2B(const int* __restrict__ blockSums, int* __restrict__ blockOffs,
                      int* __restrict__ boffC) {
  __shared__ int sh[256];
  int t = threadIdx.x;
  int v = (t < SCB2) ? blockSums[t] : 0;
  sh[t] = v;
  __syncthreads();
  for (int off = 1; off < 256; off <<= 1) {
    int u = (t >= off) ? sh[t - off] : 0;
    __syncthreads();
    sh[t] += u;
    __syncthreads();
  }
  if (t < SCB2) blockOffs[t] = sh[t] - v;   // exclusive
  if (t == 255) boffC[NBC2] = sh[255];      // = NE
}

__global__ void k_s2C(const int* __restrict__ cnt, const int* __restrict__ blockOffs,
                      int* __restrict__ boffC) {
  __shared__ int sh[256];
  int t = threadIdx.x, b = blockIdx.x;
  int i0 = b * 512 + t * 2;
  int c[2];
  int s = 0;
#pragma unroll
  for (int j = 0; j < 2; ++j) {
    int i = i0 + j;
    c[j] = (i < NBC2) ? cnt[i] : 0;
    s += c[j];
  }
  sh[t] = s;
  __syncthreads();
  for (int off = 1; off < 256; off <<= 1) {
    int u = (t >= off) ? sh[t - off] : 0;
    __syncthreads();
    sh[t] += u;
    __syncthreads();
  }
  int run = blockOffs[b] + sh[t] - s;
#pragma unroll
  for (int j = 0; j < 2; ++j) {
    int i = i0 + j;
    if (i < NBC2) { boffC[i] = run; run += c[j]; }
  }
}

__global__ __launch_bounds__(256) void k_chscatter(const int* __restrict__ src,
                                                   const int* __restrict__ dst,
                                                   const int* __restrict__ boffC,
                                                   unsigned* __restrict__ binned) {
  __shared__ int curs[NBKT];
  int tid = threadIdx.x, chunk = blockIdx.x;
  for (int i = tid; i < NBKT; i += 256) curs[i] = boffC[i * NCH + chunk];
  __syncthreads();
  int e0 = chunk * CH;
  for (int i = tid; i < CH; i += 256) {
    int e = e0 + i;
    int d = dst[e], s = src[e];
    int slot = atomicAdd(&curs[d >> 7], 1);
    binned[slot] = ((unsigned)(d & 127) << 17) | (unsigned)s;
  }
}

__global__ __launch_bounds__(256) void k_csr_bucket(
    const int* __restrict__ boffC, const unsigned* __restrict__ binned,
    int* __restrict__ rowptr, float* __restrict__ dinv, int* __restrict__ csr_src) {
  __shared__ unsigned varr[CAP];
  __shared__ int earr[CAP + 128];
  __shared__ int deg[128];
  __shared__ int sh[128];
  int b = blockIdx.x, tid = threadIdx.x;
  int e0 = boffC[b * NCH], e1 = boffC[(b + 1) * NCH], seg = e1 - e0;
  int n0 = b << 7;
  int nb = NN - n0; if (nb > 128) nb = 128;
  int gbase = e0 + n0;                      // + one self per preceding node
  if (tid < 128) deg[tid] = 0;
  __syncthreads();
  bool fast = (seg <= CAP);
  if (fast) {
    for (int i = tid; i < seg; i += 256) {
      unsigned v = binned[e0 + i];
      varr[i] = v;
      atomicAdd(&deg[(v >> 17) & 127], 1);
    }
  } else {
    for (int i = tid; i < seg; i += 256) {
      unsigned v = binned[e0 + i];
      atomicAdd(&deg[(v >> 17) & 127], 1);
    }
  }
  __syncthreads();
  int dl = 0;
  if (tid < 128) {
    dl = (tid < nb) ? deg[tid] + 1 : 0;     // +1 self-loop
    sh[tid] = dl;
  }
  __syncthreads();
  for (int off = 1; off < 128; off <<= 1) {
    int u = 0;
    if (tid < 128 && tid >= off) u = sh[tid - off];
    __syncthreads();
    if (tid < 128) sh[tid] += u;
    __syncthreads();
  }
  int excl = 0;
  if (tid < nb) {
    excl = sh[tid] - dl;
    rowptr[n0 + tid] = gbase + excl;
    dinv[n0 + tid] = rsqrtf((float)dl);
    if (fast) earr[excl] = n0 + tid;        // self-loop in first slot
    else      csr_src[gbase + excl] = n0 + tid;
  }
  __syncthreads();
  if (tid < 128) deg[tid] = (tid < nb) ? (excl + 1) : 0;   // cursor after self
  __syncthreads();
  if (fast) {
    for (int i = tid; i < seg; i += 256) {
      unsigned v = varr[i];
      int l = (v >> 17) & 127;
      int pos = atomicAdd(&deg[l], 1);
      earr[pos] = (int)(v & 0x1FFFF);
    }
    __syncthreads();
    int tot = seg + nb;
    for (int i = tid; i < tot; i += 256) csr_src[gbase + i] = earr[i];
  } else {
    for (int i = tid; i < seg; i += 256) {
      unsigned v = binned[e0 + i];
      int l = (v >> 17) & 127;
      int pos = atomicAdd(&deg[l], 1);
      csr_src[gbase + pos] = (int)(v & 0x1FFFF);
    }
  }
  if (b == 0 && tid == 0) rowptr[NN] = NT;
}

// ---------- prep: x -> bf16, W -> packed split hi/lo ----------

__global__ void k_cvt(const float* __restrict__ X, ushort* __restrict__ Hh) {
  int t = blockIdx.x * 256 + threadIdx.x;
  if (t >= NN * FD / 4) return;
  float4 v = ((const float4*)X)[t];
  ushort4 h;
  h.x = f2bf(v.x); h.y = f2bf(v.y); h.z = f2bf(v.z); h.w = f2bf(v.w);
  ((ushort4*)Hh)[t] = h;
}

// Pack W[k][col] into MFMA B-fragment order, split hi/lo (weight split kept:
// W error is systematic across nodes and would NOT average out in pooling):
// packed[(((k>>5)*128 + col)*4 + ((k>>3)&3))*8 + (k&7)]
__global__ void k_packW(const float* __restrict__ W, ushort* __restrict__ Wh,
                        ushort* __restrict__ Wl) {
  int idx = blockIdx.x * 256 + threadIdx.x;
  if (idx >= FD * FD) return;
  int k = idx >> 7, col = idx & 127;
  float v = W[idx];
  ushort h = f2bf(v);
  ushort l = f2bf(v - bf2f(h));
  size_t o = ((((size_t)(k >> 5)) * 128 + col) * 4 + ((k >> 3) & 3)) * 8 + (k & 7);
  Wh[o] = h; Wl[o] = l;
}

// ---------- MFMA GEMM: Qf8 = e4m3( dinv[row] * (Ah@(Wh+Wl)) ) ----------
// bf16 activations in; fp8 aggregation operand out (halves gather footprint).
__global__ __launch_bounds__(256, 4) void k_gemm_mfma(
    const ushort* __restrict__ Ah,
    const ushort* __restrict__ Bh, const ushort* __restrict__ Bl,
    const float* __restrict__ dinv, unsigned char* __restrict__ Qf8) {
  int tid = threadIdx.x;
  int wave = tid >> 6, lane = tid & 63;
  int m15 = lane & 15, k0 = lane >> 4;
  int row0 = blockIdx.x * 128 + wave * 32;

  int ar0 = row0 + m15;      if (ar0 >= NN) ar0 = NN - 1;
  int ar1 = row0 + 16 + m15; if (ar1 >= NN) ar1 = NN - 1;
  short8v ah0[4], ah1[4];
#pragma unroll
  for (int kc = 0; kc < 4; ++kc) {
    size_t o0 = (size_t)ar0 * FD + kc * 32 + k0 * 8;
    size_t o1 = (size_t)ar1 * FD + kc * 32 + k0 * 8;
    ah0[kc] = *(const short8v*)(Ah + o0);
    ah1[kc] = *(const short8v*)(Ah + o1);
  }

  int orow0 = row0 + k0 * 4;
  int orow1 = row0 + 16 + k0 * 4;
  float dv0[4], dv1[4];
#pragma unroll
  for (int j = 0; j < 4; ++j) {
    int r0 = orow0 + j; dv0[j] = (r0 < NN) ? dinv[r0] : 0.f;
    int r1 = orow1 + j; dv1[j] = (r1 < NN) ? dinv[r1] : 0.f;
  }

#pragma unroll
  for (int nt = 0; nt < 8; ++nt) {
    int col = nt * 16 + m15;
    f32x4 acc0 = {0.f, 0.f, 0.f, 0.f};
    f32x4 acc1 = {0.f, 0.f, 0.f, 0.f};
#pragma unroll
    for (int kc = 0; kc < 4; ++kc) {
      size_t off = (((size_t)kc * 128 + col) * 4 + k0) * 8;
      short8v bh = *(const short8v*)(Bh + off);
      short8v bl = *(const short8v*)(Bl + off);
      acc0 = __builtin_amdgcn_mfma_f32_16x16x32_bf16(ah0[kc], bh, acc0, 0, 0, 0);
      acc1 = __builtin_amdgcn_mfma_f32_16x16x32_bf16(ah1[kc], bh, acc1, 0, 0, 0);
      acc0 = __builtin_amdgcn_mfma_f32_16x16x32_bf16(ah0[kc], bl, acc0, 0, 0, 0);
      acc1 = __builtin_amdgcn_mfma_f32_16x16x32_bf16(ah1[kc], bl, acc1, 0, 0, 0);
    }
#pragma unroll
    for (int j = 0; j < 4; ++j) {
      int r0 = orow0 + j;
      if (r0 < NN) Qf8[(size_t)r0 * FD + col] = f2e4m3(dv0[j] * acc0[j]);
      int r1 = orow1 + j;
      if (r1 < NN) Qf8[(size_t)r1 * FD + col] = f2e4m3(dv1[j] * acc1[j]);
    }
  }
}

// ---------- gather: Ph = bf16( relu( dinv[i]*sum_e Qf8[src_e] + b ) ) ----------
// 32 lanes/node, 128B fp8 row (u32/lane), 4 edges in flight.
__global__ void k_gather(const int* __restrict__ rowptr, const int* __restrict__ csr_src,
                         const unsigned char* __restrict__ Qf8,
                         const float* __restrict__ b,
                         const float* __restrict__ dinv, ushort* __restrict__ Ph) {
  int node = blockIdx.x * 8 + (threadIdx.x >> 5);
  if (node >= NN) return;
  int lane = threadIdx.x & 31;
  const unsigned* __restrict__ Q4 = (const unsigned*)Qf8;
  float4 acc = {0.f, 0.f, 0.f, 0.f};
  int e0 = rowptr[node], e1 = rowptr[node + 1];
  int e = e0;
  for (; e + 3 < e1; e += 4) {
    int s0 = csr_src[e], s1 = csr_src[e + 1], s2 = csr_src[e + 2], s3 = csr_src[e + 3];
    unsigned q0 = Q4[(size_t)s0 * 32 + lane];
    unsigned q1 = Q4[(size_t)s1 * 32 + lane];
    unsigned q2 = Q4[(size_t)s2 * 32 + lane];
    unsigned q3 = Q4[(size_t)s3 * 32 + lane];
    float f0[4], f1[4], f2[4], f3[4];
    e4m3x4(q0, f0); e4m3x4(q1, f1); e4m3x4(q2, f2); e4m3x4(q3, f3);
    acc.x += (f0[0] + f1[0]) + (f2[0] + f3[0]);
    acc.y += (f0[1] + f1[1]) + (f2[1] + f3[1]);
    acc.z += (f0[2] + f1[2]) + (f2[2] + f3[2]);
    acc.w += (f0[3] + f1[3]) + (f2[3] + f3[3]);
  }
  for (; e < e1; ++e) {
    int s0 = csr_src[e];
    unsigned q0 = Q4[(size_t)s0 * 32 + lane];
    float f0[4];
    e4m3x4(q0, f0);
    acc.x += f0[0]; acc.y += f0[1]; acc.z += f0[2]; acc.w += f0[3];
  }
  float di = dinv[node];
  float4 bv = ((const float4*)b)[lane];
  acc.x = fmaxf(fmaf(di, acc.x, bv.x), 0.f);
  acc.y = fmaxf(fmaf(di, acc.y, bv.y), 0.f);
  acc.z = fmaxf(fmaf(di, acc.z, bv.z), 0.f);
  acc.w = fmaxf(fmaf(di, acc.w, bv.w), 0.f);
  ushort4 h;
  h.x = f2bf(acc.x); h.y = f2bf(acc.y); h.z = f2bf(acc.z); h.w = f2bf(acc.w);
  ((ushort4*)Ph)[(size_t)node * 32 + lane] = h;
}

// ---------- pooling + head ----------

__global__ void k_zero_pool(float* __restrict__ sums, float* __restrict__ counts) {
  int t = blockIdx.x * 256 + threadIdx.x;
  if (t < NG * FD) sums[t] = 0.f;
  if (t < NG) counts[t] = 0.f;
}

#define POOL_BLOCKS 1024
#define POOL_CHUNK 98
__global__ void k_pool(const int* __restrict__ batch, const ushort* __restrict__ Ph,
                       float* __restrict__ sums, float* __restrict__ counts) {
  int f = threadIdx.x;  // 0..127
  int i0 = blockIdx.x * POOL_CHUNK;
  if (i0 >= NN) return;
  int i1 = i0 + POOL_CHUNK;
  if (i1 > NN) i1 = NN;
  float acc = 0.f;
  int gcur = batch[i0];
  int cnt = 0;
  for (int i = i0; i < i1; ++i) {
    int g = batch[i];
    if (g != gcur) {
      atomicAdd(&sums[gcur * FD + f], acc);
      if (f == 0) atomicAdd(&counts[gcur], (float)cnt);
      acc = 0.f; cnt = 0; gcur = g;
    }
    acc += bf2f(Ph[(size_t)i * FD + f]);
    ++cnt;
  }
  atomicAdd(&sums[gcur * FD + f], acc);
  if (f == 0) atomicAdd(&counts[gcur], (float)cnt);
}

__global__ void k_head(const float* __restrict__ sums, const float* __restrict__ counts,
                       const float* __restrict__ Wm, const float* __restrict__ bm,
                       float* __restrict__ out) {
  int t = blockIdx.x * 256 + threadIdx.x;
  if (t >= NG * NC) return;
  int g = t / NC, c = t % NC;
  float inv = 1.0f / fmaxf(counts[g], 1.0f);
  float s = 0.f;
#pragma unroll 4
  for (int f = 0; f < FD; ++f) s = fmaf(sums[g * FD + f] * inv, Wm[f * NC + c], s);
  out[t] = s + bm[c];
}

extern "C" void kernel_launch(void* const* d_in, const int* in_sizes, int n_in,
                              void* d_out, int out_size, void* d_ws, size_t ws_size,
                              hipStream_t stream) {
  const float* x     = (const float*)d_in[0];
  const int*   ei    = (const int*)d_in[1];
  const int*   batch = (const int*)d_in[2];
  const float* W_in  = (const float*)d_in[3];
  const float* b_in  = (const float*)d_in[4];
  const float* W_mid = (const float*)d_in[5];
  const float* b_mid = (const float*)d_in[6];
  const float* W_mlp = (const float*)d_in[7];
  const float* b_mlp = (const float*)d_in[8];
  float* out = (float*)d_out;

  const int* src = ei;        // edge_index[0]
  const int* dst = ei + NE;   // edge_index[1]

  char* ws = (char*)d_ws;
  unsigned char* Qf8 = (unsigned char*)ws;  ws += (size_t)NN * FD;     // 12.8 MB
  ushort*   Ph      = (ushort*)ws;    ws += (size_t)NN * FD * 2;       // 25.6 MB
  float*    dinv    = (float*)ws;     ws += (size_t)NN * 4;
  int*      rowptr  = (int*)ws;       ws += (size_t)(NN + 1) * 4;
  int*      csr_src = (int*)ws;       ws += (size_t)NT * 4;            // 6.8 MB
  unsigned* binned  = (unsigned*)ws;  ws += (size_t)NE * 4;            // 6.4 MB
  int*      histG   = (int*)ws;       ws += (size_t)NBC2 * 4;          // 400 KB
  int*      boffC   = (int*)ws;       ws += (size_t)(NBC2 + 1) * 4;
  int*      cSums   = (int*)ws;       ws += 256 * 4;
  int*      cOffs   = (int*)ws;       ws += 256 * 4;
  ushort*   WhA     = (ushort*)ws;    ws += (size_t)FD * FD * 2;
  ushort*   WlA     = (ushort*)ws;    ws += (size_t)FD * FD * 2;
  ushort*   WhB     = (ushort*)ws;    ws += (size_t)FD * FD * 2;
  ushort*   WlB     = (ushort*)ws;    ws += (size_t)FD * FD * 2;
  float*    sums    = (float*)ws;     ws += (size_t)NG * FD * 4;
  float*    counts  = (float*)ws;     ws += (size_t)NG * 4;

  // chunked binned CSR build (incl. self-loops; reused by all 4 layers)
  k_hist<<<NCH, 256, 0, stream>>>(dst, histG);
  k_s2A<<<SCB2, 256, 0, stream>>>(histG, cSums);
  k_s2B<<<1, 256, 0, stream>>>(cSums, cOffs, boffC);
  k_s2C<<<SCB2, 256, 0, stream>>>(histG, cOffs, boffC);
  k_chscatter<<<NCH, 256, 0, stream>>>(src, dst, boffC, binned);
  k_csr_bucket<<<NBKT, 256, 0, stream>>>(boffC, binned, rowptr, dinv, csr_src);

  // weight packing + input conversion
  k_packW<<<(FD * FD + 255) / 256, 256, 0, stream>>>(W_in, WhA, WlA);
  k_packW<<<(FD * FD + 255) / 256, 256, 0, stream>>>(W_mid, WhB, WlB);
  k_cvt<<<(NN * FD / 4 + 255) / 256, 256, 0, stream>>>(x, Ph);

  const int gM = (NN + 127) / 128;   // 782 blocks, 128 rows each
  const int gG = (NN + 7) / 8;       // 12500 blocks, 8 nodes each
  for (int L = 0; L < 4; ++L) {
    const ushort* Wh = (L == 0) ? WhA : WhB;
    const ushort* Wl = (L == 0) ? WlA : WlB;
    const float*  b  = (L == 0) ? b_in : b_mid;
    k_gemm_mfma<<<gM, 256, 0, stream>>>(Ph, Wh, Wl, dinv, Qf8);
    k_gather<<<gG, 256, 0, stream>>>(rowptr, csr_src, Qf8, b, dinv, Ph);
  }

  k_zero_pool<<<32, 256, 0, stream>>>(sums, counts);
  k_pool<<<POOL_BLOCKS, 128, 0, stream>>>(batch, Ph, sums, counts);
  k_head<<<(NG * NC + 255) / 256, 256, 0, stream>>>(sums, counts, W_mlp, b_mlp, out);
}

// Round 15
// 401.839 us; speedup vs baseline: 1.6447x; 1.0549x over previous
//
#include <hip/hip_runtime.h>

#define NN 100000
#define NE 1600000
#define NT (NE + NN)     // edges incl. self-loops
#define FD 128
#define NC 10
#define NG 64

#define NBKT ((NN + 127) >> 7)   // 782 buckets of 128 nodes
#define NCH 128                  // edge chunks
#define CH (NE / NCH)            // 12500 edges per chunk
#define NBC2 (NBKT * NCH)        // 100096 (bucket, chunk) counters
#define SCB2 196                 // 196*512 = 100352 >= NBC2
#define CAP 3072                 // LDS edge cap per bucket (mean 2046, sigma ~45)

typedef __attribute__((ext_vector_type(8))) short short8v;   // 8 bf16 (4 VGPRs)
typedef __attribute__((ext_vector_type(4))) float f32x4;
typedef _Float16 half2v __attribute__((ext_vector_type(2)));

__device__ inline ushort f2bf(float x) {                     // round-to-nearest-even
  unsigned u = __float_as_uint(x);
  return (ushort)((u + 0x7FFF + ((u >> 16) & 1)) >> 16);
}
__device__ inline float bf2f(ushort h) { return __uint_as_float(((unsigned)h) << 16); }

// f32 -> e4m3fn byte (via f16 at 2^-8 scale; RN to 3-bit mantissa; f16 denorm = e4m3 denorm)
__device__ inline unsigned char f2e4m3(float x) {
  x = fminf(fmaxf(x, -448.f), 448.f);
  _Float16 hf = (_Float16)(x * 0.00390625f);
  unsigned short b = __builtin_bit_cast(unsigned short, hf);
  unsigned short r = (unsigned short)((b & 0x7fff) + 0x3F + ((b >> 7) & 1));
  return (unsigned char)(((r >> 7) & 0x7f) | ((b >> 8) & 0x80));
}

// dual-edge f16 dot-accumulate: acc += a.x + a.y  (b = ones), f32 accumulation
__device__ inline float dot2acc(half2v a, half2v b, float c) {
#if __has_builtin(__builtin_amdgcn_fdot2)
  return __builtin_amdgcn_fdot2(a, b, c, false);
#else
  return c + (float)a[0] * (float)b[0] + (float)a[1] * (float)b[1];
#endif
}

// decode packed [0,bA,0,bB] -> half2 (e4m3(bA)*2^-8, e4m3(bB)*2^-8)
__device__ inline half2v d2(unsigned p) {
  p = ((p >> 1) & 0x3f803f80u) | (p & 0x80008000u);
  return __builtin_bit_cast(half2v, p);
}

// ---------- chunked-LDS binned CSR build (no global atomics) ----------

__global__ __launch_bounds__(256) void k_hist(const int* __restrict__ dst,
                                              int* __restrict__ histG) {
  __shared__ int hist[NBKT];
  int tid = threadIdx.x, chunk = blockIdx.x;
  for (int i = tid; i < NBKT; i += 256) hist[i] = 0;
  __syncthreads();
  int e0 = chunk * CH;
  for (int i = tid; i < CH; i += 256)
    atomicAdd(&hist[dst[e0 + i] >> 7], 1);
  __syncthreads();
  for (int i = tid; i < NBKT; i += 256) histG[i * NCH + chunk] = hist[i];
}

__global__ void k_s2A(const int* __restrict__ cnt, int* __restrict__ blockSums) {
  __shared__ int red[256];
  int t = threadIdx.x, b = blockIdx.x;
  int i0 = b * 512 + t * 2;
  int s = 0;
#pragma unroll
  for (int j = 0; j < 2; ++j) { int i = i0 + j; if (i < NBC2) s += cnt[i]; }
  red[t] = s;
  __syncthreads();
  for (int off = 128; off > 0; off >>= 1) {
    if (t < off) red[t] += red[t + off];
    __syncthreads();
  }
  if (t == 0) blockSums[b] = red[0];
}

__global__ void k_s2B(const int* __restrict__ blockSums, int* __restrict__ blockOffs,
                      int* __restrict__ boffC) {
  __shared__ int sh[256];
  int t = threadIdx.x;
  int v = (t < SCB2) ? blockSums[t] : 0;
  sh[t] = v;
  __syncthreads();
  for (int off = 1; off < 256; off <<= 1) {
    int u = (t >= off) ? sh[t - off] : 0;
    __syncthreads();
    sh[t] += u;
    __syncthreads();
  }
  if (t < SCB2) blockOffs[t] = sh[t] - v;   // exclusive
  if (t == 255) boffC[NBC2] = sh[255];      // = NE
}

__global__ void k_s2C(const int* __restrict__ cnt, const int* __restrict__ blockOffs,
                      int* __restrict__ boffC) {
  __shared__ int sh[256];
  int t = threadIdx.x, b = blockIdx.x;
  int i0 = b * 512 + t * 2;
  int c[2];
  int s = 0;
#pragma unroll
  for (int j = 0; j < 2; ++j) {
    int i = i0 + j;
    c[j] = (i < NBC2) ? cnt[i] : 0;
    s += c[j];
  }
  sh[t] = s;
  __syncthreads();
  for (int off = 1; off < 256; off <<= 1) {
    int u = (t >= off) ? sh[t - off] : 0;
    __syncthreads();
    sh[t] += u;
    __syncthreads();
  }
  int run = blockOffs[b] + sh[t] - s;
#pragma unroll
  for (int j = 0; j < 2; ++j) {
    int i = i0 + j;
    if (i < NBC2) { boffC[i] = run; run += c[j]; }
  }
}

__global__ __launch_bounds__(256) void k_chscatter(const int* __restrict__ src,
                                                   const int* __restrict__ dst,
                                                   const int* __restrict__ boffC,
                                                   unsigned* __restrict__ binned) {
  __shared__ int curs[NBKT];
  int tid = threadIdx.x, chunk = blockIdx.x;
  for (int i = tid; i < NBKT; i += 256) curs[i] = boffC[i * NCH + chunk];
  __syncthreads();
  int e0 = chunk * CH;
  for (int i = tid; i < CH; i += 256) {
    int e = e0 + i;
    int d = dst[e], s = src[e];
    int slot = atomicAdd(&curs[d >> 7], 1);
    binned[slot] = ((unsigned)(d & 127) << 17) | (unsigned)s;
  }
}

__global__ __launch_bounds__(256) void k_csr_bucket(
    const int* __restrict__ boffC, const unsigned* __restrict__ binned,
    int* __restrict__ rowptr, float* __restrict__ dinv, int* __restrict__ csr_src) {
  __shared__ unsigned varr[CAP];
  __shared__ int earr[CAP + 128];
  __shared__ int deg[128];
  __shared__ int sh[128];
  int b = blockIdx.x, tid = threadIdx.x;
  int e0 = boffC[b * NCH], e1 = boffC[(b + 1) * NCH], seg = e1 - e0;
  int n0 = b << 7;
  int nb = NN - n0; if (nb > 128) nb = 128;
  int gbase = e0 + n0;                      // + one self per preceding node
  if (tid < 128) deg[tid] = 0;
  __syncthreads();
  bool fast = (seg <= CAP);
  if (fast) {
    for (int i = tid; i < seg; i += 256) {
      unsigned v = binned[e0 + i];
      varr[i] = v;
      atomicAdd(&deg[(v >> 17) & 127], 1);
    }
  } else {
    for (int i = tid; i < seg; i += 256) {
      unsigned v = binned[e0 + i];
      atomicAdd(&deg[(v >> 17) & 127], 1);
    }
  }
  __syncthreads();
  int dl = 0;
  if (tid < 128) {
    dl = (tid < nb) ? deg[tid] + 1 : 0;     // +1 self-loop
    sh[tid] = dl;
  }
  __syncthreads();
  for (int off = 1; off < 128; off <<= 1) {
    int u = 0;
    if (tid < 128 && tid >= off) u = sh[tid - off];
    __syncthreads();
    if (tid < 128) sh[tid] += u;
    __syncthreads();
  }
  int excl = 0;
  if (tid < nb) {
    excl = sh[tid] - dl;
    rowptr[n0 + tid] = gbase + excl;
    dinv[n0 + tid] = rsqrtf((float)dl);
    if (fast) earr[excl] = n0 + tid;        // self-loop in first slot
    else      csr_src[gbase + excl] = n0 + tid;
  }
  __syncthreads();
  if (tid < 128) deg[tid] = (tid < nb) ? (excl + 1) : 0;   // cursor after self
  __syncthreads();
  if (fast) {
    for (int i = tid; i < seg; i += 256) {
      unsigned v = varr[i];
      int l = (v >> 17) & 127;
      int pos = atomicAdd(&deg[l], 1);
      earr[pos] = (int)(v & 0x1FFFF);
    }
    __syncthreads();
    int tot = seg + nb;
    for (int i = tid; i < tot; i += 256) csr_src[gbase + i] = earr[i];
  } else {
    for (int i = tid; i < seg; i += 256) {
      unsigned v = binned[e0 + i];
      int l = (v >> 17) & 127;
      int pos = atomicAdd(&deg[l], 1);
      csr_src[gbase + pos] = (int)(v & 0x1FFFF);
    }
  }
  if (b == 0 && tid == 0) rowptr[NN] = NT;
}

// ---------- prep: x -> bf16, W -> packed split hi/lo ----------

__global__ void k_cvt(const float* __restrict__ X, ushort* __restrict__ Hh) {
  int t = blockIdx.x * 256 + threadIdx.x;
  if (t >= NN * FD / 4) return;
  float4 v = ((const float4*)X)[t];
  ushort4 h;
  h.x = f2bf(v.x); h.y = f2bf(v.y); h.z = f2bf(v.z); h.w = f2bf(v.w);
  ((ushort4*)Hh)[t] = h;
}

// Pack W[k][col] into MFMA B-fragment order, split hi/lo (weight split kept:
// W error is systematic across nodes and would NOT average out in pooling):
// packed[(((k>>5)*128 + col)*4 + ((k>>3)&3))*8 + (k&7)]
__global__ void k_packW(const float* __restrict__ W, ushort* __restrict__ Wh,
                        ushort* __restrict__ Wl) {
  int idx = blockIdx.x * 256 + threadIdx.x;
  if (idx >= FD * FD) return;
  int k = idx >> 7, col = idx & 127;
  float v = W[idx];
  ushort h = f2bf(v);
  ushort l = f2bf(v - bf2f(h));
  size_t o = ((((size_t)(k >> 5)) * 128 + col) * 4 + ((k >> 3) & 3)) * 8 + (k & 7);
  Wh[o] = h; Wl[o] = l;
}

// ---------- MFMA GEMM: Qf8 = e4m3( dinv[row] * (Ah@(Wh+Wl)) ) ----------
__global__ __launch_bounds__(256, 4) void k_gemm_mfma(
    const ushort* __restrict__ Ah,
    const ushort* __restrict__ Bh, const ushort* __restrict__ Bl,
    const float* __restrict__ dinv, unsigned char* __restrict__ Qf8) {
  int tid = threadIdx.x;
  int wave = tid >> 6, lane = tid & 63;
  int m15 = lane & 15, k0 = lane >> 4;
  int row0 = blockIdx.x * 128 + wave * 32;

  int ar0 = row0 + m15;      if (ar0 >= NN) ar0 = NN - 1;
  int ar1 = row0 + 16 + m15; if (ar1 >= NN) ar1 = NN - 1;
  short8v ah0[4], ah1[4];
#pragma unroll
  for (int kc = 0; kc < 4; ++kc) {
    size_t o0 = (size_t)ar0 * FD + kc * 32 + k0 * 8;
    size_t o1 = (size_t)ar1 * FD + kc * 32 + k0 * 8;
    ah0[kc] = *(const short8v*)(Ah + o0);
    ah1[kc] = *(const short8v*)(Ah + o1);
  }

  int orow0 = row0 + k0 * 4;
  int orow1 = row0 + 16 + k0 * 4;
  float dv0[4], dv1[4];
#pragma unroll
  for (int j = 0; j < 4; ++j) {
    int r0 = orow0 + j; dv0[j] = (r0 < NN) ? dinv[r0] : 0.f;
    int r1 = orow1 + j; dv1[j] = (r1 < NN) ? dinv[r1] : 0.f;
  }

#pragma unroll
  for (int nt = 0; nt < 8; ++nt) {
    int col = nt * 16 + m15;
    f32x4 acc0 = {0.f, 0.f, 0.f, 0.f};
    f32x4 acc1 = {0.f, 0.f, 0.f, 0.f};
#pragma unroll
    for (int kc = 0; kc < 4; ++kc) {
      size_t off = (((size_t)kc * 128 + col) * 4 + k0) * 8;
      short8v bh = *(const short8v*)(Bh + off);
      short8v bl = *(const short8v*)(Bl + off);
      acc0 = __builtin_amdgcn_mfma_f32_16x16x32_bf16(ah0[kc], bh, acc0, 0, 0, 0);
      acc1 = __builtin_amdgcn_mfma_f32_16x16x32_bf16(ah1[kc], bh, acc1, 0, 0, 0);
      acc0 = __builtin_amdgcn_mfma_f32_16x16x32_bf16(ah0[kc], bl, acc0, 0, 0, 0);
      acc1 = __builtin_amdgcn_mfma_f32_16x16x32_bf16(ah1[kc], bl, acc1, 0, 0, 0);
    }
#pragma unroll
    for (int j = 0; j < 4; ++j) {
      int r0 = orow0 + j;
      if (r0 < NN) Qf8[(size_t)r0 * FD + col] = f2e4m3(dv0[j] * acc0[j]);
      int r1 = orow1 + j;
      if (r1 < NN) Qf8[(size_t)r1 * FD + col] = f2e4m3(dv1[j] * acc1[j]);
    }
  }
}

// ---------- gather: Ph = bf16( relu( dinv*256*sum_e dec8(Qf8[src_e]) + b ) ) ----------
// 32 lanes/node, 128B fp8 row (u32/lane); edges processed in PAIRS: one v_perm
// per feature packs both edges' bytes, one shared decode, one v_dot2_f32_f16.
__global__ void k_gather(const int* __restrict__ rowptr, const int* __restrict__ csr_src,
                         const unsigned char* __restrict__ Qf8,
                         const float* __restrict__ b,
                         const float* __restrict__ dinv, ushort* __restrict__ Ph) {
  int node = blockIdx.x * 8 + (threadIdx.x >> 5);
  if (node >= NN) return;
  int lane = threadIdx.x & 31;
  const unsigned* __restrict__ Q4 = (const unsigned*)Qf8;
  float4 acc = {0.f, 0.f, 0.f, 0.f};
  const half2v ones = {(_Float16)1.0f, (_Float16)1.0f};
  int e0 = rowptr[node], e1 = rowptr[node + 1];
  int e = e0;
  for (; e + 3 < e1; e += 4) {            // two pairs, 4 loads in flight
    int s0 = csr_src[e], s1 = csr_src[e + 1], s2 = csr_src[e + 2], s3 = csr_src[e + 3];
    unsigned q0 = Q4[(size_t)s0 * 32 + lane];
    unsigned q1 = Q4[(size_t)s1 * 32 + lane];
    unsigned q2 = Q4[(size_t)s2 * 32 + lane];
    unsigned q3 = Q4[(size_t)s3 * 32 + lane];
    acc.x = dot2acc(d2(__builtin_amdgcn_perm(q1, q0, 0x040c000cu)), ones, acc.x);
    acc.y = dot2acc(d2(__builtin_amdgcn_perm(q1, q0, 0x050c010cu)), ones, acc.y);
    acc.z = dot2acc(d2(__builtin_amdgcn_perm(q1, q0, 0x060c020cu)), ones, acc.z);
    acc.w = dot2acc(d2(__builtin_amdgcn_perm(q1, q0, 0x070c030cu)), ones, acc.w);
    acc.x = dot2acc(d2(__builtin_amdgcn_perm(q3, q2, 0x040c000cu)), ones, acc.x);
    acc.y = dot2acc(d2(__builtin_amdgcn_perm(q3, q2, 0x050c010cu)), ones, acc.y);
    acc.z = dot2acc(d2(__builtin_amdgcn_perm(q3, q2, 0x060c020cu)), ones, acc.z);
    acc.w = dot2acc(d2(__builtin_amdgcn_perm(q3, q2, 0x070c030cu)), ones, acc.w);
  }
  if (e + 1 < e1) {                       // one pair
    int s0 = csr_src[e], s1 = csr_src[e + 1];
    unsigned q0 = Q4[(size_t)s0 * 32 + lane];
    unsigned q1 = Q4[(size_t)s1 * 32 + lane];
    acc.x = dot2acc(d2(__builtin_amdgcn_perm(q1, q0, 0x040c000cu)), ones, acc.x);
    acc.y = dot2acc(d2(__builtin_amdgcn_perm(q1, q0, 0x050c010cu)), ones, acc.y);
    acc.z = dot2acc(d2(__builtin_amdgcn_perm(q1, q0, 0x060c020cu)), ones, acc.z);
    acc.w = dot2acc(d2(__builtin_amdgcn_perm(q1, q0, 0x070c030cu)), ones, acc.w);
    e += 2;
  }
  if (e < e1) {                           // single tail edge
    unsigned q0 = Q4[(size_t)csr_src[e] * 32 + lane];
    acc.x = dot2acc(d2(__builtin_amdgcn_perm(0u, q0, 0x0c0c000cu)), ones, acc.x);
    acc.y = dot2acc(d2(__builtin_amdgcn_perm(0u, q0, 0x0c0c010cu)), ones, acc.y);
    acc.z = dot2acc(d2(__builtin_amdgcn_perm(0u, q0, 0x0c0c020cu)), ones, acc.z);
    acc.w = dot2acc(d2(__builtin_amdgcn_perm(0u, q0, 0x0c0c030cu)), ones, acc.w);
  }
  float di = dinv[node] * 256.0f;         // undo the 2^-8 decode scale exactly
  float4 bv = ((const float4*)b)[lane];
  acc.x = fmaxf(fmaf(di, acc.x, bv.x), 0.f);
  acc.y = fmaxf(fmaf(di, acc.y, bv.y), 0.f);
  acc.z = fmaxf(fmaf(di, acc.z, bv.z), 0.f);
  acc.w = fmaxf(fmaf(di, acc.w, bv.w), 0.f);
  ushort4 h;
  h.x = f2bf(acc.x); h.y = f2bf(acc.y); h.z = f2bf(acc.z); h.w = f2bf(acc.w);
  ((ushort4*)Ph)[(size_t)node * 32 + lane] = h;
}

// ---------- pooling + head ----------

__global__ void k_zero_pool(float* __restrict__ sums, float* __restrict__ counts) {
  int t = blockIdx.x * 256 + threadIdx.x;
  if (t < NG * FD) sums[t] = 0.f;
  if (t < NG) counts[t] = 0.f;
}

#define POOL_BLOCKS 1024
#define POOL_CHUNK 98
__global__ void k_pool(const int* __restrict__ batch, const ushort* __restrict__ Ph,
                       float* __restrict__ sums, float* __restrict__ counts) {
  int f = threadIdx.x;  // 0..127
  int i0 = blockIdx.x * POOL_CHUNK;
  if (i0 >= NN) return;
  int i1 = i0 + POOL_CHUNK;
  if (i1 > NN) i1 = NN;
  float acc = 0.f;
  int gcur = batch[i0];
  int cnt = 0;
  for (int i = i0; i < i1; ++i) {
    int g = batch[i];
    if (g != gcur) {
      atomicAdd(&sums[gcur * FD + f], acc);
      if (f == 0) atomicAdd(&counts[gcur], (float)cnt);
      acc = 0.f; cnt = 0; gcur = g;
    }
    acc += bf2f(Ph[(size_t)i * FD + f]);
    ++cnt;
  }
  atomicAdd(&sums[gcur * FD + f], acc);
  if (f == 0) atomicAdd(&counts[gcur], (float)cnt);
}

__global__ void k_head(const float* __restrict__ sums, const float* __restrict__ counts,
                       const float* __restrict__ Wm, const float* __restrict__ bm,
                       float* __restrict__ out) {
  int t = blockIdx.x * 256 + threadIdx.x;
  if (t >= NG * NC) return;
  int g = t / NC, c = t % NC;
  float inv = 1.0f / fmaxf(counts[g], 1.0f);
  float s = 0.f;
#pragma unroll 4
  for (int f = 0; f < FD; ++f) s = fmaf(sums[g * FD + f] * inv, Wm[f * NC + c], s);
  out[t] = s + bm[c];
}

extern "C" void kernel_launch(void* const* d_in, const int* in_sizes, int n_in,
                              void* d_out, int out_size, void* d_ws, size_t ws_size,
                              hipStream_t stream) {
  const float* x     = (const float*)d_in[0];
  const int*   ei    = (const int*)d_in[1];
  const int*   batch = (const int*)d_in[2];
  const float* W_in  = (const float*)d_in[3];
  const float* b_in  = (const float*)d_in[4];
  const float* W_mid = (const float*)d_in[5];
  const float* b_mid = (const float*)d_in[6];
  const float* W_mlp = (const float*)d_in[7];
  const float* b_mlp = (const float*)d_in[8];
  float* out = (float*)d_out;

  const int* src = ei;        // edge_index[0]
  const int* dst = ei + NE;   // edge_index[1]

  char* ws = (char*)d_ws;
  unsigned char* Qf8 = (unsigned char*)ws;  ws += (size_t)NN * FD;     // 12.8 MB
  ushort*   Ph      = (ushort*)ws;    ws += (size_t)NN * FD * 2;       // 25.6 MB
  float*    dinv    = (float*)ws;     ws += (size_t)NN * 4;
  int*      rowptr  = (int*)ws;       ws += (size_t)(NN + 1) * 4;
  int*      csr_src = (int*)ws;       ws += (size_t)NT * 4;            // 6.8 MB
  unsigned* binned  = (unsigned*)ws;  ws += (size_t)NE * 4;            // 6.4 MB
  int*      histG   = (int*)ws;       ws += (size_t)NBC2 * 4;          // 400 KB
  int*      boffC   = (int*)ws;       ws += (size_t)(NBC2 + 1) * 4;
  int*      cSums   = (int*)ws;       ws += 256 * 4;
  int*      cOffs   = (int*)ws;       ws += 256 * 4;
  ushort*   WhA     = (ushort*)ws;    ws += (size_t)FD * FD * 2;
  ushort*   WlA     = (ushort*)ws;    ws += (size_t)FD * FD * 2;
  ushort*   WhB     = (ushort*)ws;    ws += (size_t)FD * FD * 2;
  ushort*   WlB     = (ushort*)ws;    ws += (size_t)FD * FD * 2;
  float*    sums    = (float*)ws;     ws += (size_t)NG * FD * 4;
  float*    counts  = (float*)ws;     ws += (size_t)NG * 4;

  // chunked binned CSR build (incl. self-loops; reused by all 4 layers)
  k_hist<<<NCH, 256, 0, stream>>>(dst, histG);
  k_s2A<<<SCB2, 256, 0, stream>>>(histG, cSums);
  k_s2B<<<1, 256, 0, stream>>>(cSums, cOffs, boffC);
  k_s2C<<<SCB2, 256, 0, stream>>>(histG, cOffs, boffC);
  k_chscatter<<<NCH, 256, 0, stream>>>(src, dst, boffC, binned);
  k_csr_bucket<<<NBKT, 256, 0, stream>>>(boffC, binned, rowptr, dinv, csr_src);

  // weight packing + input conversion
  k_packW<<<(FD * FD + 255) / 256, 256, 0, stream>>>(W_in, WhA, WlA);
  k_packW<<<(FD * FD + 255) / 256, 256, 0, stream>>>(W_mid, WhB, WlB);
  k_cvt<<<(NN * FD / 4 + 255) / 256, 256, 0, stream>>>(x, Ph);

  const int gM = (NN + 127) / 128;   // 782 blocks, 128 rows each
  const int gG = (NN + 7) / 8;       // 12500 blocks, 8 nodes each
  for (int L = 0; L < 4; ++L) {
    const ushort* Wh = (L == 0) ? WhA : WhB;
    const ushort* Wl = (L == 0) ? WlA : WlB;
    const float*  b  = (L == 0) ? b_in : b_mid;
    k_gemm_mfma<<<gM, 256, 0, stream>>>(Ph, Wh, Wl, dinv, Qf8);
    k_gather<<<gG, 256, 0, stream>>>(rowptr, csr_src, Qf8, b, dinv, Ph);
  }

  k_zero_pool<<<32, 256, 0, stream>>>(sums, counts);
  k_pool<<<POOL_BLOCKS, 128, 0, stream>>>(batch, Ph, sums, counts);
  k_head<<<(NG * NC + 255) / 256, 256, 0, stream>>>(sums, counts, W_mlp, b_mlp, out);
}

// Round 16
// 398.674 us; speedup vs baseline: 1.6577x; 1.0079x over previous
//
#include <hip/hip_runtime.h>

#define NN 100000
#define NE 1600000
#define NT (NE + NN)     // edges incl. self-loops
#define FD 128
#define NC 10
#define NG 64

#define NBKT ((NN + 127) >> 7)   // 782 buckets of 128 nodes
#define NCH 128                  // edge chunks
#define CH (NE / NCH)            // 12500 edges per chunk
#define NBC2 (NBKT * NCH)        // 100096 (bucket, chunk) counters
#define SCB2 196                 // 196*512 = 100352 >= NBC2
#define CAP 3072                 // LDS edge cap per bucket (mean 2046, sigma ~45)

#if __has_builtin(__builtin_amdgcn_dot4_f32_fp8_fp8)
#define HAVE_DOT4 1
#else
#define HAVE_DOT4 0
#endif

typedef __attribute__((ext_vector_type(8))) short short8v;   // 8 bf16 (4 VGPRs)
typedef __attribute__((ext_vector_type(4))) float f32x4;
typedef _Float16 half2v __attribute__((ext_vector_type(2)));

__device__ inline ushort f2bf(float x) {                     // round-to-nearest-even
  unsigned u = __float_as_uint(x);
  return (ushort)((u + 0x7FFF + ((u >> 16) & 1)) >> 16);
}
__device__ inline float bf2f(ushort h) { return __uint_as_float(((unsigned)h) << 16); }

// f32 -> e4m3fn byte (via f16 at 2^-8 scale; RN to 3-bit mantissa; f16 denorm = e4m3 denorm)
__device__ inline unsigned char f2e4m3(float x) {
  x = fminf(fmaxf(x, -448.f), 448.f);
  _Float16 hf = (_Float16)(x * 0.00390625f);
  unsigned short b = __builtin_bit_cast(unsigned short, hf);
  unsigned short r = (unsigned short)((b & 0x7fff) + 0x3F + ((b >> 7) & 1));
  return (unsigned char)(((r >> 7) & 0x7f) | ((b >> 8) & 0x80));
}

// fallback path helpers (f16-subnormal decode + dot2 accumulate)
__device__ inline float dot2acc(half2v a, half2v b, float c) {
#if __has_builtin(__builtin_amdgcn_fdot2)
  return __builtin_amdgcn_fdot2(a, b, c, false);
#else
  return c + (float)a[0] * (float)b[0] + (float)a[1] * (float)b[1];
#endif
}
__device__ inline half2v d2(unsigned p) {
  p = ((p >> 1) & 0x3f803f80u) | (p & 0x80008000u);
  return __builtin_bit_cast(half2v, p);
}

// ---------- chunked-LDS binned CSR build (no global atomics) ----------

__global__ __launch_bounds__(256) void k_hist(const int* __restrict__ dst,
                                              int* __restrict__ histG) {
  __shared__ int hist[NBKT];
  int tid = threadIdx.x, chunk = blockIdx.x;
  for (int i = tid; i < NBKT; i += 256) hist[i] = 0;
  __syncthreads();
  int e0 = chunk * CH;
  for (int i = tid; i < CH; i += 256)
    atomicAdd(&hist[dst[e0 + i] >> 7], 1);
  __syncthreads();
  for (int i = tid; i < NBKT; i += 256) histG[i * NCH + chunk] = hist[i];
}

__global__ void k_s2A(const int* __restrict__ cnt, int* __restrict__ blockSums) {
  __shared__ int red[256];
  int t = threadIdx.x, b = blockIdx.x;
  int i0 = b * 512 + t * 2;
  int s = 0;
#pragma unroll
  for (int j = 0; j < 2; ++j) { int i = i0 + j; if (i < NBC2) s += cnt[i]; }
  red[t] = s;
  __syncthreads();
  for (int off = 128; off > 0; off >>= 1) {
    if (t < off) red[t] += red[t + off];
    __syncthreads();
  }
  if (t == 0) blockSums[b] = red[0];
}

__global__ void k_s2B(const int* __restrict__ blockSums, int* __restrict__ blockOffs,
                      int* __restrict__ boffC) {
  __shared__ int sh[256];
  int t = threadIdx.x;
  int v = (t < SCB2) ? blockSums[t] : 0;
  sh[t] = v;
  __syncthreads();
  for (int off = 1; off < 256; off <<= 1) {
    int u = (t >= off) ? sh[t - off] : 0;
    __syncthreads();
    sh[t] += u;
    __syncthreads();
  }
  if (t < SCB2) blockOffs[t] = sh[t] - v;   // exclusive
  if (t == 255) boffC[NBC2] = sh[255];      // = NE
}

__global__ void k_s2C(const int* __restrict__ cnt, const int* __restrict__ blockOffs,
                      int* __restrict__ boffC) {
  __shared__ int sh[256];
  int t = threadIdx.x, b = blockIdx.x;
  int i0 = b * 512 + t * 2;
  int c[2];
  int s = 0;
#pragma unroll
  for (int j = 0; j < 2; ++j) {
    int i = i0 + j;
    c[j] = (i < NBC2) ? cnt[i] : 0;
    s += c[j];
  }
  sh[t] = s;
  __syncthreads();
  for (int off = 1; off < 256; off <<= 1) {
    int u = (t >= off) ? sh[t - off] : 0;
    __syncthreads();
    sh[t] += u;
    __syncthreads();
  }
  int run = blockOffs[b] + sh[t] - s;
#pragma unroll
  for (int j = 0; j < 2; ++j) {
    int i = i0 + j;
    if (i < NBC2) { boffC[i] = run; run += c[j]; }
  }
}

__global__ __launch_bounds__(256) void k_chscatter(const int* __restrict__ src,
                                                   const int* __restrict__ dst,
                                                   const int* __restrict__ boffC,
                                                   unsigned* __restrict__ binned) {
  __shared__ int curs[NBKT];
  int tid = threadIdx.x, chunk = blockIdx.x;
  for (int i = tid; i < NBKT; i += 256) curs[i] = boffC[i * NCH + chunk];
  __syncthreads();
  int e0 = chunk * CH;
  for (int i = tid; i < CH; i += 256) {
    int e = e0 + i;
    int d = dst[e], s = src[e];
    int slot = atomicAdd(&curs[d >> 7], 1);
    binned[slot] = ((unsigned)(d & 127) << 17) | (unsigned)s;
  }
}

__global__ __launch_bounds__(256) void k_csr_bucket(
    const int* __restrict__ boffC, const unsigned* __restrict__ binned,
    int* __restrict__ rowptr, float* __restrict__ dinv, int* __restrict__ csr_src) {
  __shared__ unsigned varr[CAP];
  __shared__ int earr[CAP + 128];
  __shared__ int deg[128];
  __shared__ int sh[128];
  int b = blockIdx.x, tid = threadIdx.x;
  int e0 = boffC[b * NCH], e1 = boffC[(b + 1) * NCH], seg = e1 - e0;
  int n0 = b << 7;
  int nb = NN - n0; if (nb > 128) nb = 128;
  int gbase = e0 + n0;                      // + one self per preceding node
  if (tid < 128) deg[tid] = 0;
  __syncthreads();
  bool fast = (seg <= CAP);
  if (fast) {
    for (int i = tid; i < seg; i += 256) {
      unsigned v = binned[e0 + i];
      varr[i] = v;
      atomicAdd(&deg[(v >> 17) & 127], 1);
    }
  } else {
    for (int i = tid; i < seg; i += 256) {
      unsigned v = binned[e0 + i];
      atomicAdd(&deg[(v >> 17) & 127], 1);
    }
  }
  __syncthreads();
  int dl = 0;
  if (tid < 128) {
    dl = (tid < nb) ? deg[tid] + 1 : 0;     // +1 self-loop
    sh[tid] = dl;
  }
  __syncthreads();
  for (int off = 1; off < 128; off <<= 1) {
    int u = 0;
    if (tid < 128 && tid >= off) u = sh[tid - off];
    __syncthreads();
    if (tid < 128) sh[tid] += u;
    __syncthreads();
  }
  int excl = 0;
  if (tid < nb) {
    excl = sh[tid] - dl;
    rowptr[n0 + tid] = gbase + excl;
    dinv[n0 + tid] = rsqrtf((float)dl);
    if (fast) earr[excl] = n0 + tid;        // self-loop in first slot
    else      csr_src[gbase + excl] = n0 + tid;
  }
  __syncthreads();
  if (tid < 128) deg[tid] = (tid < nb) ? (excl + 1) : 0;   // cursor after self
  __syncthreads();
  if (fast) {
    for (int i = tid; i < seg; i += 256) {
      unsigned v = varr[i];
      int l = (v >> 17) & 127;
      int pos = atomicAdd(&deg[l], 1);
      earr[pos] = (int)(v & 0x1FFFF);
    }
    __syncthreads();
    int tot = seg + nb;
    for (int i = tid; i < tot; i += 256) csr_src[gbase + i] = earr[i];
  } else {
    for (int i = tid; i < seg; i += 256) {
      unsigned v = binned[e0 + i];
      int l = (v >> 17) & 127;
      int pos = atomicAdd(&deg[l], 1);
      csr_src[gbase + pos] = (int)(v & 0x1FFFF);
    }
  }
  if (b == 0 && tid == 0) rowptr[NN] = NT;
}

// ---------- prep: x -> bf16, W -> packed split hi/lo ----------

__global__ void k_cvt(const float* __restrict__ X, ushort* __restrict__ Hh) {
  int t = blockIdx.x * 256 + threadIdx.x;
  if (t >= NN * FD / 4) return;
  float4 v = ((const float4*)X)[t];
  ushort4 h;
  h.x = f2bf(v.x); h.y = f2bf(v.y); h.z = f2bf(v.z); h.w = f2bf(v.w);
  ((ushort4*)Hh)[t] = h;
}

// Pack W[k][col] into MFMA B-fragment order, split hi/lo (weight split kept:
// W error is systematic across nodes and would NOT average out in pooling):
// packed[(((k>>5)*128 + col)*4 + ((k>>3)&3))*8 + (k&7)]
__global__ void k_packW(const float* __restrict__ W, ushort* __restrict__ Wh,
                        ushort* __restrict__ Wl) {
  int idx = blockIdx.x * 256 + threadIdx.x;
  if (idx >= FD * FD) return;
  int k = idx >> 7, col = idx & 127;
  float v = W[idx];
  ushort h = f2bf(v);
  ushort l = f2bf(v - bf2f(h));
  size_t o = ((((size_t)(k >> 5)) * 128 + col) * 4 + ((k >> 3) & 3)) * 8 + (k & 7);
  Wh[o] = h; Wl[o] = l;
}

// ---------- MFMA GEMM: Qf8 = e4m3( dinv[row] * (Ah@(Wh+Wl)) ) ----------
__global__ __launch_bounds__(256, 4) void k_gemm_mfma(
    const ushort* __restrict__ Ah,
    const ushort* __restrict__ Bh, const ushort* __restrict__ Bl,
    const float* __restrict__ dinv, unsigned char* __restrict__ Qf8) {
  int tid = threadIdx.x;
  int wave = tid >> 6, lane = tid & 63;
  int m15 = lane & 15, k0 = lane >> 4;
  int row0 = blockIdx.x * 128 + wave * 32;

  int ar0 = row0 + m15;      if (ar0 >= NN) ar0 = NN - 1;
  int ar1 = row0 + 16 + m15; if (ar1 >= NN) ar1 = NN - 1;
  short8v ah0[4], ah1[4];
#pragma unroll
  for (int kc = 0; kc < 4; ++kc) {
    size_t o0 = (size_t)ar0 * FD + kc * 32 + k0 * 8;
    size_t o1 = (size_t)ar1 * FD + kc * 32 + k0 * 8;
    ah0[kc] = *(const short8v*)(Ah + o0);
    ah1[kc] = *(const short8v*)(Ah + o1);
  }

  int orow0 = row0 + k0 * 4;
  int orow1 = row0 + 16 + k0 * 4;
  float dv0[4], dv1[4];
#pragma unroll
  for (int j = 0; j < 4; ++j) {
    int r0 = orow0 + j; dv0[j] = (r0 < NN) ? dinv[r0] : 0.f;
    int r1 = orow1 + j; dv1[j] = (r1 < NN) ? dinv[r1] : 0.f;
  }

#pragma unroll
  for (int nt = 0; nt < 8; ++nt) {
    int col = nt * 16 + m15;
    f32x4 acc0 = {0.f, 0.f, 0.f, 0.f};
    f32x4 acc1 = {0.f, 0.f, 0.f, 0.f};
#pragma unroll
    for (int kc = 0; kc < 4; ++kc) {
      size_t off = (((size_t)kc * 128 + col) * 4 + k0) * 8;
      short8v bh = *(const short8v*)(Bh + off);
      short8v bl = *(const short8v*)(Bl + off);
      acc0 = __builtin_amdgcn_mfma_f32_16x16x32_bf16(ah0[kc], bh, acc0, 0, 0, 0);
      acc1 = __builtin_amdgcn_mfma_f32_16x16x32_bf16(ah1[kc], bh, acc1, 0, 0, 0);
      acc0 = __builtin_amdgcn_mfma_f32_16x16x32_bf16(ah0[kc], bl, acc0, 0, 0, 0);
      acc1 = __builtin_amdgcn_mfma_f32_16x16x32_bf16(ah1[kc], bl, acc1, 0, 0, 0);
    }
#pragma unroll
    for (int j = 0; j < 4; ++j) {
      int r0 = orow0 + j;
      if (r0 < NN) Qf8[(size_t)r0 * FD + col] = f2e4m3(dv0[j] * acc0[j]);
      int r1 = orow1 + j;
      if (r1 < NN) Qf8[(size_t)r1 * FD + col] = f2e4m3(dv1[j] * acc1[j]);
    }
  }
}

// ---------- gather: Ph = bf16( relu( scale*sum_e dec8(Qf8[src_e]) + b ) ) ----------
// 32 lanes/node, 128B fp8 row (u32/lane); edge PAIRS: 1 v_perm packs
// [q0.b_i, q1.b_i, 0, 0]; HW v_dot4_f32_fp8_fp8 vs e4m3(1.0) accumulates both
// edges into f32 — no bit-decode. Fallback: f16-subnormal decode + dot2.
__global__ void k_gather(const int* __restrict__ rowptr, const int* __restrict__ csr_src,
                         const unsigned char* __restrict__ Qf8,
                         const float* __restrict__ b,
                         const float* __restrict__ dinv, ushort* __restrict__ Ph) {
  int node = blockIdx.x * 8 + (threadIdx.x >> 5);
  if (node >= NN) return;
  int lane = threadIdx.x & 31;
  const unsigned* __restrict__ Q4 = (const unsigned*)Qf8;
  float4 acc = {0.f, 0.f, 0.f, 0.f};
#if HAVE_DOT4
  const unsigned ones8 = 0x38383838u;     // e4m3fn 1.0 x4 (zero bytes add 0)
#else
  const half2v ones = {(_Float16)1.0f, (_Float16)1.0f};
#endif
  int e0 = rowptr[node], e1 = rowptr[node + 1];
  int e = e0;
  for (; e + 3 < e1; e += 4) {            // two pairs, 4 loads in flight
    int s0 = csr_src[e], s1 = csr_src[e + 1], s2 = csr_src[e + 2], s3 = csr_src[e + 3];
    unsigned q0 = Q4[(size_t)s0 * 32 + lane];
    unsigned q1 = Q4[(size_t)s1 * 32 + lane];
    unsigned q2 = Q4[(size_t)s2 * 32 + lane];
    unsigned q3 = Q4[(size_t)s3 * 32 + lane];
#if HAVE_DOT4
    acc.x = __builtin_amdgcn_dot4_f32_fp8_fp8(__builtin_amdgcn_perm(q1, q0, 0x0c0c0400u), ones8, acc.x);
    acc.y = __builtin_amdgcn_dot4_f32_fp8_fp8(__builtin_amdgcn_perm(q1, q0, 0x0c0c0501u), ones8, acc.y);
    acc.z = __builtin_amdgcn_dot4_f32_fp8_fp8(__builtin_amdgcn_perm(q1, q0, 0x0c0c0602u), ones8, acc.z);
    acc.w = __builtin_amdgcn_dot4_f32_fp8_fp8(__builtin_amdgcn_perm(q1, q0, 0x0c0c0703u), ones8, acc.w);
    acc.x = __builtin_amdgcn_dot4_f32_fp8_fp8(__builtin_amdgcn_perm(q3, q2, 0x0c0c0400u), ones8, acc.x);
    acc.y = __builtin_amdgcn_dot4_f32_fp8_fp8(__builtin_amdgcn_perm(q3, q2, 0x0c0c0501u), ones8, acc.y);
    acc.z = __builtin_amdgcn_dot4_f32_fp8_fp8(__builtin_amdgcn_perm(q3, q2, 0x0c0c0602u), ones8, acc.z);
    acc.w = __builtin_amdgcn_dot4_f32_fp8_fp8(__builtin_amdgcn_perm(q3, q2, 0x0c0c0703u), ones8, acc.w);
#else
    acc.x = dot2acc(d2(__builtin_amdgcn_perm(q1, q0, 0x040c000cu)), ones, acc.x);
    acc.y = dot2acc(d2(__builtin_amdgcn_perm(q1, q0, 0x050c010cu)), ones, acc.y);
    acc.z = dot2acc(d2(__builtin_amdgcn_perm(q1, q0, 0x060c020cu)), ones, acc.z);
    acc.w = dot2acc(d2(__builtin_amdgcn_perm(q1, q0, 0x070c030cu)), ones, acc.w);
    acc.x = dot2acc(d2(__builtin_amdgcn_perm(q3, q2, 0x040c000cu)), ones, acc.x);
    acc.y = dot2acc(d2(__builtin_amdgcn_perm(q3, q2, 0x050c010cu)), ones, acc.y);
    acc.z = dot2acc(d2(__builtin_amdgcn_perm(q3, q2, 0x060c020cu)), ones, acc.z);
    acc.w = dot2acc(d2(__builtin_amdgcn_perm(q3, q2, 0x070c030cu)), ones, acc.w);
#endif
  }
  if (e + 1 < e1) {                       // one pair
    int s0 = csr_src[e], s1 = csr_src[e + 1];
    unsigned q0 = Q4[(size_t)s0 * 32 + lane];
    unsigned q1 = Q4[(size_t)s1 * 32 + lane];
#if HAVE_DOT4
    acc.x = __builtin_amdgcn_dot4_f32_fp8_fp8(__builtin_amdgcn_perm(q1, q0, 0x0c0c0400u), ones8, acc.x);
    acc.y = __builtin_amdgcn_dot4_f32_fp8_fp8(__builtin_amdgcn_perm(q1, q0, 0x0c0c0501u), ones8, acc.y);
    acc.z = __builtin_amdgcn_dot4_f32_fp8_fp8(__builtin_amdgcn_perm(q1, q0, 0x0c0c0602u), ones8, acc.z);
    acc.w = __builtin_amdgcn_dot4_f32_fp8_fp8(__builtin_amdgcn_perm(q1, q0, 0x0c0c0703u), ones8, acc.w);
#else
    acc.x = dot2acc(d2(__builtin_amdgcn_perm(q1, q0, 0x040c000cu)), ones, acc.x);
    acc.y = dot2acc(d2(__builtin_amdgcn_perm(q1, q0, 0x050c010cu)), ones, acc.y);
    acc.z = dot2acc(d2(__builtin_amdgcn_perm(q1, q0, 0x060c020cu)), ones, acc.z);
    acc.w = dot2acc(d2(__builtin_amdgcn_perm(q1, q0, 0x070c030cu)), ones, acc.w);
#endif
    e += 2;
  }
  if (e < e1) {                           // single tail edge
    unsigned q0 = Q4[(size_t)csr_src[e] * 32 + lane];
#if HAVE_DOT4
    acc.x = __builtin_amdgcn_dot4_f32_fp8_fp8(__builtin_amdgcn_perm(0u, q0, 0x0c0c0c00u), ones8, acc.x);
    acc.y = __builtin_amdgcn_dot4_f32_fp8_fp8(__builtin_amdgcn_perm(0u, q0, 0x0c0c0c01u), ones8, acc.y);
    acc.z = __builtin_amdgcn_dot4_f32_fp8_fp8(__builtin_amdgcn_perm(0u, q0, 0x0c0c0c02u), ones8, acc.z);
    acc.w = __builtin_amdgcn_dot4_f32_fp8_fp8(__builtin_amdgcn_perm(0u, q0, 0x0c0c0c03u), ones8, acc.w);
#else
    acc.x = dot2acc(d2(__builtin_amdgcn_perm(0u, q0, 0x0c0c000cu)), ones, acc.x);
    acc.y = dot2acc(d2(__builtin_amdgcn_perm(0u, q0, 0x0c0c010cu)), ones, acc.y);
    acc.z = dot2acc(d2(__builtin_amdgcn_perm(0u, q0, 0x0c0c020cu)), ones, acc.z);
    acc.w = dot2acc(d2(__builtin_amdgcn_perm(0u, q0, 0x0c0c030cu)), ones, acc.w);
#endif
  }
#if HAVE_DOT4
  float di = dinv[node];                  // dot4 decodes true e4m3 values
#else
  float di = dinv[node] * 256.0f;         // undo the 2^-8 f16-decode scale
#endif
  float4 bv = ((const float4*)b)[lane];
  acc.x = fmaxf(fmaf(di, acc.x, bv.x), 0.f);
  acc.y = fmaxf(fmaf(di, acc.y, bv.y), 0.f);
  acc.z = fmaxf(fmaf(di, acc.z, bv.z), 0.f);
  acc.w = fmaxf(fmaf(di, acc.w, bv.w), 0.f);
  ushort4 h;
  h.x = f2bf(acc.x); h.y = f2bf(acc.y); h.z = f2bf(acc.z); h.w = f2bf(acc.w);
  ((ushort4*)Ph)[(size_t)node * 32 + lane] = h;
}

// ---------- pooling + head ----------

__global__ void k_zero_pool(float* __restrict__ sums, float* __restrict__ counts) {
  int t = blockIdx.x * 256 + threadIdx.x;
  if (t < NG * FD) sums[t] = 0.f;
  if (t < NG) counts[t] = 0.f;
}

#define POOL_BLOCKS 1024
#define POOL_CHUNK 98
__global__ void k_pool(const int* __restrict__ batch, const ushort* __restrict__ Ph,
                       float* __restrict__ sums, float* __restrict__ counts) {
  int f = threadIdx.x;  // 0..127
  int i0 = blockIdx.x * POOL_CHUNK;
  if (i0 >= NN) return;
  int i1 = i0 + POOL_CHUNK;
  if (i1 > NN) i1 = NN;
  float acc = 0.f;
  int gcur = batch[i0];
  int cnt = 0;
  for (int i = i0; i < i1; ++i) {
    int g = batch[i];
    if (g != gcur) {
      atomicAdd(&sums[gcur * FD + f], acc);
      if (f == 0) atomicAdd(&counts[gcur], (float)cnt);
      acc = 0.f; cnt = 0; gcur = g;
    }
    acc += bf2f(Ph[(size_t)i * FD + f]);
    ++cnt;
  }
  atomicAdd(&sums[gcur * FD + f], acc);
  if (f == 0) atomicAdd(&counts[gcur], (float)cnt);
}

__global__ void k_head(const float* __restrict__ sums, const float* __restrict__ counts,
                       const float* __restrict__ Wm, const float* __restrict__ bm,
                       float* __restrict__ out) {
  int t = blockIdx.x * 256 + threadIdx.x;
  if (t >= NG * NC) return;
  int g = t / NC, c = t % NC;
  float inv = 1.0f / fmaxf(counts[g], 1.0f);
  float s = 0.f;
#pragma unroll 4
  for (int f = 0; f < FD; ++f) s = fmaf(sums[g * FD + f] * inv, Wm[f * NC + c], s);
  out[t] = s + bm[c];
}

extern "C" void kernel_launch(void* const* d_in, const int* in_sizes, int n_in,
                              void* d_out, int out_size, void* d_ws, size_t ws_size,
                              hipStream_t stream) {
  const float* x     = (const float*)d_in[0];
  const int*   ei    = (const int*)d_in[1];
  const int*   batch = (const int*)d_in[2];
  const float* W_in  = (const float*)d_in[3];
  const float* b_in  = (const float*)d_in[4];
  const float* W_mid = (const float*)d_in[5];
  const float* b_mid = (const float*)d_in[6];
  const float* W_mlp = (const float*)d_in[7];
  const float* b_mlp = (const float*)d_in[8];
  float* out = (float*)d_out;

  const int* src = ei;        // edge_index[0]
  const int* dst = ei + NE;   // edge_index[1]

  char* ws = (char*)d_ws;
  unsigned char* Qf8 = (unsigned char*)ws;  ws += (size_t)NN * FD;     // 12.8 MB
  ushort*   Ph      = (ushort*)ws;    ws += (size_t)NN * FD * 2;       // 25.6 MB
  float*    dinv    = (float*)ws;     ws += (size_t)NN * 4;
  int*      rowptr  = (int*)ws;       ws += (size_t)(NN + 1) * 4;
  int*      csr_src = (int*)ws;       ws += (size_t)NT * 4;            // 6.8 MB
  unsigned* binned  = (unsigned*)ws;  ws += (size_t)NE * 4;            // 6.4 MB
  int*      histG   = (int*)ws;       ws += (size_t)NBC2 * 4;          // 400 KB
  int*      boffC   = (int*)ws;       ws += (size_t)(NBC2 + 1) * 4;
  int*      cSums   = (int*)ws;       ws += 256 * 4;
  int*      cOffs   = (int*)ws;       ws += 256 * 4;
  ushort*   WhA     = (ushort*)ws;    ws += (size_t)FD * FD * 2;
  ushort*   WlA     = (ushort*)ws;    ws += (size_t)FD * FD * 2;
  ushort*   WhB     = (ushort*)ws;    ws += (size_t)FD * FD * 2;
  ushort*   WlB     = (ushort*)ws;    ws += (size_t)FD * FD * 2;
  float*    sums    = (float*)ws;     ws += (size_t)NG * FD * 4;
  float*    counts  = (float*)ws;     ws += (size_t)NG * 4;

  // chunked binned CSR build (incl. self-loops; reused by all 4 layers)
  k_hist<<<NCH, 256, 0, stream>>>(dst, histG);
  k_s2A<<<SCB2, 256, 0, stream>>>(histG, cSums);
  k_s2B<<<1, 256, 0, stream>>>(cSums, cOffs, boffC);
  k_s2C<<<SCB2, 256, 0, stream>>>(histG, cOffs, boffC);
  k_chscatter<<<NCH, 256, 0, stream>>>(src, dst, boffC, binned);
  k_csr_bucket<<<NBKT, 256, 0, stream>>>(boffC, binned, rowptr, dinv, csr_src);

  // weight packing + input conversion
  k_packW<<<(FD * FD + 255) / 256, 256, 0, stream>>>(W_in, WhA, WlA);
  k_packW<<<(FD * FD + 255) / 256, 256, 0, stream>>>(W_mid, WhB, WlB);
  k_cvt<<<(NN * FD / 4 + 255) / 256, 256, 0, stream>>>(x, Ph);

  const int gM = (NN + 127) / 128;   // 782 blocks, 128 rows each
  const int gG = (NN + 7) / 8;       // 12500 blocks, 8 nodes each
  for (int L = 0; L < 4; ++L) {
    const ushort* Wh = (L == 0) ? WhA : WhB;
    const ushort* Wl = (L == 0) ? WlA : WlB;
    const float*  b  = (L == 0) ? b_in : b_mid;
    k_gemm_mfma<<<gM, 256, 0, stream>>>(Ph, Wh, Wl, dinv, Qf8);
    k_gather<<<gG, 256, 0, stream>>>(rowptr, csr_src, Qf8, b, dinv, Ph);
  }

  k_zero_pool<<<32, 256, 0, stream>>>(sums, counts);
  k_pool<<<POOL_BLOCKS, 128, 0, stream>>>(batch, Ph, sums, counts);
  k_head<<<(NG * NC + 255) / 256, 256, 0, stream>>>(sums, counts, W_mlp, b_mlp, out);
}

// Round 17
// 397.199 us; speedup vs baseline: 1.6639x; 1.0037x over previous
//
#include <hip/hip_runtime.h>

#define NN 100000
#define NE 1600000
#define NT (NE + NN)     // edges incl. self-loops
#define FD 128
#define NC 10
#define NG 64

#define NBKT ((NN + 127) >> 7)   // 782 buckets of 128 nodes
#define NCH 128                  // edge chunks
#define CH (NE / NCH)            // 12500 edges per chunk
#define NBC2 (NBKT * NCH)        // 100096 (bucket, chunk) counters
#define SCB2 196                 // 196*512 = 100352 >= NBC2
#define CAP 3072                 // LDS edge cap per bucket (mean 2046, sigma ~45)

#if __has_builtin(__builtin_amdgcn_cvt_pk_f32_fp8)
#define HAVE_DEC 1
#else
#define HAVE_DEC 0
#endif
#if __has_builtin(__builtin_amdgcn_cvt_pk_fp8_f32)
#define HAVE_ENC 1
#else
#define HAVE_ENC 0
#endif

typedef __attribute__((ext_vector_type(8))) short short8v;   // 8 bf16 (4 VGPRs)
typedef __attribute__((ext_vector_type(4))) float f32x4;
typedef __attribute__((ext_vector_type(2))) float f32x2;
typedef _Float16 half2v __attribute__((ext_vector_type(2)));

__device__ inline ushort f2bf(float x) {                     // round-to-nearest-even
  unsigned u = __float_as_uint(x);
  return (ushort)((u + 0x7FFF + ((u >> 16) & 1)) >> 16);
}
__device__ inline float bf2f(ushort h) { return __uint_as_float(((unsigned)h) << 16); }

// software e4m3fn encode (fallback): via f16 at 2^-8 scale, RNE to 3-bit mantissa
__device__ inline unsigned char f2e4m3(float x) {
  x = fminf(fmaxf(x, -448.f), 448.f);
  _Float16 hf = (_Float16)(x * 0.00390625f);
  unsigned short b = __builtin_bit_cast(unsigned short, hf);
  unsigned short r = (unsigned short)((b & 0x7fff) + 0x3F + ((b >> 7) & 1));
  return (unsigned char)(((r >> 7) & 0x7f) | ((b >> 8) & 0x80));
}

// e4m3 encode: HW v_cvt_pk_fp8_f32 when available (RNE, saturating)
__device__ inline unsigned char enc8(float v) {
#if HAVE_ENC
  return (unsigned char)(__builtin_amdgcn_cvt_pk_fp8_f32(v, v, 0, false) & 0xff);
#else
  return f2e4m3(v);
#endif
}

#if !HAVE_DEC
// fallback decode helpers (f16-subnormal trick; values scaled by 2^-8)
__device__ inline float dot2acc(half2v a, half2v b, float c) {
#if __has_builtin(__builtin_amdgcn_fdot2)
  return __builtin_amdgcn_fdot2(a, b, c, false);
#else
  return c + (float)a[0] * (float)b[0] + (float)a[1] * (float)b[1];
#endif
}
__device__ inline half2v d2(unsigned p) {
  p = ((p >> 1) & 0x3f803f80u) | (p & 0x80008000u);
  return __builtin_bit_cast(half2v, p);
}
#endif

// accumulate 4 e4m3 features (one u32) into acc
__device__ inline void dec8acc(unsigned q, float4& acc) {
#if HAVE_DEC
  f32x2 lo = __builtin_amdgcn_cvt_pk_f32_fp8((int)q, false);
  f32x2 hi = __builtin_amdgcn_cvt_pk_f32_fp8((int)q, true);
  acc.x += lo[0]; acc.y += lo[1]; acc.z += hi[0]; acc.w += hi[1];
#else
  const half2v ones = {(_Float16)1.0f, (_Float16)1.0f};
  acc.x = dot2acc(d2(__builtin_amdgcn_perm(0u, q, 0x0c0c000cu)), ones, acc.x);
  acc.y = dot2acc(d2(__builtin_amdgcn_perm(0u, q, 0x0c0c010cu)), ones, acc.y);
  acc.z = dot2acc(d2(__builtin_amdgcn_perm(0u, q, 0x0c0c020cu)), ones, acc.z);
  acc.w = dot2acc(d2(__builtin_amdgcn_perm(0u, q, 0x0c0c030cu)), ones, acc.w);
#endif
}

// ---------- chunked-LDS binned CSR build (no global atomics) ----------

__global__ __launch_bounds__(256) void k_hist(const int* __restrict__ dst,
                                              int* __restrict__ histG) {
  __shared__ int hist[NBKT];
  int tid = threadIdx.x, chunk = blockIdx.x;
  for (int i = tid; i < NBKT; i += 256) hist[i] = 0;
  __syncthreads();
  int e0 = chunk * CH;
  for (int i = tid; i < CH; i += 256)
    atomicAdd(&hist[dst[e0 + i] >> 7], 1);
  __syncthreads();
  for (int i = tid; i < NBKT; i += 256) histG[i * NCH + chunk] = hist[i];
}

__global__ void k_s2A(const int* __restrict__ cnt, int* __restrict__ blockSums) {
  __shared__ int red[256];
  int t = threadIdx.x, b = blockIdx.x;
  int i0 = b * 512 + t * 2;
  int s = 0;
#pragma unroll
  for (int j = 0; j < 2; ++j) { int i = i0 + j; if (i < NBC2) s += cnt[i]; }
  red[t] = s;
  __syncthreads();
  for (int off = 128; off > 0; off >>= 1) {
    if (t < off) red[t] += red[t + off];
    __syncthreads();
  }
  if (t == 0) blockSums[b] = red[0];
}

__global__ void k_s2B(const int* __restrict__ blockSums, int* __restrict__ blockOffs,
                      int* __restrict__ boffC) {
  __shared__ int sh[256];
  int t = threadIdx.x;
  int v = (t < SCB2) ? blockSums[t] : 0;
  sh[t] = v;
  __syncthreads();
  for (int off = 1; off < 256; off <<= 1) {
    int u = (t >= off) ? sh[t - off] : 0;
    __syncthreads();
    sh[t] += u;
    __syncthreads();
  }
  if (t < SCB2) blockOffs[t] = sh[t] - v;   // exclusive
  if (t == 255) boffC[NBC2] = sh[255];      // = NE
}

__global__ void k_s2C(const int* __restrict__ cnt, const int* __restrict__ blockOffs,
                      int* __restrict__ boffC) {
  __shared__ int sh[256];
  int t = threadIdx.x, b = blockIdx.x;
  int i0 = b * 512 + t * 2;
  int c[2];
  int s = 0;
#pragma unroll
  for (int j = 0; j < 2; ++j) {
    int i = i0 + j;
    c[j] = (i < NBC2) ? cnt[i] : 0;
    s += c[j];
  }
  sh[t] = s;
  __syncthreads();
  for (int off = 1; off < 256; off <<= 1) {
    int u = (t >= off) ? sh[t - off] : 0;
    __syncthreads();
    sh[t] += u;
    __syncthreads();
  }
  int run = blockOffs[b] + sh[t] - s;
#pragma unroll
  for (int j = 0; j < 2; ++j) {
    int i = i0 + j;
    if (i < NBC2) { boffC[i] = run; run += c[j]; }
  }
}

__global__ __launch_bounds__(256) void k_chscatter(const int* __restrict__ src,
                                                   const int* __restrict__ dst,
                                                   const int* __restrict__ boffC,
                                                   unsigned* __restrict__ binned) {
  __shared__ int curs[NBKT];
  int tid = threadIdx.x, chunk = blockIdx.x;
  for (int i = tid; i < NBKT; i += 256) curs[i] = boffC[i * NCH + chunk];
  __syncthreads();
  int e0 = chunk * CH;
  for (int i = tid; i < CH; i += 256) {
    int e = e0 + i;
    int d = dst[e], s = src[e];
    int slot = atomicAdd(&curs[d >> 7], 1);
    binned[slot] = ((unsigned)(d & 127) << 17) | (unsigned)s;
  }
}

__global__ __launch_bounds__(256) void k_csr_bucket(
    const int* __restrict__ boffC, const unsigned* __restrict__ binned,
    int* __restrict__ rowptr, float* __restrict__ dinv, int* __restrict__ csr_src) {
  __shared__ unsigned varr[CAP];
  __shared__ int earr[CAP + 128];
  __shared__ int deg[128];
  __shared__ int sh[128];
  int b = blockIdx.x, tid = threadIdx.x;
  int e0 = boffC[b * NCH], e1 = boffC[(b + 1) * NCH], seg = e1 - e0;
  int n0 = b << 7;
  int nb = NN - n0; if (nb > 128) nb = 128;
  int gbase = e0 + n0;                      // + one self per preceding node
  if (tid < 128) deg[tid] = 0;
  __syncthreads();
  bool fast = (seg <= CAP);
  if (fast) {
    for (int i = tid; i < seg; i += 256) {
      unsigned v = binned[e0 + i];
      varr[i] = v;
      atomicAdd(&deg[(v >> 17) & 127], 1);
    }
  } else {
    for (int i = tid; i < seg; i += 256) {
      unsigned v = binned[e0 + i];
      atomicAdd(&deg[(v >> 17) & 127], 1);
    }
  }
  __syncthreads();
  int dl = 0;
  if (tid < 128) {
    dl = (tid < nb) ? deg[tid] + 1 : 0;     // +1 self-loop
    sh[tid] = dl;
  }
  __syncthreads();
  for (int off = 1; off < 128; off <<= 1) {
    int u = 0;
    if (tid < 128 && tid >= off) u = sh[tid - off];
    __syncthreads();
    if (tid < 128) sh[tid] += u;
    __syncthreads();
  }
  int excl = 0;
  if (tid < nb) {
    excl = sh[tid] - dl;
    rowptr[n0 + tid] = gbase + excl;
    dinv[n0 + tid] = rsqrtf((float)dl);
    if (fast) earr[excl] = n0 + tid;        // self-loop in first slot
    else      csr_src[gbase + excl] = n0 + tid;
  }
  __syncthreads();
  if (tid < 128) deg[tid] = (tid < nb) ? (excl + 1) : 0;   // cursor after self
  __syncthreads();
  if (fast) {
    for (int i = tid; i < seg; i += 256) {
      unsigned v = varr[i];
      int l = (v >> 17) & 127;
      int pos = atomicAdd(&deg[l], 1);
      earr[pos] = (int)(v & 0x1FFFF);
    }
    __syncthreads();
    int tot = seg + nb;
    for (int i = tid; i < tot; i += 256) csr_src[gbase + i] = earr[i];
  } else {
    for (int i = tid; i < seg; i += 256) {
      unsigned v = binned[e0 + i];
      int l = (v >> 17) & 127;
      int pos = atomicAdd(&deg[l], 1);
      csr_src[gbase + pos] = (int)(v & 0x1FFFF);
    }
  }
  if (b == 0 && tid == 0) rowptr[NN] = NT;
}

// ---------- prep: x -> bf16, W -> packed split hi/lo ----------

__global__ void k_cvt(const float* __restrict__ X, ushort* __restrict__ Hh) {
  int t = blockIdx.x * 256 + threadIdx.x;
  if (t >= NN * FD / 4) return;
  float4 v = ((const float4*)X)[t];
  ushort4 h;
  h.x = f2bf(v.x); h.y = f2bf(v.y); h.z = f2bf(v.z); h.w = f2bf(v.w);
  ((ushort4*)Hh)[t] = h;
}

// Pack W[k][col] into MFMA B-fragment order, split hi/lo (weight split kept:
// W error is systematic across nodes and would NOT average out in pooling):
// packed[(((k>>5)*128 + col)*4 + ((k>>3)&3))*8 + (k&7)]
__global__ void k_packW(const float* __restrict__ W, ushort* __restrict__ Wh,
                        ushort* __restrict__ Wl) {
  int idx = blockIdx.x * 256 + threadIdx.x;
  if (idx >= FD * FD) return;
  int k = idx >> 7, col = idx & 127;
  float v = W[idx];
  ushort h = f2bf(v);
  ushort l = f2bf(v - bf2f(h));
  size_t o = ((((size_t)(k >> 5)) * 128 + col) * 4 + ((k >> 3) & 3)) * 8 + (k & 7);
  Wh[o] = h; Wl[o] = l;
}

// ---------- MFMA GEMM: Qf8 = e4m3( dinv[row] * (Ah@(Wh+Wl)) ) ----------
// HW v_cvt_pk_fp8_f32 epilogue (1 VALU/value vs ~10 software).
__global__ __launch_bounds__(256, 4) void k_gemm_mfma(
    const ushort* __restrict__ Ah,
    const ushort* __restrict__ Bh, const ushort* __restrict__ Bl,
    const float* __restrict__ dinv, unsigned char* __restrict__ Qf8) {
  int tid = threadIdx.x;
  int wave = tid >> 6, lane = tid & 63;
  int m15 = lane & 15, k0 = lane >> 4;
  int row0 = blockIdx.x * 128 + wave * 32;

  int ar0 = row0 + m15;      if (ar0 >= NN) ar0 = NN - 1;
  int ar1 = row0 + 16 + m15; if (ar1 >= NN) ar1 = NN - 1;
  short8v ah0[4], ah1[4];
#pragma unroll
  for (int kc = 0; kc < 4; ++kc) {
    size_t o0 = (size_t)ar0 * FD + kc * 32 + k0 * 8;
    size_t o1 = (size_t)ar1 * FD + kc * 32 + k0 * 8;
    ah0[kc] = *(const short8v*)(Ah + o0);
    ah1[kc] = *(const short8v*)(Ah + o1);
  }

  int orow0 = row0 + k0 * 4;
  int orow1 = row0 + 16 + k0 * 4;
  float dv0[4], dv1[4];
#pragma unroll
  for (int j = 0; j < 4; ++j) {
    int r0 = orow0 + j; dv0[j] = (r0 < NN) ? dinv[r0] : 0.f;
    int r1 = orow1 + j; dv1[j] = (r1 < NN) ? dinv[r1] : 0.f;
  }

#pragma unroll
  for (int nt = 0; nt < 8; ++nt) {
    int col = nt * 16 + m15;
    f32x4 acc0 = {0.f, 0.f, 0.f, 0.f};
    f32x4 acc1 = {0.f, 0.f, 0.f, 0.f};
#pragma unroll
    for (int kc = 0; kc < 4; ++kc) {
      size_t off = (((size_t)kc * 128 + col) * 4 + k0) * 8;
      short8v bh = *(const short8v*)(Bh + off);
      short8v bl = *(const short8v*)(Bl + off);
      acc0 = __builtin_amdgcn_mfma_f32_16x16x32_bf16(ah0[kc], bh, acc0, 0, 0, 0);
      acc1 = __builtin_amdgcn_mfma_f32_16x16x32_bf16(ah1[kc], bh, acc1, 0, 0, 0);
      acc0 = __builtin_amdgcn_mfma_f32_16x16x32_bf16(ah0[kc], bl, acc0, 0, 0, 0);
      acc1 = __builtin_amdgcn_mfma_f32_16x16x32_bf16(ah1[kc], bl, acc1, 0, 0, 0);
    }
#pragma unroll
    for (int j = 0; j < 4; ++j) {
      int r0 = orow0 + j;
      if (r0 < NN) Qf8[(size_t)r0 * FD + col] = enc8(dv0[j] * acc0[j]);
      int r1 = orow1 + j;
      if (r1 < NN) Qf8[(size_t)r1 * FD + col] = enc8(dv1[j] * acc1[j]);
    }
  }
}

// ---------- gather: Ph = bf16( relu( scale*sum_e dec(Qf8[src_e]) + b ) ) ----------
// 32 lanes/node, 128B fp8 row (u32/lane); HW v_cvt_pk_f32_fp8 decode:
// 2 cvt + 4 adds per edge (no perm/bitfield). 4 loads in flight.
__global__ void k_gather(const int* __restrict__ rowptr, const int* __restrict__ csr_src,
                         const unsigned char* __restrict__ Qf8,
                         const float* __restrict__ b,
                         const float* __restrict__ dinv, ushort* __restrict__ Ph) {
  int node = blockIdx.x * 8 + (threadIdx.x >> 5);
  if (node >= NN) return;
  int lane = threadIdx.x & 31;
  const unsigned* __restrict__ Q4 = (const unsigned*)Qf8;
  float4 acc = {0.f, 0.f, 0.f, 0.f};
  int e0 = rowptr[node], e1 = rowptr[node + 1];
  int e = e0;
  for (; e + 3 < e1; e += 4) {
    int s0 = csr_src[e], s1 = csr_src[e + 1], s2 = csr_src[e + 2], s3 = csr_src[e + 3];
    unsigned q0 = Q4[(size_t)s0 * 32 + lane];
    unsigned q1 = Q4[(size_t)s1 * 32 + lane];
    unsigned q2 = Q4[(size_t)s2 * 32 + lane];
    unsigned q3 = Q4[(size_t)s3 * 32 + lane];
    dec8acc(q0, acc); dec8acc(q1, acc); dec8acc(q2, acc); dec8acc(q3, acc);
  }
  for (; e < e1; ++e) {
    unsigned q0 = Q4[(size_t)csr_src[e] * 32 + lane];
    dec8acc(q0, acc);
  }
#if HAVE_DEC
  float di = dinv[node];                  // HW decode yields true values
#else
  float di = dinv[node] * 256.0f;         // undo the 2^-8 f16-decode scale
#endif
  float4 bv = ((const float4*)b)[lane];
  acc.x = fmaxf(fmaf(di, acc.x, bv.x), 0.f);
  acc.y = fmaxf(fmaf(di, acc.y, bv.y), 0.f);
  acc.z = fmaxf(fmaf(di, acc.z, bv.z), 0.f);
  acc.w = fmaxf(fmaf(di, acc.w, bv.w), 0.f);
  ushort4 h;
  h.x = f2bf(acc.x); h.y = f2bf(acc.y); h.z = f2bf(acc.z); h.w = f2bf(acc.w);
  ((ushort4*)Ph)[(size_t)node * 32 + lane] = h;
}

// ---------- pooling + head ----------

__global__ void k_zero_pool(float* __restrict__ sums, float* __restrict__ counts) {
  int t = blockIdx.x * 256 + threadIdx.x;
  if (t < NG * FD) sums[t] = 0.f;
  if (t < NG) counts[t] = 0.f;
}

#define POOL_BLOCKS 1024
#define POOL_CHUNK 98
__global__ void k_pool(const int* __restrict__ batch, const ushort* __restrict__ Ph,
                       float* __restrict__ sums, float* __restrict__ counts) {
  int f = threadIdx.x;  // 0..127
  int i0 = blockIdx.x * POOL_CHUNK;
  if (i0 >= NN) return;
  int i1 = i0 + POOL_CHUNK;
  if (i1 > NN) i1 = NN;
  float acc = 0.f;
  int gcur = batch[i0];
  int cnt = 0;
  for (int i = i0; i < i1; ++i) {
    int g = batch[i];
    if (g != gcur) {
      atomicAdd(&sums[gcur * FD + f], acc);
      if (f == 0) atomicAdd(&counts[gcur], (float)cnt);
      acc = 0.f; cnt = 0; gcur = g;
    }
    acc += bf2f(Ph[(size_t)i * FD + f]);
    ++cnt;
  }
  atomicAdd(&sums[gcur * FD + f], acc);
  if (f == 0) atomicAdd(&counts[gcur], (float)cnt);
}

__global__ void k_head(const float* __restrict__ sums, const float* __restrict__ counts,
                       const float* __restrict__ Wm, const float* __restrict__ bm,
                       float* __restrict__ out) {
  int t = blockIdx.x * 256 + threadIdx.x;
  if (t >= NG * NC) return;
  int g = t / NC, c = t % NC;
  float inv = 1.0f / fmaxf(counts[g], 1.0f);
  float s = 0.f;
#pragma unroll 4
  for (int f = 0; f < FD; ++f) s = fmaf(sums[g * FD + f] * inv, Wm[f * NC + c], s);
  out[t] = s + bm[c];
}

extern "C" void kernel_launch(void* const* d_in, const int* in_sizes, int n_in,
                              void* d_out, int out_size, void* d_ws, size_t ws_size,
                              hipStream_t stream) {
  const float* x     = (const float*)d_in[0];
  const int*   ei    = (const int*)d_in[1];
  const int*   batch = (const int*)d_in[2];
  const float* W_in  = (const float*)d_in[3];
  const float* b_in  = (const float*)d_in[4];
  const float* W_mid = (const float*)d_in[5];
  const float* b_mid = (const float*)d_in[6];
  const float* W_mlp = (const float*)d_in[7];
  const float* b_mlp = (const float*)d_in[8];
  float* out = (float*)d_out;

  const int* src = ei;        // edge_index[0]
  const int* dst = ei + NE;   // edge_index[1]

  char* ws = (char*)d_ws;
  unsigned char* Qf8 = (unsigned char*)ws;  ws += (size_t)NN * FD;     // 12.8 MB
  ushort*   Ph      = (ushort*)ws;    ws += (size_t)NN * FD * 2;       // 25.6 MB
  float*    dinv    = (float*)ws;     ws += (size_t)NN * 4;
  int*      rowptr  = (int*)ws;       ws += (size_t)(NN + 1) * 4;
  int*      csr_src = (int*)ws;       ws += (size_t)NT * 4;            // 6.8 MB
  unsigned* binned  = (unsigned*)ws;  ws += (size_t)NE * 4;            // 6.4 MB
  int*      histG   = (int*)ws;       ws += (size_t)NBC2 * 4;          // 400 KB
  int*      boffC   = (int*)ws;       ws += (size_t)(NBC2 + 1) * 4;
  int*      cSums   = (int*)ws;       ws += 256 * 4;
  int*      cOffs   = (int*)ws;       ws += 256 * 4;
  ushort*   WhA     = (ushort*)ws;    ws += (size_t)FD * FD * 2;
  ushort*   WlA     = (ushort*)ws;    ws += (size_t)FD * FD * 2;
  ushort*   WhB     = (ushort*)ws;    ws += (size_t)FD * FD * 2;
  ushort*   WlB     = (ushort*)ws;    ws += (size_t)FD * FD * 2;
  float*    sums    = (float*)ws;     ws += (size_t)NG * FD * 4;
  float*    counts  = (float*)ws;     ws += (size_t)NG * 4;

  // chunked binned CSR build (incl. self-loops; reused by all 4 layers)
  k_hist<<<NCH, 256, 0, stream>>>(dst, histG);
  k_s2A<<<SCB2, 256, 0, stream>>>(histG, cSums);
  k_s2B<<<1, 256, 0, stream>>>(cSums, cOffs, boffC);
  k_s2C<<<SCB2, 256, 0, stream>>>(histG, cOffs, boffC);
  k_chscatter<<<NCH, 256, 0, stream>>>(src, dst, boffC, binned);
  k_csr_bucket<<<NBKT, 256, 0, stream>>>(boffC, binned, rowptr, dinv, csr_src);

  // weight packing + input conversion
  k_packW<<<(FD * FD + 255) / 256, 256, 0, stream>>>(W_in, WhA, WlA);
  k_packW<<<(FD * FD + 255) / 256, 256, 0, stream>>>(W_mid, WhB, WlB);
  k_cvt<<<(NN * FD / 4 + 255) / 256, 256, 0, stream>>>(x, Ph);

  const int gM = (NN + 127) / 128;   // 782 blocks, 128 rows each
  const int gG = (NN + 7) / 8;       // 12500 blocks, 8 nodes each
  for (int L = 0; L < 4; ++L) {
    const ushort* Wh = (L == 0) ? WhA : WhB;
    const ushort* Wl = (L == 0) ? WlA : WlB;
    const float*  b  = (L == 0) ? b_in : b_mid;
    k_gemm_mfma<<<gM, 256, 0, stream>>>(Ph, Wh, Wl, dinv, Qf8);
    k_gather<<<gG, 256, 0, stream>>>(rowptr, csr_src, Qf8, b, dinv, Ph);
  }

  k_zero_pool<<<32, 256, 0, stream>>>(sums, counts);
  k_pool<<<POOL_BLOCKS, 128, 0, stream>>>(batch, Ph, sums, counts);
  k_head<<<(NG * NC + 255) / 256, 256, 0, stream>>>(sums, counts, W_mlp, b_mlp, out);
}

// Round 18
// 366.580 us; speedup vs baseline: 1.8029x; 1.0835x over previous
//
#include <hip/hip_runtime.h>

#define NN 100000
#define NE 1600000
#define NT (NE + NN)     // edges incl. self-loops
#define FD 128
#define NC 10
#define NG 64

#define NBKT ((NN + 127) >> 7)   // 782 buckets of 128 nodes
#define NCH 128                  // edge chunks
#define CH (NE / NCH)            // 12500 edges per chunk
#define NBC2 (NBKT * NCH)        // 100096 (bucket, chunk) counters
#define SCB2 196                 // 196*512 = 100352 >= NBC2
#define CAP 3072                 // LDS edge cap per bucket (mean 2046, sigma ~45)

#if __has_builtin(__builtin_amdgcn_cvt_pk_f32_fp8)
#define HAVE_DEC 1
#else
#define HAVE_DEC 0
#endif
#if __has_builtin(__builtin_amdgcn_cvt_pk_fp8_f32)
#define HAVE_ENC 1
#else
#define HAVE_ENC 0
#endif

typedef __attribute__((ext_vector_type(8))) short short8v;   // 8 bf16 (4 VGPRs)
typedef __attribute__((ext_vector_type(4))) float f32x4;
typedef __attribute__((ext_vector_type(2))) float f32x2;
typedef _Float16 half2v __attribute__((ext_vector_type(2)));

__device__ inline ushort f2bf(float x) {                     // round-to-nearest-even
  unsigned u = __float_as_uint(x);
  return (ushort)((u + 0x7FFF + ((u >> 16) & 1)) >> 16);
}
__device__ inline float bf2f(ushort h) { return __uint_as_float(((unsigned)h) << 16); }

// software e4m3fn encode (fallback)
__device__ inline unsigned char f2e4m3(float x) {
  x = fminf(fmaxf(x, -448.f), 448.f);
  _Float16 hf = (_Float16)(x * 0.00390625f);
  unsigned short b = __builtin_bit_cast(unsigned short, hf);
  unsigned short r = (unsigned short)((b & 0x7fff) + 0x3F + ((b >> 7) & 1));
  return (unsigned char)(((r >> 7) & 0x7f) | ((b >> 8) & 0x80));
}

// pack 4 f32 -> 4 e4m3 bytes in one dword (HW cvt_pk when available)
__device__ inline unsigned pack4e4m3(float v0, float v1, float v2, float v3) {
#if HAVE_ENC
  unsigned w = (unsigned)__builtin_amdgcn_cvt_pk_fp8_f32(v0, v1, 0, false);
  w = (unsigned)__builtin_amdgcn_cvt_pk_fp8_f32(v2, v3, (int)w, true);
  return w;
#else
  return (unsigned)f2e4m3(v0) | ((unsigned)f2e4m3(v1) << 8) |
         ((unsigned)f2e4m3(v2) << 16) | ((unsigned)f2e4m3(v3) << 24);
#endif
}

#if !HAVE_DEC
__device__ inline float dot2acc(half2v a, half2v b, float c) {
#if __has_builtin(__builtin_amdgcn_fdot2)
  return __builtin_amdgcn_fdot2(a, b, c, false);
#else
  return c + (float)a[0] * (float)b[0] + (float)a[1] * (float)b[1];
#endif
}
__device__ inline half2v d2(unsigned p) {
  p = ((p >> 1) & 0x3f803f80u) | (p & 0x80008000u);
  return __builtin_bit_cast(half2v, p);
}
#endif

// accumulate 4 e4m3 features (one u32) into acc
__device__ inline void dec8acc(unsigned q, float4& acc) {
#if HAVE_DEC
  f32x2 lo = __builtin_amdgcn_cvt_pk_f32_fp8((int)q, false);
  f32x2 hi = __builtin_amdgcn_cvt_pk_f32_fp8((int)q, true);
  acc.x += lo[0]; acc.y += lo[1]; acc.z += hi[0]; acc.w += hi[1];
#else
  const half2v ones = {(_Float16)1.0f, (_Float16)1.0f};
  acc.x = dot2acc(d2(__builtin_amdgcn_perm(0u, q, 0x0c0c000cu)), ones, acc.x);
  acc.y = dot2acc(d2(__builtin_amdgcn_perm(0u, q, 0x0c0c010cu)), ones, acc.y);
  acc.z = dot2acc(d2(__builtin_amdgcn_perm(0u, q, 0x0c0c020cu)), ones, acc.z);
  acc.w = dot2acc(d2(__builtin_amdgcn_perm(0u, q, 0x0c0c030cu)), ones, acc.w);
#endif
}

// ---------- chunked-LDS binned CSR build (no global atomics) ----------

__global__ __launch_bounds__(256) void k_hist(const int* __restrict__ dst,
                                              int* __restrict__ histG) {
  __shared__ int hist[NBKT];
  int tid = threadIdx.x, chunk = blockIdx.x;
  for (int i = tid; i < NBKT; i += 256) hist[i] = 0;
  __syncthreads();
  int e0 = chunk * CH;
  for (int i = tid; i < CH; i += 256)
    atomicAdd(&hist[dst[e0 + i] >> 7], 1);
  __syncthreads();
  for (int i = tid; i < NBKT; i += 256) histG[i * NCH + chunk] = hist[i];
}

__global__ void k_s2A(const int* __restrict__ cnt, int* __restrict__ blockSums) {
  __shared__ int red[256];
  int t = threadIdx.x, b = blockIdx.x;
  int i0 = b * 512 + t * 2;
  int s = 0;
#pragma unroll
  for (int j = 0; j < 2; ++j) { int i = i0 + j; if (i < NBC2) s += cnt[i]; }
  red[t] = s;
  __syncthreads();
  for (int off = 128; off > 0; off >>= 1) {
    if (t < off) red[t] += red[t + off];
    __syncthreads();
  }
  if (t == 0) blockSums[b] = red[0];
}

__global__ void k_s2B(const int* __restrict__ blockSums, int* __restrict__ blockOffs,
                      int* __restrict__ boffC) {
  __shared__ int sh[256];
  int t = threadIdx.x;
  int v = (t < SCB2) ? blockSums[t] : 0;
  sh[t] = v;
  __syncthreads();
  for (int off = 1; off < 256; off <<= 1) {
    int u = (t >= off) ? sh[t - off] : 0;
    __syncthreads();
    sh[t] += u;
    __syncthreads();
  }
  if (t < SCB2) blockOffs[t] = sh[t] - v;   // exclusive
  if (t == 255) boffC[NBC2] = sh[255];      // = NE
}

__global__ void k_s2C(const int* __restrict__ cnt, const int* __restrict__ blockOffs,
                      int* __restrict__ boffC) {
  __shared__ int sh[256];
  int t = threadIdx.x, b = blockIdx.x;
  int i0 = b * 512 + t * 2;
  int c[2];
  int s = 0;
#pragma unroll
  for (int j = 0; j < 2; ++j) {
    int i = i0 + j;
    c[j] = (i < NBC2) ? cnt[i] : 0;
    s += c[j];
  }
  sh[t] = s;
  __syncthreads();
  for (int off = 1; off < 256; off <<= 1) {
    int u = (t >= off) ? sh[t - off] : 0;
    __syncthreads();
    sh[t] += u;
    __syncthreads();
  }
  int run = blockOffs[b] + sh[t] - s;
#pragma unroll
  for (int j = 0; j < 2; ++j) {
    int i = i0 + j;
    if (i < NBC2) { boffC[i] = run; run += c[j]; }
  }
}

__global__ __launch_bounds__(256) void k_chscatter(const int* __restrict__ src,
                                                   const int* __restrict__ dst,
                                                   const int* __restrict__ boffC,
                                                   unsigned* __restrict__ binned) {
  __shared__ int curs[NBKT];
  int tid = threadIdx.x, chunk = blockIdx.x;
  for (int i = tid; i < NBKT; i += 256) curs[i] = boffC[i * NCH + chunk];
  __syncthreads();
  int e0 = chunk * CH;
  for (int i = tid; i < CH; i += 256) {
    int e = e0 + i;
    int d = dst[e], s = src[e];
    int slot = atomicAdd(&curs[d >> 7], 1);
    binned[slot] = ((unsigned)(d & 127) << 17) | (unsigned)s;
  }
}

__global__ __launch_bounds__(256) void k_csr_bucket(
    const int* __restrict__ boffC, const unsigned* __restrict__ binned,
    int* __restrict__ rowptr, float* __restrict__ dinv, int* __restrict__ csr_src) {
  __shared__ unsigned varr[CAP];
  __shared__ int earr[CAP + 128];
  __shared__ int deg[128];
  __shared__ int sh[128];
  int b = blockIdx.x, tid = threadIdx.x;
  int e0 = boffC[b * NCH], e1 = boffC[(b + 1) * NCH], seg = e1 - e0;
  int n0 = b << 7;
  int nb = NN - n0; if (nb > 128) nb = 128;
  int gbase = e0 + n0;                      // + one self per preceding node
  if (tid < 128) deg[tid] = 0;
  __syncthreads();
  bool fast = (seg <= CAP);
  if (fast) {
    for (int i = tid; i < seg; i += 256) {
      unsigned v = binned[e0 + i];
      varr[i] = v;
      atomicAdd(&deg[(v >> 17) & 127], 1);
    }
  } else {
    for (int i = tid; i < seg; i += 256) {
      unsigned v = binned[e0 + i];
      atomicAdd(&deg[(v >> 17) & 127], 1);
    }
  }
  __syncthreads();
  int dl = 0;
  if (tid < 128) {
    dl = (tid < nb) ? deg[tid] + 1 : 0;     // +1 self-loop
    sh[tid] = dl;
  }
  __syncthreads();
  for (int off = 1; off < 128; off <<= 1) {
    int u = 0;
    if (tid < 128 && tid >= off) u = sh[tid - off];
    __syncthreads();
    if (tid < 128) sh[tid] += u;
    __syncthreads();
  }
  int excl = 0;
  if (tid < nb) {
    excl = sh[tid] - dl;
    rowptr[n0 + tid] = gbase + excl;
    dinv[n0 + tid] = rsqrtf((float)dl);
    if (fast) earr[excl] = n0 + tid;        // self-loop in first slot
    else      csr_src[gbase + excl] = n0 + tid;
  }
  __syncthreads();
  if (tid < 128) deg[tid] = (tid < nb) ? (excl + 1) : 0;   // cursor after self
  __syncthreads();
  if (fast) {
    for (int i = tid; i < seg; i += 256) {
      unsigned v = varr[i];
      int l = (v >> 17) & 127;
      int pos = atomicAdd(&deg[l], 1);
      earr[pos] = (int)(v & 0x1FFFF);
    }
    __syncthreads();
    int tot = seg + nb;
    for (int i = tid; i < tot; i += 256) csr_src[gbase + i] = earr[i];
  } else {
    for (int i = tid; i < seg; i += 256) {
      unsigned v = binned[e0 + i];
      int l = (v >> 17) & 127;
      int pos = atomicAdd(&deg[l], 1);
      csr_src[gbase + pos] = (int)(v & 0x1FFFF);
    }
  }
  if (b == 0 && tid == 0) rowptr[NN] = NT;
}

// ---------- prep: x -> bf16, W -> packed W^T MFMA A-fragments (hi/lo) ----------

__global__ void k_cvt(const float* __restrict__ X, ushort* __restrict__ Hh) {
  int t = blockIdx.x * 256 + threadIdx.x;
  if (t >= NN * FD / 4) return;
  float4 v = ((const float4*)X)[t];
  ushort4 h;
  h.x = f2bf(v.x); h.y = f2bf(v.y); h.z = f2bf(v.z); h.w = f2bf(v.w);
  ((ushort4*)Hh)[t] = h;
}

// W[k][col] -> W^T A-fragment order for the TRANSPOSED gemm:
// tile (nt = col>>4, kc = k>>5); lane = (col&15) + 16*((k>>3)&3); elem i = k&7
// off = ((nt*4 + kc)*64 + lane)*8 + i
__global__ void k_packW(const float* __restrict__ W, ushort* __restrict__ Wh,
                        ushort* __restrict__ Wl) {
  int idx = blockIdx.x * 256 + threadIdx.x;
  if (idx >= FD * FD) return;
  int k = idx >> 7, col = idx & 127;
  float v = W[idx];
  ushort h = f2bf(v);
  ushort l = f2bf(v - bf2f(h));
  int nt = col >> 4, kc = k >> 5;
  int lane = (col & 15) + ((k >> 3) & 3) * 16;
  size_t o = (((size_t)(nt * 4 + kc)) * 64 + lane) * 8 + (k & 7);
  Wh[o] = h; Wl[o] = l;
}

// ---------- transposed MFMA GEMM: Q^T tiles = (Wt_h+Wt_l) @ X^T ----------
// A = W^T fragments (M = 16 Q-cols/tile), B = X row-loads (N = 16 nodes).
// D: lane m15 = node, reg j = Q-col k0*4+j -> 4 CONSECUTIVE cols per lane:
// pack 4 e4m3 bytes into one dword store (16 dword stores/thread vs 64 byte).
__global__ __launch_bounds__(256, 4) void k_gemm_mfma(
    const ushort* __restrict__ Ah,
    const ushort* __restrict__ Wth, const ushort* __restrict__ Wtl,
    const float* __restrict__ dinv, unsigned char* __restrict__ Qf8) {
  int tid = threadIdx.x;
  int wave = tid >> 6, lane = tid & 63;
  int m15 = lane & 15, k0 = lane >> 4;
  int row0 = blockIdx.x * 128 + wave * 32;

  int n0 = row0 + m15;            // node (g=0)
  int n1 = row0 + 16 + m15;       // node (g=1)
  int a0 = (n0 >= NN) ? NN - 1 : n0;
  int a1 = (n1 >= NN) ? NN - 1 : n1;
  short8v x0[4], x1[4];
#pragma unroll
  for (int kc = 0; kc < 4; ++kc) {
    x0[kc] = *(const short8v*)(Ah + (size_t)a0 * FD + kc * 32 + k0 * 8);
    x1[kc] = *(const short8v*)(Ah + (size_t)a1 * FD + kc * 32 + k0 * 8);
  }
  float dv0 = (n0 < NN) ? dinv[n0] : 0.f;
  float dv1 = (n1 < NN) ? dinv[n1] : 0.f;

#pragma unroll
  for (int nt = 0; nt < 8; ++nt) {
    f32x4 acc0 = {0.f, 0.f, 0.f, 0.f};
    f32x4 acc1 = {0.f, 0.f, 0.f, 0.f};
#pragma unroll
    for (int kc = 0; kc < 4; ++kc) {
      size_t off = (((size_t)(nt * 4 + kc)) * 64 + lane) * 8;
      short8v wh = *(const short8v*)(Wth + off);
      short8v wl = *(const short8v*)(Wtl + off);
      acc0 = __builtin_amdgcn_mfma_f32_16x16x32_bf16(wh, x0[kc], acc0, 0, 0, 0);
      acc1 = __builtin_amdgcn_mfma_f32_16x16x32_bf16(wh, x1[kc], acc1, 0, 0, 0);
      acc0 = __builtin_amdgcn_mfma_f32_16x16x32_bf16(wl, x0[kc], acc0, 0, 0, 0);
      acc1 = __builtin_amdgcn_mfma_f32_16x16x32_bf16(wl, x1[kc], acc1, 0, 0, 0);
    }
    int colb = nt * 16 + k0 * 4;
    if (n0 < NN) {
      unsigned w = pack4e4m3(dv0 * acc0[0], dv0 * acc0[1], dv0 * acc0[2], dv0 * acc0[3]);
      *(unsigned*)(Qf8 + (size_t)n0 * FD + colb) = w;
    }
    if (n1 < NN) {
      unsigned w = pack4e4m3(dv1 * acc1[0], dv1 * acc1[1], dv1 * acc1[2], dv1 * acc1[3]);
      *(unsigned*)(Qf8 + (size_t)n1 * FD + colb) = w;
    }
  }
}

// ---------- gather: Ph = bf16( relu( scale*sum_e dec(Qf8[src_e]) + b ) ) ----------
// 32 lanes/node, u32/lane; 8 edges in flight, dual accumulators (break add chain).
__global__ void k_gather(const int* __restrict__ rowptr, const int* __restrict__ csr_src,
                         const unsigned char* __restrict__ Qf8,
                         const float* __restrict__ b,
                         const float* __restrict__ dinv, ushort* __restrict__ Ph) {
  int node = blockIdx.x * 8 + (threadIdx.x >> 5);
  if (node >= NN) return;
  int lane = threadIdx.x & 31;
  const unsigned* __restrict__ Q4 = (const unsigned*)Qf8;
  float4 accA = {0.f, 0.f, 0.f, 0.f};
  float4 accB = {0.f, 0.f, 0.f, 0.f};
  int e0 = rowptr[node], e1 = rowptr[node + 1];
  int e = e0;
  for (; e + 7 < e1; e += 8) {
    unsigned q0 = Q4[(size_t)csr_src[e]     * 32 + lane];
    unsigned q1 = Q4[(size_t)csr_src[e + 1] * 32 + lane];
    unsigned q2 = Q4[(size_t)csr_src[e + 2] * 32 + lane];
    unsigned q3 = Q4[(size_t)csr_src[e + 3] * 32 + lane];
    unsigned q4 = Q4[(size_t)csr_src[e + 4] * 32 + lane];
    unsigned q5 = Q4[(size_t)csr_src[e + 5] * 32 + lane];
    unsigned q6 = Q4[(size_t)csr_src[e + 6] * 32 + lane];
    unsigned q7 = Q4[(size_t)csr_src[e + 7] * 32 + lane];
    dec8acc(q0, accA); dec8acc(q1, accB);
    dec8acc(q2, accA); dec8acc(q3, accB);
    dec8acc(q4, accA); dec8acc(q5, accB);
    dec8acc(q6, accA); dec8acc(q7, accB);
  }
  for (; e + 3 < e1; e += 4) {
    unsigned q0 = Q4[(size_t)csr_src[e]     * 32 + lane];
    unsigned q1 = Q4[(size_t)csr_src[e + 1] * 32 + lane];
    unsigned q2 = Q4[(size_t)csr_src[e + 2] * 32 + lane];
    unsigned q3 = Q4[(size_t)csr_src[e + 3] * 32 + lane];
    dec8acc(q0, accA); dec8acc(q1, accB);
    dec8acc(q2, accA); dec8acc(q3, accB);
  }
  for (; e < e1; ++e) {
    unsigned q0 = Q4[(size_t)csr_src[e] * 32 + lane];
    dec8acc(q0, accA);
  }
  float4 acc;
  acc.x = accA.x + accB.x; acc.y = accA.y + accB.y;
  acc.z = accA.z + accB.z; acc.w = accA.w + accB.w;
#if HAVE_DEC
  float di = dinv[node];
#else
  float di = dinv[node] * 256.0f;
#endif
  float4 bv = ((const float4*)b)[lane];
  acc.x = fmaxf(fmaf(di, acc.x, bv.x), 0.f);
  acc.y = fmaxf(fmaf(di, acc.y, bv.y), 0.f);
  acc.z = fmaxf(fmaf(di, acc.z, bv.z), 0.f);
  acc.w = fmaxf(fmaf(di, acc.w, bv.w), 0.f);
  ushort4 h;
  h.x = f2bf(acc.x); h.y = f2bf(acc.y); h.z = f2bf(acc.z); h.w = f2bf(acc.w);
  ((ushort4*)Ph)[(size_t)node * 32 + lane] = h;
}

// ---------- pooling + head ----------

__global__ void k_zero_pool(float* __restrict__ sums, float* __restrict__ counts) {
  int t = blockIdx.x * 256 + threadIdx.x;
  if (t < NG * FD) sums[t] = 0.f;
  if (t < NG) counts[t] = 0.f;
}

#define POOL_BLOCKS 1024
#define POOL_CHUNK 98
__global__ void k_pool(const int* __restrict__ batch, const ushort* __restrict__ Ph,
                       float* __restrict__ sums, float* __restrict__ counts) {
  int f = threadIdx.x;  // 0..127
  int i0 = blockIdx.x * POOL_CHUNK;
  if (i0 >= NN) return;
  int i1 = i0 + POOL_CHUNK;
  if (i1 > NN) i1 = NN;
  float acc = 0.f;
  int gcur = batch[i0];
  int cnt = 0;
  for (int i = i0; i < i1; ++i) {
    int g = batch[i];
    if (g != gcur) {
      atomicAdd(&sums[gcur * FD + f], acc);
      if (f == 0) atomicAdd(&counts[gcur], (float)cnt);
      acc = 0.f; cnt = 0; gcur = g;
    }
    acc += bf2f(Ph[(size_t)i * FD + f]);
    ++cnt;
  }
  atomicAdd(&sums[gcur * FD + f], acc);
  if (f == 0) atomicAdd(&counts[gcur], (float)cnt);
}

__global__ void k_head(const float* __restrict__ sums, const float* __restrict__ counts,
                       const float* __restrict__ Wm, const float* __restrict__ bm,
                       float* __restrict__ out) {
  int t = blockIdx.x * 256 + threadIdx.x;
  if (t >= NG * NC) return;
  int g = t / NC, c = t % NC;
  float inv = 1.0f / fmaxf(counts[g], 1.0f);
  float s = 0.f;
#pragma unroll 4
  for (int f = 0; f < FD; ++f) s = fmaf(sums[g * FD + f] * inv, Wm[f * NC + c], s);
  out[t] = s + bm[c];
}

extern "C" void kernel_launch(void* const* d_in, const int* in_sizes, int n_in,
                              void* d_out, int out_size, void* d_ws, size_t ws_size,
                              hipStream_t stream) {
  const float* x     = (const float*)d_in[0];
  const int*   ei    = (const int*)d_in[1];
  const int*   batch = (const int*)d_in[2];
  const float* W_in  = (const float*)d_in[3];
  const float* b_in  = (const float*)d_in[4];
  const float* W_mid = (const float*)d_in[5];
  const float* b_mid = (const float*)d_in[6];
  const float* W_mlp = (const float*)d_in[7];
  const float* b_mlp = (const float*)d_in[8];
  float* out = (float*)d_out;

  const int* src = ei;        // edge_index[0]
  const int* dst = ei + NE;   // edge_index[1]

  char* ws = (char*)d_ws;
  unsigned char* Qf8 = (unsigned char*)ws;  ws += (size_t)NN * FD;     // 12.8 MB
  ushort*   Ph      = (ushort*)ws;    ws += (size_t)NN * FD * 2;       // 25.6 MB
  float*    dinv    = (float*)ws;     ws += (size_t)NN * 4;
  int*      rowptr  = (int*)ws;       ws += (size_t)(NN + 1) * 4;
  int*      csr_src = (int*)ws;       ws += (size_t)NT * 4;            // 6.8 MB
  unsigned* binned  = (unsigned*)ws;  ws += (size_t)NE * 4;            // 6.4 MB
  int*      histG   = (int*)ws;       ws += (size_t)NBC2 * 4;          // 400 KB
  int*      boffC   = (int*)ws;       ws += (size_t)(NBC2 + 1) * 4;
  int*      cSums   = (int*)ws;       ws += 256 * 4;
  int*      cOffs   = (int*)ws;       ws += 256 * 4;
  ushort*   WhA     = (ushort*)ws;    ws += (size_t)FD * FD * 2;
  ushort*   WlA     = (ushort*)ws;    ws += (size_t)FD * FD * 2;
  ushort*   WhB     = (ushort*)ws;    ws += (size_t)FD * FD * 2;
  ushort*   WlB     = (ushort*)ws;    ws += (size_t)FD * FD * 2;
  float*    sums    = (float*)ws;     ws += (size_t)NG * FD * 4;
  float*    counts  = (float*)ws;     ws += (size_t)NG * 4;

  // chunked binned CSR build (incl. self-loops; reused by all 4 layers)
  k_hist<<<NCH, 256, 0, stream>>>(dst, histG);
  k_s2A<<<SCB2, 256, 0, stream>>>(histG, cSums);
  k_s2B<<<1, 256, 0, stream>>>(cSums, cOffs, boffC);
  k_s2C<<<SCB2, 256, 0, stream>>>(histG, cOffs, boffC);
  k_chscatter<<<NCH, 256, 0, stream>>>(src, dst, boffC, binned);
  k_csr_bucket<<<NBKT, 256, 0, stream>>>(boffC, binned, rowptr, dinv, csr_src);

  // weight packing (W^T fragment order) + input conversion
  k_packW<<<(FD * FD + 255) / 256, 256, 0, stream>>>(W_in, WhA, WlA);
  k_packW<<<(FD * FD + 255) / 256, 256, 0, stream>>>(W_mid, WhB, WlB);
  k_cvt<<<(NN * FD / 4 + 255) / 256, 256, 0, stream>>>(x, Ph);

  const int gM = (NN + 127) / 128;   // 782 blocks, 128 rows each
  const int gG = (NN + 7) / 8;       // 12500 blocks, 8 nodes each
  for (int L = 0; L < 4; ++L) {
    const ushort* Wh = (L == 0) ? WhA : WhB;
    const ushort* Wl = (L == 0) ? WlA : WlB;
    const float*  b  = (L == 0) ? b_in : b_mid;
    k_gemm_mfma<<<gM, 256, 0, stream>>>(Ph, Wh, Wl, dinv, Qf8);
    k_gather<<<gG, 256, 0, stream>>>(rowptr, csr_src, Qf8, b, dinv, Ph);
  }

  k_zero_pool<<<32, 256, 0, stream>>>(sums, counts);
  k_pool<<<POOL_BLOCKS, 128, 0, stream>>>(batch, Ph, sums, counts);
  k_head<<<(NG * NC + 255) / 256, 256, 0, stream>>>(sums, counts, W_mlp, b_mlp, out);
}

// Round 19
// 355.938 us; speedup vs baseline: 1.8568x; 1.0299x over previous
//
#include <hip/hip_runtime.h>

#define NN 100000
#define NE 1600000
#define NT (NE + NN)     // edges incl. self-loops
#define FD 128
#define NC 10
#define NG 64

#define NBKT ((NN + 127) >> 7)   // 782 buckets of 128 nodes
#define NCH 128                  // edge chunks
#define CH (NE / NCH)            // 12500 edges per chunk
#define NBC2 (NBKT * NCH)        // 100096 (bucket, chunk) counters
#define SCB2 196                 // 196*512 = 100352 >= NBC2
#define CAP 3072                 // LDS edge cap per bucket (mean 2046, sigma ~45)

#if __has_builtin(__builtin_amdgcn_cvt_pk_f32_fp8)
#define HAVE_DEC 1
#else
#define HAVE_DEC 0
#endif
#if __has_builtin(__builtin_amdgcn_cvt_pk_fp8_f32)
#define HAVE_ENC 1
#else
#define HAVE_ENC 0
#endif

typedef __attribute__((ext_vector_type(8))) short short8v;   // 8 bf16 (4 VGPRs)
typedef __attribute__((ext_vector_type(4))) float f32x4;
typedef __attribute__((ext_vector_type(2))) float f32x2;
typedef _Float16 half2v __attribute__((ext_vector_type(2)));

__device__ inline ushort f2bf(float x) {                     // round-to-nearest-even
  unsigned u = __float_as_uint(x);
  return (ushort)((u + 0x7FFF + ((u >> 16) & 1)) >> 16);
}
__device__ inline float bf2f(ushort h) { return __uint_as_float(((unsigned)h) << 16); }

// software e4m3fn encode (fallback)
__device__ inline unsigned char f2e4m3(float x) {
  x = fminf(fmaxf(x, -448.f), 448.f);
  _Float16 hf = (_Float16)(x * 0.00390625f);
  unsigned short b = __builtin_bit_cast(unsigned short, hf);
  unsigned short r = (unsigned short)((b & 0x7fff) + 0x3F + ((b >> 7) & 1));
  return (unsigned char)(((r >> 7) & 0x7f) | ((b >> 8) & 0x80));
}

// pack 4 f32 -> 4 e4m3 bytes in one dword (HW cvt_pk when available)
__device__ inline unsigned pack4e4m3(float v0, float v1, float v2, float v3) {
#if HAVE_ENC
  unsigned w = (unsigned)__builtin_amdgcn_cvt_pk_fp8_f32(v0, v1, 0, false);
  w = (unsigned)__builtin_amdgcn_cvt_pk_fp8_f32(v2, v3, (int)w, true);
  return w;
#else
  return (unsigned)f2e4m3(v0) | ((unsigned)f2e4m3(v1) << 8) |
         ((unsigned)f2e4m3(v2) << 16) | ((unsigned)f2e4m3(v3) << 24);
#endif
}

#if !HAVE_DEC
__device__ inline float dot2acc(half2v a, half2v b, float c) {
#if __has_builtin(__builtin_amdgcn_fdot2)
  return __builtin_amdgcn_fdot2(a, b, c, false);
#else
  return c + (float)a[0] * (float)b[0] + (float)a[1] * (float)b[1];
#endif
}
__device__ inline half2v d2(unsigned p) {
  p = ((p >> 1) & 0x3f803f80u) | (p & 0x80008000u);
  return __builtin_bit_cast(half2v, p);
}
#endif

// accumulate 4 e4m3 features (one u32) into acc
__device__ inline void dec8acc(unsigned q, float4& acc) {
#if HAVE_DEC
  f32x2 lo = __builtin_amdgcn_cvt_pk_f32_fp8((int)q, false);
  f32x2 hi = __builtin_amdgcn_cvt_pk_f32_fp8((int)q, true);
  acc.x += lo[0]; acc.y += lo[1]; acc.z += hi[0]; acc.w += hi[1];
#else
  const half2v ones = {(_Float16)1.0f, (_Float16)1.0f};
  acc.x = dot2acc(d2(__builtin_amdgcn_perm(0u, q, 0x0c0c000cu)), ones, acc.x);
  acc.y = dot2acc(d2(__builtin_amdgcn_perm(0u, q, 0x0c0c010cu)), ones, acc.y);
  acc.z = dot2acc(d2(__builtin_amdgcn_perm(0u, q, 0x0c0c020cu)), ones, acc.z);
  acc.w = dot2acc(d2(__builtin_amdgcn_perm(0u, q, 0x0c0c030cu)), ones, acc.w);
#endif
}

// ---------- chunked-LDS binned CSR build (no global atomics) ----------

__global__ __launch_bounds__(256) void k_hist(const int* __restrict__ dst,
                                              int* __restrict__ histG) {
  __shared__ int hist[NBKT];
  int tid = threadIdx.x, chunk = blockIdx.x;
  for (int i = tid; i < NBKT; i += 256) hist[i] = 0;
  __syncthreads();
  int e0 = chunk * CH;
  for (int i = tid; i < CH; i += 256)
    atomicAdd(&hist[dst[e0 + i] >> 7], 1);
  __syncthreads();
  for (int i = tid; i < NBKT; i += 256) histG[i * NCH + chunk] = hist[i];
}

__global__ void k_s2A(const int* __restrict__ cnt, int* __restrict__ blockSums) {
  __shared__ int red[256];
  int t = threadIdx.x, b = blockIdx.x;
  int i0 = b * 512 + t * 2;
  int s = 0;
#pragma unroll
  for (int j = 0; j < 2; ++j) { int i = i0 + j; if (i < NBC2) s += cnt[i]; }
  red[t] = s;
  __syncthreads();
  for (int off = 128; off > 0; off >>= 1) {
    if (t < off) red[t] += red[t + off];
    __syncthreads();
  }
  if (t == 0) blockSums[b] = red[0];
}

__global__ void k_s2B(const int* __restrict__ blockSums, int* __restrict__ blockOffs,
                      int* __restrict__ boffC) {
  __shared__ int sh[256];
  int t = threadIdx.x;
  int v = (t < SCB2) ? blockSums[t] : 0;
  sh[t] = v;
  __syncthreads();
  for (int off = 1; off < 256; off <<= 1) {
    int u = (t >= off) ? sh[t - off] : 0;
    __syncthreads();
    sh[t] += u;
    __syncthreads();
  }
  if (t < SCB2) blockOffs[t] = sh[t] - v;   // exclusive
  if (t == 255) boffC[NBC2] = sh[255];      // = NE
}

__global__ void k_s2C(const int* __restrict__ cnt, const int* __restrict__ blockOffs,
                      int* __restrict__ boffC) {
  __shared__ int sh[256];
  int t = threadIdx.x, b = blockIdx.x;
  int i0 = b * 512 + t * 2;
  int c[2];
  int s = 0;
#pragma unroll
  for (int j = 0; j < 2; ++j) {
    int i = i0 + j;
    c[j] = (i < NBC2) ? cnt[i] : 0;
    s += c[j];
  }
  sh[t] = s;
  __syncthreads();
  for (int off = 1; off < 256; off <<= 1) {
    int u = (t >= off) ? sh[t - off] : 0;
    __syncthreads();
    sh[t] += u;
    __syncthreads();
  }
  int run = blockOffs[b] + sh[t] - s;
#pragma unroll
  for (int j = 0; j < 2; ++j) {
    int i = i0 + j;
    if (i < NBC2) { boffC[i] = run; run += c[j]; }
  }
}

__global__ __launch_bounds__(256) void k_chscatter(const int* __restrict__ src,
                                                   const int* __restrict__ dst,
                                                   const int* __restrict__ boffC,
                                                   unsigned* __restrict__ binned) {
  __shared__ int curs[NBKT];
  int tid = threadIdx.x, chunk = blockIdx.x;
  for (int i = tid; i < NBKT; i += 256) curs[i] = boffC[i * NCH + chunk];
  __syncthreads();
  int e0 = chunk * CH;
  for (int i = tid; i < CH; i += 256) {
    int e = e0 + i;
    int d = dst[e], s = src[e];
    int slot = atomicAdd(&curs[d >> 7], 1);
    binned[slot] = ((unsigned)(d & 127) << 17) | (unsigned)s;
  }
}

__global__ __launch_bounds__(256) void k_csr_bucket(
    const int* __restrict__ boffC, const unsigned* __restrict__ binned,
    int* __restrict__ rowptr, float* __restrict__ dinv, int* __restrict__ csr_src) {
  __shared__ unsigned varr[CAP];
  __shared__ int earr[CAP + 128];
  __shared__ int deg[128];
  __shared__ int sh[128];
  int b = blockIdx.x, tid = threadIdx.x;
  int e0 = boffC[b * NCH], e1 = boffC[(b + 1) * NCH], seg = e1 - e0;
  int n0 = b << 7;
  int nb = NN - n0; if (nb > 128) nb = 128;
  int gbase = e0 + n0;                      // + one self per preceding node
  if (tid < 128) deg[tid] = 0;
  __syncthreads();
  bool fast = (seg <= CAP);
  if (fast) {
    for (int i = tid; i < seg; i += 256) {
      unsigned v = binned[e0 + i];
      varr[i] = v;
      atomicAdd(&deg[(v >> 17) & 127], 1);
    }
  } else {
    for (int i = tid; i < seg; i += 256) {
      unsigned v = binned[e0 + i];
      atomicAdd(&deg[(v >> 17) & 127], 1);
    }
  }
  __syncthreads();
  int dl = 0;
  if (tid < 128) {
    dl = (tid < nb) ? deg[tid] + 1 : 0;     // +1 self-loop
    sh[tid] = dl;
  }
  __syncthreads();
  for (int off = 1; off < 128; off <<= 1) {
    int u = 0;
    if (tid < 128 && tid >= off) u = sh[tid - off];
    __syncthreads();
    if (tid < 128) sh[tid] += u;
    __syncthreads();
  }
  int excl = 0;
  if (tid < nb) {
    excl = sh[tid] - dl;
    rowptr[n0 + tid] = gbase + excl;
    dinv[n0 + tid] = rsqrtf((float)dl);
    if (fast) earr[excl] = n0 + tid;        // self-loop in first slot
    else      csr_src[gbase + excl] = n0 + tid;
  }
  __syncthreads();
  if (tid < 128) deg[tid] = (tid < nb) ? (excl + 1) : 0;   // cursor after self
  __syncthreads();
  if (fast) {
    for (int i = tid; i < seg; i += 256) {
      unsigned v = varr[i];
      int l = (v >> 17) & 127;
      int pos = atomicAdd(&deg[l], 1);
      earr[pos] = (int)(v & 0x1FFFF);
    }
    __syncthreads();
    int tot = seg + nb;
    for (int i = tid; i < tot; i += 256) csr_src[gbase + i] = earr[i];
  } else {
    for (int i = tid; i < seg; i += 256) {
      unsigned v = binned[e0 + i];
      int l = (v >> 17) & 127;
      int pos = atomicAdd(&deg[l], 1);
      csr_src[gbase + pos] = (int)(v & 0x1FFFF);
    }
  }
  if (b == 0 && tid == 0) rowptr[NN] = NT;
}

// ---------- prep: x -> bf16, W -> packed W^T MFMA A-fragments (hi/lo) ----------

__global__ void k_cvt(const float* __restrict__ X, ushort* __restrict__ Hh) {
  int t = blockIdx.x * 256 + threadIdx.x;
  if (t >= NN * FD / 4) return;
  float4 v = ((const float4*)X)[t];
  ushort4 h;
  h.x = f2bf(v.x); h.y = f2bf(v.y); h.z = f2bf(v.z); h.w = f2bf(v.w);
  ((ushort4*)Hh)[t] = h;
}

// W[k][col] -> W^T A-fragment order for the TRANSPOSED gemm:
// tile (nt = col>>4, kc = k>>5); lane = (col&15) + 16*((k>>3)&3); elem i = k&7
__global__ void k_packW(const float* __restrict__ W, ushort* __restrict__ Wh,
                        ushort* __restrict__ Wl) {
  int idx = blockIdx.x * 256 + threadIdx.x;
  if (idx >= FD * FD) return;
  int k = idx >> 7, col = idx & 127;
  float v = W[idx];
  ushort h = f2bf(v);
  ushort l = f2bf(v - bf2f(h));
  int nt = col >> 4, kc = k >> 5;
  int lane = (col & 15) + ((k >> 3) & 3) * 16;
  size_t o = (((size_t)(nt * 4 + kc)) * 64 + lane) * 8 + (k & 7);
  Wh[o] = h; Wl[o] = l;
}

// ---------- transposed MFMA GEMM: Q^T tiles = (Wt_h+Wt_l) @ X^T ----------
// 64 rows/wave (4x 16-node groups): W fragment loads amortized over 4
// independent MFMA chains (halves W L2 traffic, 4x ILP).
__global__ __launch_bounds__(256, 4) void k_gemm_mfma(
    const ushort* __restrict__ Ah,
    const ushort* __restrict__ Wth, const ushort* __restrict__ Wtl,
    const float* __restrict__ dinv, unsigned char* __restrict__ Qf8) {
  int tid = threadIdx.x;
  int wave = tid >> 6, lane = tid & 63;
  int m15 = lane & 15, k0 = lane >> 4;
  int row0 = blockIdx.x * 256 + wave * 64;

  int n0 = row0 + m15, n1 = row0 + 16 + m15;
  int n2 = row0 + 32 + m15, n3 = row0 + 48 + m15;
  int a0 = (n0 >= NN) ? NN - 1 : n0;
  int a1 = (n1 >= NN) ? NN - 1 : n1;
  int a2 = (n2 >= NN) ? NN - 1 : n2;
  int a3 = (n3 >= NN) ? NN - 1 : n3;
  short8v x0[4], x1[4], x2[4], x3[4];
#pragma unroll
  for (int kc = 0; kc < 4; ++kc) {
    x0[kc] = *(const short8v*)(Ah + (size_t)a0 * FD + kc * 32 + k0 * 8);
    x1[kc] = *(const short8v*)(Ah + (size_t)a1 * FD + kc * 32 + k0 * 8);
    x2[kc] = *(const short8v*)(Ah + (size_t)a2 * FD + kc * 32 + k0 * 8);
    x3[kc] = *(const short8v*)(Ah + (size_t)a3 * FD + kc * 32 + k0 * 8);
  }
  float dv0 = (n0 < NN) ? dinv[n0] : 0.f;
  float dv1 = (n1 < NN) ? dinv[n1] : 0.f;
  float dv2 = (n2 < NN) ? dinv[n2] : 0.f;
  float dv3 = (n3 < NN) ? dinv[n3] : 0.f;

#pragma unroll
  for (int nt = 0; nt < 8; ++nt) {
    f32x4 acc0 = {0.f, 0.f, 0.f, 0.f};
    f32x4 acc1 = {0.f, 0.f, 0.f, 0.f};
    f32x4 acc2 = {0.f, 0.f, 0.f, 0.f};
    f32x4 acc3 = {0.f, 0.f, 0.f, 0.f};
#pragma unroll
    for (int kc = 0; kc < 4; ++kc) {
      size_t off = (((size_t)(nt * 4 + kc)) * 64 + lane) * 8;
      short8v wh = *(const short8v*)(Wth + off);
      short8v wl = *(const short8v*)(Wtl + off);
      acc0 = __builtin_amdgcn_mfma_f32_16x16x32_bf16(wh, x0[kc], acc0, 0, 0, 0);
      acc1 = __builtin_amdgcn_mfma_f32_16x16x32_bf16(wh, x1[kc], acc1, 0, 0, 0);
      acc2 = __builtin_amdgcn_mfma_f32_16x16x32_bf16(wh, x2[kc], acc2, 0, 0, 0);
      acc3 = __builtin_amdgcn_mfma_f32_16x16x32_bf16(wh, x3[kc], acc3, 0, 0, 0);
      acc0 = __builtin_amdgcn_mfma_f32_16x16x32_bf16(wl, x0[kc], acc0, 0, 0, 0);
      acc1 = __builtin_amdgcn_mfma_f32_16x16x32_bf16(wl, x1[kc], acc1, 0, 0, 0);
      acc2 = __builtin_amdgcn_mfma_f32_16x16x32_bf16(wl, x2[kc], acc2, 0, 0, 0);
      acc3 = __builtin_amdgcn_mfma_f32_16x16x32_bf16(wl, x3[kc], acc3, 0, 0, 0);
    }
    int colb = nt * 16 + k0 * 4;
    if (n0 < NN)
      *(unsigned*)(Qf8 + (size_t)n0 * FD + colb) =
          pack4e4m3(dv0 * acc0[0], dv0 * acc0[1], dv0 * acc0[2], dv0 * acc0[3]);
    if (n1 < NN)
      *(unsigned*)(Qf8 + (size_t)n1 * FD + colb) =
          pack4e4m3(dv1 * acc1[0], dv1 * acc1[1], dv1 * acc1[2], dv1 * acc1[3]);
    if (n2 < NN)
      *(unsigned*)(Qf8 + (size_t)n2 * FD + colb) =
          pack4e4m3(dv2 * acc2[0], dv2 * acc2[1], dv2 * acc2[2], dv2 * acc2[3]);
    if (n3 < NN)
      *(unsigned*)(Qf8 + (size_t)n3 * FD + colb) =
          pack4e4m3(dv3 * acc3[0], dv3 * acc3[1], dv3 * acc3[2], dv3 * acc3[3]);
  }
}

// ---------- gather: Ph = bf16( relu( scale*sum_e dec(Qf8[src_e]) + b ) ) ----------
// 32 lanes/node, u32/lane; 8 edges in flight, dual accumulators.
__global__ void k_gather(const int* __restrict__ rowptr, const int* __restrict__ csr_src,
                         const unsigned char* __restrict__ Qf8,
                         const float* __restrict__ b,
                         const float* __restrict__ dinv, ushort* __restrict__ Ph) {
  int node = blockIdx.x * 8 + (threadIdx.x >> 5);
  if (node >= NN) return;
  int lane = threadIdx.x & 31;
  const unsigned* __restrict__ Q4 = (const unsigned*)Qf8;
  float4 accA = {0.f, 0.f, 0.f, 0.f};
  float4 accB = {0.f, 0.f, 0.f, 0.f};
  int e0 = rowptr[node], e1 = rowptr[node + 1];
  int e = e0;
  for (; e + 7 < e1; e += 8) {
    unsigned q0 = Q4[(size_t)csr_src[e]     * 32 + lane];
    unsigned q1 = Q4[(size_t)csr_src[e + 1] * 32 + lane];
    unsigned q2 = Q4[(size_t)csr_src[e + 2] * 32 + lane];
    unsigned q3 = Q4[(size_t)csr_src[e + 3] * 32 + lane];
    unsigned q4 = Q4[(size_t)csr_src[e + 4] * 32 + lane];
    unsigned q5 = Q4[(size_t)csr_src[e + 5] * 32 + lane];
    unsigned q6 = Q4[(size_t)csr_src[e + 6] * 32 + lane];
    unsigned q7 = Q4[(size_t)csr_src[e + 7] * 32 + lane];
    dec8acc(q0, accA); dec8acc(q1, accB);
    dec8acc(q2, accA); dec8acc(q3, accB);
    dec8acc(q4, accA); dec8acc(q5, accB);
    dec8acc(q6, accA); dec8acc(q7, accB);
  }
  for (; e + 3 < e1; e += 4) {
    unsigned q0 = Q4[(size_t)csr_src[e]     * 32 + lane];
    unsigned q1 = Q4[(size_t)csr_src[e + 1] * 32 + lane];
    unsigned q2 = Q4[(size_t)csr_src[e + 2] * 32 + lane];
    unsigned q3 = Q4[(size_t)csr_src[e + 3] * 32 + lane];
    dec8acc(q0, accA); dec8acc(q1, accB);
    dec8acc(q2, accA); dec8acc(q3, accB);
  }
  for (; e < e1; ++e) {
    unsigned q0 = Q4[(size_t)csr_src[e] * 32 + lane];
    dec8acc(q0, accA);
  }
  float4 acc;
  acc.x = accA.x + accB.x; acc.y = accA.y + accB.y;
  acc.z = accA.z + accB.z; acc.w = accA.w + accB.w;
#if HAVE_DEC
  float di = dinv[node];
#else
  float di = dinv[node] * 256.0f;
#endif
  float4 bv = ((const float4*)b)[lane];
  acc.x = fmaxf(fmaf(di, acc.x, bv.x), 0.f);
  acc.y = fmaxf(fmaf(di, acc.y, bv.y), 0.f);
  acc.z = fmaxf(fmaf(di, acc.z, bv.z), 0.f);
  acc.w = fmaxf(fmaf(di, acc.w, bv.w), 0.f);
  ushort4 h;
  h.x = f2bf(acc.x); h.y = f2bf(acc.y); h.z = f2bf(acc.z); h.w = f2bf(acc.w);
  ((ushort4*)Ph)[(size_t)node * 32 + lane] = h;
}

// ---------- pooling + head ----------

__global__ void k_zero_pool(float* __restrict__ sums, float* __restrict__ counts) {
  int t = blockIdx.x * 256 + threadIdx.x;
  if (t < NG * FD) sums[t] = 0.f;
  if (t < NG) counts[t] = 0.f;
}

#define POOL_BLOCKS 1024
#define POOL_CHUNK 98
__global__ void k_pool(const int* __restrict__ batch, const ushort* __restrict__ Ph,
                       float* __restrict__ sums, float* __restrict__ counts) {
  int f = threadIdx.x;  // 0..127
  int i0 = blockIdx.x * POOL_CHUNK;
  if (i0 >= NN) return;
  int i1 = i0 + POOL_CHUNK;
  if (i1 > NN) i1 = NN;
  float acc = 0.f;
  int gcur = batch[i0];
  int cnt = 0;
  for (int i = i0; i < i1; ++i) {
    int g = batch[i];
    if (g != gcur) {
      atomicAdd(&sums[gcur * FD + f], acc);
      if (f == 0) atomicAdd(&counts[gcur], (float)cnt);
      acc = 0.f; cnt = 0; gcur = g;
    }
    acc += bf2f(Ph[(size_t)i * FD + f]);
    ++cnt;
  }
  atomicAdd(&sums[gcur * FD + f], acc);
  if (f == 0) atomicAdd(&counts[gcur], (float)cnt);
}

__global__ void k_head(const float* __restrict__ sums, const float* __restrict__ counts,
                       const float* __restrict__ Wm, const float* __restrict__ bm,
                       float* __restrict__ out) {
  int t = blockIdx.x * 256 + threadIdx.x;
  if (t >= NG * NC) return;
  int g = t / NC, c = t % NC;
  float inv = 1.0f / fmaxf(counts[g], 1.0f);
  float s = 0.f;
#pragma unroll 4
  for (int f = 0; f < FD; ++f) s = fmaf(sums[g * FD + f] * inv, Wm[f * NC + c], s);
  out[t] = s + bm[c];
}

extern "C" void kernel_launch(void* const* d_in, const int* in_sizes, int n_in,
                              void* d_out, int out_size, void* d_ws, size_t ws_size,
                              hipStream_t stream) {
  const float* x     = (const float*)d_in[0];
  const int*   ei    = (const int*)d_in[1];
  const int*   batch = (const int*)d_in[2];
  const float* W_in  = (const float*)d_in[3];
  const float* b_in  = (const float*)d_in[4];
  const float* W_mid = (const float*)d_in[5];
  const float* b_mid = (const float*)d_in[6];
  const float* W_mlp = (const float*)d_in[7];
  const float* b_mlp = (const float*)d_in[8];
  float* out = (float*)d_out;

  const int* src = ei;        // edge_index[0]
  const int* dst = ei + NE;   // edge_index[1]

  char* ws = (char*)d_ws;
  unsigned char* Qf8 = (unsigned char*)ws;  ws += (size_t)NN * FD;     // 12.8 MB
  ushort*   Ph      = (ushort*)ws;    ws += (size_t)NN * FD * 2;       // 25.6 MB
  float*    dinv    = (float*)ws;     ws += (size_t)NN * 4;
  int*      rowptr  = (int*)ws;       ws += (size_t)(NN + 1) * 4;
  int*      csr_src = (int*)ws;       ws += (size_t)NT * 4;            // 6.8 MB
  unsigned* binned  = (unsigned*)ws;  ws += (size_t)NE * 4;            // 6.4 MB
  int*      histG   = (int*)ws;       ws += (size_t)NBC2 * 4;          // 400 KB
  int*      boffC   = (int*)ws;       ws += (size_t)(NBC2 + 1) * 4;
  int*      cSums   = (int*)ws;       ws += 256 * 4;
  int*      cOffs   = (int*)ws;       ws += 256 * 4;
  ushort*   WhA     = (ushort*)ws;    ws += (size_t)FD * FD * 2;
  ushort*   WlA     = (ushort*)ws;    ws += (size_t)FD * FD * 2;
  ushort*   WhB     = (ushort*)ws;    ws += (size_t)FD * FD * 2;
  ushort*   WlB     = (ushort*)ws;    ws += (size_t)FD * FD * 2;
  float*    sums    = (float*)ws;     ws += (size_t)NG * FD * 4;
  float*    counts  = (float*)ws;     ws += (size_t)NG * 4;

  // chunked binned CSR build (incl. self-loops; reused by all 4 layers)
  k_hist<<<NCH, 256, 0, stream>>>(dst, histG);
  k_s2A<<<SCB2, 256, 0, stream>>>(histG, cSums);
  k_s2B<<<1, 256, 0, stream>>>(cSums, cOffs, boffC);
  k_s2C<<<SCB2, 256, 0, stream>>>(histG, cOffs, boffC);
  k_chscatter<<<NCH, 256, 0, stream>>>(src, dst, boffC, binned);
  k_csr_bucket<<<NBKT, 256, 0, stream>>>(boffC, binned, rowptr, dinv, csr_src);

  // weight packing (W^T fragment order) + input conversion
  k_packW<<<(FD * FD + 255) / 256, 256, 0, stream>>>(W_in, WhA, WlA);
  k_packW<<<(FD * FD + 255) / 256, 256, 0, stream>>>(W_mid, WhB, WlB);
  k_cvt<<<(NN * FD / 4 + 255) / 256, 256, 0, stream>>>(x, Ph);

  const int gM = (NN + 255) / 256;   // 391 blocks, 256 rows each
  const int gG = (NN + 7) / 8;       // 12500 blocks, 8 nodes each
  for (int L = 0; L < 4; ++L) {
    const ushort* Wh = (L == 0) ? WhA : WhB;
    const ushort* Wl = (L == 0) ? WlA : WlB;
    const float*  b  = (L == 0) ? b_in : b_mid;
    k_gemm_mfma<<<gM, 256, 0, stream>>>(Ph, Wh, Wl, dinv, Qf8);
    k_gather<<<gG, 256, 0, stream>>>(rowptr, csr_src, Qf8, b, dinv, Ph);
  }

  k_zero_pool<<<32, 256, 0, stream>>>(sums, counts);
  k_pool<<<POOL_BLOCKS, 128, 0, stream>>>(batch, Ph, sums, counts);
  k_head<<<(NG * NC + 255) / 256, 256, 0, stream>>>(sums, counts, W_mlp, b_mlp, out);
}

// Round 20
// 343.780 us; speedup vs baseline: 1.9224x; 1.0354x over previous
//
#include <hip/hip_runtime.h>

#define NN 100000
#define NE 1600000
#define NT (NE + NN)     // edges incl. self-loops
#define FD 128
#define NC 10
#define NG 64

#define NBKT ((NN + 127) >> 7)   // 782 buckets of 128 nodes
#define NCH 128                  // edge chunks
#define CH (NE / NCH)            // 12500 edges per chunk
#define NBC2 (NBKT * NCH)        // 100096 (bucket, chunk) counters
#define SCB2 196                 // 196*512 = 100352 >= NBC2
#define CAP 3072                 // LDS edge cap per bucket (mean 2046, sigma ~45)

#if __has_builtin(__builtin_amdgcn_cvt_pk_f32_fp8)
#define HAVE_DEC 1
#else
#define HAVE_DEC 0
#endif
#if __has_builtin(__builtin_amdgcn_cvt_pk_fp8_f32)
#define HAVE_ENC 1
#else
#define HAVE_ENC 0
#endif

typedef __attribute__((ext_vector_type(8))) short short8v;   // 8 bf16 (4 VGPRs)
typedef __attribute__((ext_vector_type(4))) float f32x4;
typedef __attribute__((ext_vector_type(2))) float f32x2;
typedef _Float16 half2v __attribute__((ext_vector_type(2)));

__device__ inline ushort f2bf(float x) {                     // round-to-nearest-even
  unsigned u = __float_as_uint(x);
  return (ushort)((u + 0x7FFF + ((u >> 16) & 1)) >> 16);
}
__device__ inline float bf2f(ushort h) { return __uint_as_float(((unsigned)h) << 16); }

// software e4m3fn encode (fallback)
__device__ inline unsigned char f2e4m3(float x) {
  x = fminf(fmaxf(x, -448.f), 448.f);
  _Float16 hf = (_Float16)(x * 0.00390625f);
  unsigned short b = __builtin_bit_cast(unsigned short, hf);
  unsigned short r = (unsigned short)((b & 0x7fff) + 0x3F + ((b >> 7) & 1));
  return (unsigned char)(((r >> 7) & 0x7f) | ((b >> 8) & 0x80));
}

// pack 4 f32 -> 4 e4m3 bytes in one dword (HW cvt_pk when available)
__device__ inline unsigned pack4e4m3(float v0, float v1, float v2, float v3) {
#if HAVE_ENC
  unsigned w = (unsigned)__builtin_amdgcn_cvt_pk_fp8_f32(v0, v1, 0, false);
  w = (unsigned)__builtin_amdgcn_cvt_pk_fp8_f32(v2, v3, (int)w, true);
  return w;
#else
  return (unsigned)f2e4m3(v0) | ((unsigned)f2e4m3(v1) << 8) |
         ((unsigned)f2e4m3(v2) << 16) | ((unsigned)f2e4m3(v3) << 24);
#endif
}

#if !HAVE_DEC
__device__ inline float dot2acc(half2v a, half2v b, float c) {
#if __has_builtin(__builtin_amdgcn_fdot2)
  return __builtin_amdgcn_fdot2(a, b, c, false);
#else
  return c + (float)a[0] * (float)b[0] + (float)a[1] * (float)b[1];
#endif
}
__device__ inline half2v d2(unsigned p) {
  p = ((p >> 1) & 0x3f803f80u) | (p & 0x80008000u);
  return __builtin_bit_cast(half2v, p);
}
#endif

// accumulate 4 e4m3 features (one u32) into two f32x2 accs (v_pk_add_f32)
__device__ inline void dec8acc2(unsigned q, f32x2& aLo, f32x2& aHi) {
#if HAVE_DEC
  aLo += __builtin_amdgcn_cvt_pk_f32_fp8((int)q, false);
  aHi += __builtin_amdgcn_cvt_pk_f32_fp8((int)q, true);
#else
  const half2v ones = {(_Float16)1.0f, (_Float16)1.0f};
  aLo[0] = dot2acc(d2(__builtin_amdgcn_perm(0u, q, 0x0c0c000cu)), ones, aLo[0]);
  aLo[1] = dot2acc(d2(__builtin_amdgcn_perm(0u, q, 0x0c0c010cu)), ones, aLo[1]);
  aHi[0] = dot2acc(d2(__builtin_amdgcn_perm(0u, q, 0x0c0c020cu)), ones, aHi[0]);
  aHi[1] = dot2acc(d2(__builtin_amdgcn_perm(0u, q, 0x0c0c030cu)), ones, aHi[1]);
#endif
}

// ---------- chunked-LDS binned CSR build (no global atomics) ----------

__global__ __launch_bounds__(256) void k_hist(const int* __restrict__ dst,
                                              int* __restrict__ histG) {
  __shared__ int hist[NBKT];
  int tid = threadIdx.x, chunk = blockIdx.x;
  for (int i = tid; i < NBKT; i += 256) hist[i] = 0;
  __syncthreads();
  int e0 = chunk * CH;
  for (int i = tid; i < CH; i += 256)
    atomicAdd(&hist[dst[e0 + i] >> 7], 1);
  __syncthreads();
  for (int i = tid; i < NBKT; i += 256) histG[i * NCH + chunk] = hist[i];
}

__global__ void k_s2A(const int* __restrict__ cnt, int* __restrict__ blockSums) {
  __shared__ int red[256];
  int t = threadIdx.x, b = blockIdx.x;
  int i0 = b * 512 + t * 2;
  int s = 0;
#pragma unroll
  for (int j = 0; j < 2; ++j) { int i = i0 + j; if (i < NBC2) s += cnt[i]; }
  red[t] = s;
  __syncthreads();
  for (int off = 128; off > 0; off >>= 1) {
    if (t < off) red[t] += red[t + off];
    __syncthreads();
  }
  if (t == 0) blockSums[b] = red[0];
}

__global__ void k_s2B(const int* __restrict__ blockSums, int* __restrict__ blockOffs,
                      int* __restrict__ boffC) {
  __shared__ int sh[256];
  int t = threadIdx.x;
  int v = (t < SCB2) ? blockSums[t] : 0;
  sh[t] = v;
  __syncthreads();
  for (int off = 1; off < 256; off <<= 1) {
    int u = (t >= off) ? sh[t - off] : 0;
    __syncthreads();
    sh[t] += u;
    __syncthreads();
  }
  if (t < SCB2) blockOffs[t] = sh[t] - v;   // exclusive
  if (t == 255) boffC[NBC2] = sh[255];      // = NE
}

__global__ void k_s2C(const int* __restrict__ cnt, const int* __restrict__ blockOffs,
                      int* __restrict__ boffC) {
  __shared__ int sh[256];
  int t = threadIdx.x, b = blockIdx.x;
  int i0 = b * 512 + t * 2;
  int c[2];
  int s = 0;
#pragma unroll
  for (int j = 0; j < 2; ++j) {
    int i = i0 + j;
    c[j] = (i < NBC2) ? cnt[i] : 0;
    s += c[j];
  }
  sh[t] = s;
  __syncthreads();
  for (int off = 1; off < 256; off <<= 1) {
    int u = (t >= off) ? sh[t - off] : 0;
    __syncthreads();
    sh[t] += u;
    __syncthreads();
  }
  int run = blockOffs[b] + sh[t] - s;
#pragma unroll
  for (int j = 0; j < 2; ++j) {
    int i = i0 + j;
    if (i < NBC2) { boffC[i] = run; run += c[j]; }
  }
}

__global__ __launch_bounds__(256) void k_chscatter(const int* __restrict__ src,
                                                   const int* __restrict__ dst,
                                                   const int* __restrict__ boffC,
                                                   unsigned* __restrict__ binned) {
  __shared__ int curs[NBKT];
  int tid = threadIdx.x, chunk = blockIdx.x;
  for (int i = tid; i < NBKT; i += 256) curs[i] = boffC[i * NCH + chunk];
  __syncthreads();
  int e0 = chunk * CH;
  for (int i = tid; i < CH; i += 256) {
    int e = e0 + i;
    int d = dst[e], s = src[e];
    int slot = atomicAdd(&curs[d >> 7], 1);
    binned[slot] = ((unsigned)(d & 127) << 17) | (unsigned)s;
  }
}

__global__ __launch_bounds__(256) void k_csr_bucket(
    const int* __restrict__ boffC, const unsigned* __restrict__ binned,
    int* __restrict__ rowptr, float* __restrict__ dinv, int* __restrict__ csr_src) {
  __shared__ unsigned varr[CAP];
  __shared__ int earr[CAP + 128];
  __shared__ int deg[128];
  __shared__ int sh[128];
  int b = blockIdx.x, tid = threadIdx.x;
  int e0 = boffC[b * NCH], e1 = boffC[(b + 1) * NCH], seg = e1 - e0;
  int n0 = b << 7;
  int nb = NN - n0; if (nb > 128) nb = 128;
  int gbase = e0 + n0;                      // + one self per preceding node
  if (tid < 128) deg[tid] = 0;
  __syncthreads();
  bool fast = (seg <= CAP);
  if (fast) {
    for (int i = tid; i < seg; i += 256) {
      unsigned v = binned[e0 + i];
      varr[i] = v;
      atomicAdd(&deg[(v >> 17) & 127], 1);
    }
  } else {
    for (int i = tid; i < seg; i += 256) {
      unsigned v = binned[e0 + i];
      atomicAdd(&deg[(v >> 17) & 127], 1);
    }
  }
  __syncthreads();
  int dl = 0;
  if (tid < 128) {
    dl = (tid < nb) ? deg[tid] + 1 : 0;     // +1 self-loop
    sh[tid] = dl;
  }
  __syncthreads();
  for (int off = 1; off < 128; off <<= 1) {
    int u = 0;
    if (tid < 128 && tid >= off) u = sh[tid - off];
    __syncthreads();
    if (tid < 128) sh[tid] += u;
    __syncthreads();
  }
  int excl = 0;
  if (tid < nb) {
    excl = sh[tid] - dl;
    rowptr[n0 + tid] = gbase + excl;
    dinv[n0 + tid] = rsqrtf((float)dl);
    if (fast) earr[excl] = n0 + tid;        // self-loop in first slot
    else      csr_src[gbase + excl] = n0 + tid;
  }
  __syncthreads();
  if (tid < 128) deg[tid] = (tid < nb) ? (excl + 1) : 0;   // cursor after self
  __syncthreads();
  if (fast) {
    for (int i = tid; i < seg; i += 256) {
      unsigned v = varr[i];
      int l = (v >> 17) & 127;
      int pos = atomicAdd(&deg[l], 1);
      earr[pos] = (int)(v & 0x1FFFF);
    }
    __syncthreads();
    int tot = seg + nb;
    for (int i = tid; i < tot; i += 256) csr_src[gbase + i] = earr[i];
  } else {
    for (int i = tid; i < seg; i += 256) {
      unsigned v = binned[e0 + i];
      int l = (v >> 17) & 127;
      int pos = atomicAdd(&deg[l], 1);
      csr_src[gbase + pos] = (int)(v & 0x1FFFF);
    }
  }
  if (b == 0 && tid == 0) rowptr[NN] = NT;
}

// ---------- prep: x -> bf16, W -> packed W^T MFMA A-fragments (hi/lo) ----------

__global__ void k_cvt(const float* __restrict__ X, ushort* __restrict__ Hh) {
  int t = blockIdx.x * 256 + threadIdx.x;
  if (t >= NN * FD / 4) return;
  float4 v = ((const float4*)X)[t];
  ushort4 h;
  h.x = f2bf(v.x); h.y = f2bf(v.y); h.z = f2bf(v.z); h.w = f2bf(v.w);
  ((ushort4*)Hh)[t] = h;
}

// W[k][col] -> W^T A-fragment order for the TRANSPOSED gemm:
// tile (nt = col>>4, kc = k>>5); lane = (col&15) + 16*((k>>3)&3); elem i = k&7
__global__ void k_packW(const float* __restrict__ W, ushort* __restrict__ Wh,
                        ushort* __restrict__ Wl) {
  int idx = blockIdx.x * 256 + threadIdx.x;
  if (idx >= FD * FD) return;
  int k = idx >> 7, col = idx & 127;
  float v = W[idx];
  ushort h = f2bf(v);
  ushort l = f2bf(v - bf2f(h));
  int nt = col >> 4, kc = k >> 5;
  int lane = (col & 15) + ((k >> 3) & 3) * 16;
  size_t o = (((size_t)(nt * 4 + kc)) * 64 + lane) * 8 + (k & 7);
  Wh[o] = h; Wl[o] = l;
}

// ---------- transposed MFMA GEMM: Q^T tiles = (Wt_h+Wt_l) @ X^T ----------
// Packed W (hi+lo, 64KB) staged in LDS: fragment reads become conflict-free
// ds_read_b128 (stride-16B across 64 lanes) instead of ~200cy L2 hits.
// 64 rows/wave (4x 16-node groups), 4 independent MFMA chains.
__global__ __launch_bounds__(256, 2) void k_gemm_mfma(
    const ushort* __restrict__ Ah,
    const ushort* __restrict__ Wth, const ushort* __restrict__ Wtl,
    const float* __restrict__ dinv, unsigned char* __restrict__ Qf8) {
  __shared__ ushort WhL[FD * FD];   // 32 KB
  __shared__ ushort WlL[FD * FD];   // 32 KB
  int tid = threadIdx.x;
  {
    const float4* sh = (const float4*)Wth;
    const float4* sl = (const float4*)Wtl;
    float4* dh = (float4*)WhL;
    float4* dl = (float4*)WlL;
#pragma unroll
    for (int i = 0; i < FD * FD * 2 / 16 / 256; ++i) {   // 8 iters
      dh[tid + i * 256] = sh[tid + i * 256];
      dl[tid + i * 256] = sl[tid + i * 256];
    }
  }
  __syncthreads();

  int wave = tid >> 6, lane = tid & 63;
  int m15 = lane & 15, k0 = lane >> 4;
  int row0 = blockIdx.x * 256 + wave * 64;

  int n0 = row0 + m15, n1 = row0 + 16 + m15;
  int n2 = row0 + 32 + m15, n3 = row0 + 48 + m15;
  int a0 = (n0 >= NN) ? NN - 1 : n0;
  int a1 = (n1 >= NN) ? NN - 1 : n1;
  int a2 = (n2 >= NN) ? NN - 1 : n2;
  int a3 = (n3 >= NN) ? NN - 1 : n3;
  short8v x0[4], x1[4], x2[4], x3[4];
#pragma unroll
  for (int kc = 0; kc < 4; ++kc) {
    x0[kc] = *(const short8v*)(Ah + (size_t)a0 * FD + kc * 32 + k0 * 8);
    x1[kc] = *(const short8v*)(Ah + (size_t)a1 * FD + kc * 32 + k0 * 8);
    x2[kc] = *(const short8v*)(Ah + (size_t)a2 * FD + kc * 32 + k0 * 8);
    x3[kc] = *(const short8v*)(Ah + (size_t)a3 * FD + kc * 32 + k0 * 8);
  }
  float dv0 = (n0 < NN) ? dinv[n0] : 0.f;
  float dv1 = (n1 < NN) ? dinv[n1] : 0.f;
  float dv2 = (n2 < NN) ? dinv[n2] : 0.f;
  float dv3 = (n3 < NN) ? dinv[n3] : 0.f;

#pragma unroll
  for (int nt = 0; nt < 8; ++nt) {
    f32x4 acc0 = {0.f, 0.f, 0.f, 0.f};
    f32x4 acc1 = {0.f, 0.f, 0.f, 0.f};
    f32x4 acc2 = {0.f, 0.f, 0.f, 0.f};
    f32x4 acc3 = {0.f, 0.f, 0.f, 0.f};
#pragma unroll
    for (int kc = 0; kc < 4; ++kc) {
      int off = ((nt * 4 + kc) * 64 + lane) * 8;
      short8v wh = *(const short8v*)(WhL + off);
      short8v wl = *(const short8v*)(WlL + off);
      acc0 = __builtin_amdgcn_mfma_f32_16x16x32_bf16(wh, x0[kc], acc0, 0, 0, 0);
      acc1 = __builtin_amdgcn_mfma_f32_16x16x32_bf16(wh, x1[kc], acc1, 0, 0, 0);
      acc2 = __builtin_amdgcn_mfma_f32_16x16x32_bf16(wh, x2[kc], acc2, 0, 0, 0);
      acc3 = __builtin_amdgcn_mfma_f32_16x16x32_bf16(wh, x3[kc], acc3, 0, 0, 0);
      acc0 = __builtin_amdgcn_mfma_f32_16x16x32_bf16(wl, x0[kc], acc0, 0, 0, 0);
      acc1 = __builtin_amdgcn_mfma_f32_16x16x32_bf16(wl, x1[kc], acc1, 0, 0, 0);
      acc2 = __builtin_amdgcn_mfma_f32_16x16x32_bf16(wl, x2[kc], acc2, 0, 0, 0);
      acc3 = __builtin_amdgcn_mfma_f32_16x16x32_bf16(wl, x3[kc], acc3, 0, 0, 0);
    }
    int colb = nt * 16 + k0 * 4;
    if (n0 < NN)
      *(unsigned*)(Qf8 + (size_t)n0 * FD + colb) =
          pack4e4m3(dv0 * acc0[0], dv0 * acc0[1], dv0 * acc0[2], dv0 * acc0[3]);
    if (n1 < NN)
      *(unsigned*)(Qf8 + (size_t)n1 * FD + colb) =
          pack4e4m3(dv1 * acc1[0], dv1 * acc1[1], dv1 * acc1[2], dv1 * acc1[3]);
    if (n2 < NN)
      *(unsigned*)(Qf8 + (size_t)n2 * FD + colb) =
          pack4e4m3(dv2 * acc2[0], dv2 * acc2[1], dv2 * acc2[2], dv2 * acc2[3]);
    if (n3 < NN)
      *(unsigned*)(Qf8 + (size_t)n3 * FD + colb) =
          pack4e4m3(dv3 * acc3[0], dv3 * acc3[1], dv3 * acc3[2], dv3 * acc3[3]);
  }
}

// ---------- gather: Ph = bf16( relu( scale*sum_e dec(Qf8[src_e]) + b ) ) ----------
// 32 lanes/node, u32/lane; 8 edges in flight; packed f32x2 accumulation
// (v_pk_add_f32), dual accumulator pairs.
__global__ void k_gather(const int* __restrict__ rowptr, const int* __restrict__ csr_src,
                         const unsigned char* __restrict__ Qf8,
                         const float* __restrict__ b,
                         const float* __restrict__ dinv, ushort* __restrict__ Ph) {
  int node = blockIdx.x * 8 + (threadIdx.x >> 5);
  if (node >= NN) return;
  int lane = threadIdx.x & 31;
  const unsigned* __restrict__ Q4 = (const unsigned*)Qf8;
  f32x2 aLoA = {0.f, 0.f}, aHiA = {0.f, 0.f};
  f32x2 aLoB = {0.f, 0.f}, aHiB = {0.f, 0.f};
  int e0 = rowptr[node], e1 = rowptr[node + 1];
  int e = e0;
  for (; e + 7 < e1; e += 8) {
    unsigned q0 = Q4[(size_t)csr_src[e]     * 32 + lane];
    unsigned q1 = Q4[(size_t)csr_src[e + 1] * 32 + lane];
    unsigned q2 = Q4[(size_t)csr_src[e + 2] * 32 + lane];
    unsigned q3 = Q4[(size_t)csr_src[e + 3] * 32 + lane];
    unsigned q4 = Q4[(size_t)csr_src[e + 4] * 32 + lane];
    unsigned q5 = Q4[(size_t)csr_src[e + 5] * 32 + lane];
    unsigned q6 = Q4[(size_t)csr_src[e + 6] * 32 + lane];
    unsigned q7 = Q4[(size_t)csr_src[e + 7] * 32 + lane];
    dec8acc2(q0, aLoA, aHiA); dec8acc2(q1, aLoB, aHiB);
    dec8acc2(q2, aLoA, aHiA); dec8acc2(q3, aLoB, aHiB);
    dec8acc2(q4, aLoA, aHiA); dec8acc2(q5, aLoB, aHiB);
    dec8acc2(q6, aLoA, aHiA); dec8acc2(q7, aLoB, aHiB);
  }
  for (; e + 3 < e1; e += 4) {
    unsigned q0 = Q4[(size_t)csr_src[e]     * 32 + lane];
    unsigned q1 = Q4[(size_t)csr_src[e + 1] * 32 + lane];
    unsigned q2 = Q4[(size_t)csr_src[e + 2] * 32 + lane];
    unsigned q3 = Q4[(size_t)csr_src[e + 3] * 32 + lane];
    dec8acc2(q0, aLoA, aHiA); dec8acc2(q1, aLoB, aHiB);
    dec8acc2(q2, aLoA, aHiA); dec8acc2(q3, aLoB, aHiB);
  }
  for (; e < e1; ++e) {
    unsigned q0 = Q4[(size_t)csr_src[e] * 32 + lane];
    dec8acc2(q0, aLoA, aHiA);
  }
  float4 acc;
  acc.x = aLoA[0] + aLoB[0]; acc.y = aLoA[1] + aLoB[1];
  acc.z = aHiA[0] + aHiB[0]; acc.w = aHiA[1] + aHiB[1];
#if HAVE_DEC
  float di = dinv[node];
#else
  float di = dinv[node] * 256.0f;
#endif
  float4 bv = ((const float4*)b)[lane];
  acc.x = fmaxf(fmaf(di, acc.x, bv.x), 0.f);
  acc.y = fmaxf(fmaf(di, acc.y, bv.y), 0.f);
  acc.z = fmaxf(fmaf(di, acc.z, bv.z), 0.f);
  acc.w = fmaxf(fmaf(di, acc.w, bv.w), 0.f);
  ushort4 h;
  h.x = f2bf(acc.x); h.y = f2bf(acc.y); h.z = f2bf(acc.z); h.w = f2bf(acc.w);
  ((ushort4*)Ph)[(size_t)node * 32 + lane] = h;
}

// ---------- pooling + head ----------

__global__ void k_zero_pool(float* __restrict__ sums, float* __restrict__ counts) {
  int t = blockIdx.x * 256 + threadIdx.x;
  if (t < NG * FD) sums[t] = 0.f;
  if (t < NG) counts[t] = 0.f;
}

#define POOL_BLOCKS 1024
#define POOL_CHUNK 98
__global__ void k_pool(const int* __restrict__ batch, const ushort* __restrict__ Ph,
                       float* __restrict__ sums, float* __restrict__ counts) {
  int f = threadIdx.x;  // 0..127
  int i0 = blockIdx.x * POOL_CHUNK;
  if (i0 >= NN) return;
  int i1 = i0 + POOL_CHUNK;
  if (i1 > NN) i1 = NN;
  float acc = 0.f;
  int gcur = batch[i0];
  int cnt = 0;
  for (int i = i0; i < i1; ++i) {
    int g = batch[i];
    if (g != gcur) {
      atomicAdd(&sums[gcur * FD + f], acc);
      if (f == 0) atomicAdd(&counts[gcur], (float)cnt);
      acc = 0.f; cnt = 0; gcur = g;
    }
    acc += bf2f(Ph[(size_t)i * FD + f]);
    ++cnt;
  }
  atomicAdd(&sums[gcur * FD + f], acc);
  if (f == 0) atomicAdd(&counts[gcur], (float)cnt);
}

__global__ void k_head(const float* __restrict__ sums, const float* __restrict__ counts,
                       const float* __restrict__ Wm, const float* __restrict__ bm,
                       float* __restrict__ out) {
  int t = blockIdx.x * 256 + threadIdx.x;
  if (t >= NG * NC) return;
  int g = t / NC, c = t % NC;
  float inv = 1.0f / fmaxf(counts[g], 1.0f);
  float s = 0.f;
#pragma unroll 4
  for (int f = 0; f < FD; ++f) s = fmaf(sums[g * FD + f] * inv, Wm[f * NC + c], s);
  out[t] = s + bm[c];
}

extern "C" void kernel_launch(void* const* d_in, const int* in_sizes, int n_in,
                              void* d_out, int out_size, void* d_ws, size_t ws_size,
                              hipStream_t stream) {
  const float* x     = (const float*)d_in[0];
  const int*   ei    = (const int*)d_in[1];
  const int*   batch = (const int*)d_in[2];
  const float* W_in  = (const float*)d_in[3];
  const float* b_in  = (const float*)d_in[4];
  const float* W_mid = (const float*)d_in[5];
  const float* b_mid = (const float*)d_in[6];
  const float* W_mlp = (const float*)d_in[7];
  const float* b_mlp = (const float*)d_in[8];
  float* out = (float*)d_out;

  const int* src = ei;        // edge_index[0]
  const int* dst = ei + NE;   // edge_index[1]

  char* ws = (char*)d_ws;
  unsigned char* Qf8 = (unsigned char*)ws;  ws += (size_t)NN * FD;     // 12.8 MB
  ushort*   Ph      = (ushort*)ws;    ws += (size_t)NN * FD * 2;       // 25.6 MB
  float*    dinv    = (float*)ws;     ws += (size_t)NN * 4;
  int*      rowptr  = (int*)ws;       ws += (size_t)(NN + 1) * 4;
  int*      csr_src = (int*)ws;       ws += (size_t)NT * 4;            // 6.8 MB
  unsigned* binned  = (unsigned*)ws;  ws += (size_t)NE * 4;            // 6.4 MB
  int*      histG   = (int*)ws;       ws += (size_t)NBC2 * 4;          // 400 KB
  int*      boffC   = (int*)ws;       ws += (size_t)(NBC2 + 1) * 4;
  int*      cSums   = (int*)ws;       ws += 256 * 4;
  int*      cOffs   = (int*)ws;       ws += 256 * 4;
  ushort*   WhA     = (ushort*)ws;    ws += (size_t)FD * FD * 2;
  ushort*   WlA     = (ushort*)ws;    ws += (size_t)FD * FD * 2;
  ushort*   WhB     = (ushort*)ws;    ws += (size_t)FD * FD * 2;
  ushort*   WlB     = (ushort*)ws;    ws += (size_t)FD * FD * 2;
  float*    sums    = (float*)ws;     ws += (size_t)NG * FD * 4;
  float*    counts  = (float*)ws;     ws += (size_t)NG * 4;

  // chunked binned CSR build (incl. self-loops; reused by all 4 layers)
  k_hist<<<NCH, 256, 0, stream>>>(dst, histG);
  k_s2A<<<SCB2, 256, 0, stream>>>(histG, cSums);
  k_s2B<<<1, 256, 0, stream>>>(cSums, cOffs, boffC);
  k_s2C<<<SCB2, 256, 0, stream>>>(histG, cOffs, boffC);
  k_chscatter<<<NCH, 256, 0, stream>>>(src, dst, boffC, binned);
  k_csr_bucket<<<NBKT, 256, 0, stream>>>(boffC, binned, rowptr, dinv, csr_src);

  // weight packing (W^T fragment order) + input conversion
  k_packW<<<(FD * FD + 255) / 256, 256, 0, stream>>>(W_in, WhA, WlA);
  k_packW<<<(FD * FD + 255) / 256, 256, 0, stream>>>(W_mid, WhB, WlB);
  k_cvt<<<(NN * FD / 4 + 255) / 256, 256, 0, stream>>>(x, Ph);

  const int gM = (NN + 255) / 256;   // 391 blocks, 256 rows each
  const int gG = (NN + 7) / 8;       // 12500 blocks, 8 nodes each
  for (int L = 0; L < 4; ++L) {
    const ushort* Wh = (L == 0) ? WhA : WhB;
    const ushort* Wl = (L == 0) ? WlA : WlB;
    const float*  b  = (L == 0) ? b_in : b_mid;
    k_gemm_mfma<<<gM, 256, 0, stream>>>(Ph, Wh, Wl, dinv, Qf8);
    k_gather<<<gG, 256, 0, stream>>>(rowptr, csr_src, Qf8, b, dinv, Ph);
  }

  k_zero_pool<<<32, 256, 0, stream>>>(sums, counts);
  k_pool<<<POOL_BLOCKS, 128, 0, stream>>>(batch, Ph, sums, counts);
  k_head<<<(NG * NC + 255) / 256, 256, 0, stream>>>(sums, counts, W_mlp, b_mlp, out);
}